// Round 14
// baseline (282.022 us; speedup 1.0000x reference)
//
#include <hip/hip_runtime.h>
#include <math.h>

constexpr int S  = 2048;
constexpr int D  = 1024;
constexpr int NH = 16;
constexpr int NE = 8;
constexpr float EPS   = 1e-6f;
constexpr float THETA = 10000.0f;
constexpr float SCL2  = 0.125f * 1.4426950408889634f;  // attn scale * log2(e)
constexpr float LOG2E = 1.4426950408889634f;

typedef unsigned short u16;
typedef unsigned int   u32;
typedef unsigned long long u64;
typedef __attribute__((ext_vector_type(8))) short short8;
typedef __attribute__((ext_vector_type(4))) float f32x4;

__device__ __forceinline__ u16 f2bf(float x) {
  union { float f; u32 u; } v; v.f = x;
  u32 r = (v.u + 0x7FFFu + ((v.u >> 16) & 1u)) >> 16;
  return (u16)r;
}
__device__ __forceinline__ float bf2f(u16 h) {
  union { u32 u; float f; } v; v.u = ((u32)h) << 16;
  return v.f;
}
__device__ __forceinline__ f32x4 mfma16(short8 a, short8 b, f32x4 c) {
  return __builtin_amdgcn_mfma_f32_16x16x32_bf16(a, b, c, 0, 0, 0);
}
__device__ __forceinline__ void gl_lds16(const void* g, void* l) {
  __builtin_amdgcn_global_load_lds((const __attribute__((address_space(1))) u32*)g,
                                   (__attribute__((address_space(3))) u32*)l, 16, 0, 0);
}
__device__ __forceinline__ u64 pack4bf(float a, float b, float c, float d) {
  return (u64)f2bf(a) | ((u64)f2bf(b) << 16) | ((u64)f2bf(c) << 32) | ((u64)f2bf(d) << 48);
}

// ================================================= unified prep kernel
// [0,7168): weight transposes; [7168,7424): rope tab; [7424,9472): rmsnorm_split rows
__global__ __launch_bounds__(256) void prep_kernel(const float* __restrict__ wqkv,
    const float* __restrict__ wo, const float* __restrict__ wg, const float* __restrict__ wu,
    const float* __restrict__ wd, const int* __restrict__ positions,
    const float* __restrict__ hidden, const float* __restrict__ ln1_w,
    u16* __restrict__ wqkvT2, u16* __restrict__ woT2, u16* __restrict__ wgT,
    u16* __restrict__ wuT, u16* __restrict__ wdT, float2* __restrict__ ropetab,
    u16* __restrict__ xn2) {
  const int b = blockIdx.x;
  const int tid = threadIdx.x;
  if (b >= 7424) {  // rmsnorm_split
    const int t = b - 7424;
    const float* xr = hidden + (size_t)t * D;
    float v[4]; float ss = 0.f;
#pragma unroll
    for (int i = 0; i < 4; ++i) v[i] = xr[tid + i * 256];
#pragma unroll
    for (int i = 0; i < 4; ++i) ss += v[i] * v[i];
#pragma unroll
    for (int m = 32; m >= 1; m >>= 1) ss += __shfl_xor(ss, m, 64);
    __shared__ float red[4];
    if ((tid & 63) == 0) red[tid >> 6] = ss;
    __syncthreads();
    const float rs = rsqrtf((red[0] + red[1] + red[2] + red[3]) * (1.f / (float)D) + EPS);
#pragma unroll
    for (int i = 0; i < 4; ++i) {
      const int d = tid + i * 256;
      const float y = v[i] * rs * ln1_w[d];
      const u16 h = f2bf(y);
      xn2[(size_t)t * 2048 + d] = h;
      xn2[(size_t)t * 2048 + 1024 + d] = f2bf(y - bf2f(h));
    }
    return;
  }
  if (b >= 7168) {  // rope table
    const int idx = (b - 7168) * 256 + tid;
    const int t = idx >> 5, p = idx & 31;
    const float inv = powf(THETA, -(float)p * (1.f / 32.f));
    const float fr = (float)positions[t] * inv;
    float sn, cs; sincosf(fr, &sn, &cs);
    ropetab[idx] = make_float2(cs, sn);
    return;
  }
  __shared__ float t_[64][65];
  const float* W; u16* out; int N, n0, k0; bool split;
  if (b < 768) {
    W = wqkv; out = wqkvT2; N = 3072; split = true;
    n0 = (b % 48) * 64; k0 = (b / 48) * 64;
  } else if (b < 1024) {
    W = wo; out = woT2; N = 1024; split = true;
    const int r = b - 768; n0 = (r & 15) * 64; k0 = (r >> 4) * 64;
  } else {
    int r;
    if (b < 3072)      { r = b - 1024; const int e = r >> 8; W = wg + (size_t)e * 1048576; out = wgT + (size_t)e * 1048576; }
    else if (b < 5120) { r = b - 3072; const int e = r >> 8; W = wu + (size_t)e * 1048576; out = wuT + (size_t)e * 1048576; }
    else               { r = b - 5120; const int e = r >> 8; W = wd + (size_t)e * 1048576; out = wdT + (size_t)e * 1048576; }
    N = 1024; split = false;
    r &= 255; n0 = (r & 15) * 64; k0 = (r >> 4) * 64;
  }
  const int rr = tid >> 4, c4 = (tid & 15) * 4;
  float4 vv[4];
#pragma unroll
  for (int i = 0; i < 4; ++i)
    vv[i] = *(const float4*)(W + (size_t)(k0 + rr + i * 16) * N + n0 + c4);
#pragma unroll
  for (int i = 0; i < 4; ++i) {
    t_[rr + i * 16][c4 + 0] = vv[i].x; t_[rr + i * 16][c4 + 1] = vv[i].y;
    t_[rr + i * 16][c4 + 2] = vv[i].z; t_[rr + i * 16][c4 + 3] = vv[i].w;
  }
  __syncthreads();
  float cv[4][4];
#pragma unroll
  for (int i = 0; i < 4; ++i)
#pragma unroll
    for (int j = 0; j < 4; ++j) cv[i][j] = t_[c4 + j][rr + i * 16];
  if (split) {
    u64 hi_[4], lo_[4];
#pragma unroll
    for (int i = 0; i < 4; ++i) {
      u64 hw = 0, lw = 0;
#pragma unroll
      for (int j = 0; j < 4; ++j) {
        const float v = cv[i][j];
        const u16 h = f2bf(v);
        const u16 l = f2bf(v - bf2f(h));
        hw |= (u64)h << (j * 16);
        lw |= (u64)l << (j * 16);
      }
      hi_[i] = hw; lo_[i] = lw;
    }
#pragma unroll
    for (int i = 0; i < 4; ++i) {
      u16* oh = out + (size_t)(n0 + rr + i * 16) * 2048 + k0 + c4;
      *(u64*)(void*)oh = hi_[i];
      *(u64*)(void*)(oh + 1024) = lo_[i];
    }
  } else {
    u64 pw[4];
#pragma unroll
    for (int i = 0; i < 4; ++i)
      pw[i] = pack4bf(cv[i][0], cv[i][1], cv[i][2], cv[i][3]);
#pragma unroll
    for (int i = 0; i < 4; ++i)
      *(u64*)(void*)(out + (size_t)(n0 + rr + i * 16) * 1024 + k0 + c4) = pw[i];
  }
}

// ================================================= QKV GEMM: 64x128 tile, full K (3-seg split),
// direct bf16 hi/lo output + rope epilogue. grid 768: xcd=b&7; ii=b>>3: m=ii&31, np=ii>>5
__global__ __launch_bounds__(256) void gemm_qkv(const u16* __restrict__ A2,
    const u16* __restrict__ Bt2, const float2* __restrict__ tab,
    u16* __restrict__ Ch, u16* __restrict__ Cl) {
  __shared__ u16 As[2][64 * 32];
  __shared__ u16 Bs[2][128 * 32];
  const int b = blockIdx.x;
  const int xcd = b & 7, ii = b >> 3;
  const int m0 = (ii & 31) * 64;
  const int np = ii >> 5;
  const int n0 = (xcd * 3 + np) * 128;
  const int tid = threadIdx.x, wv = tid >> 6, lane = tid & 63;
  const int l15 = lane & 15, lg = lane >> 4;
  const int wr = wv >> 1, wc = wv & 1;
  const int sr = lane >> 2, sk = (lane & 3) * 16;
  const u16* aptr = A2 + (size_t)(m0 + wv * 16 + sr) * 2048;
  const u16* bptr[2];
#pragma unroll
  for (int i = 0; i < 2; ++i)
    bptr[i] = Bt2 + (size_t)(n0 + (wv * 2 + i) * 16 + sr) * 2048;
  auto STAGE = [&](int buf, int kk) {
    const int t = kk * 32;
    int ka, kb;
    if (t < 1024)      { ka = t;        kb = t; }
    else if (t < 2048) { ka = t;        kb = t - 1024; }
    else               { ka = t - 2048; kb = t - 1024; }
    gl_lds16((const char*)(aptr + ka) + sk, (char*)As + buf * 4096 + wv * 1024);
#pragma unroll
    for (int i = 0; i < 2; ++i)
      gl_lds16((const char*)(bptr[i] + kb) + sk, (char*)Bs + buf * 8192 + (wv * 2 + i) * 1024);
  };
  f32x4 acc[2][4] = {};
  STAGE(0, 0);
  __syncthreads();
  int cur = 0;
  for (int kk = 0; kk < 96; ++kk) {
    if (kk < 95) STAGE(cur ^ 1, kk + 1);
    const u16* Ab = (const u16*)As + cur * 2048;
    const u16* Bb = (const u16*)Bs + cur * 4096;
    short8 a[2], bb[4];
#pragma unroll
    for (int i = 0; i < 2; ++i)
      a[i] = *(const short8*)(const void*)(Ab + (size_t)(wr * 32 + i * 16 + l15) * 32 + lg * 8);
#pragma unroll
    for (int j = 0; j < 4; ++j)
      bb[j] = *(const short8*)(const void*)(Bb + (size_t)(wc * 64 + j * 16 + l15) * 32 + lg * 8);
    __builtin_amdgcn_s_setprio(1);
#pragma unroll
    for (int i = 0; i < 2; ++i)
#pragma unroll
      for (int j = 0; j < 4; ++j) acc[i][j] = mfma16(a[i], bb[j], acc[i][j]);
    __builtin_amdgcn_s_setprio(0);
    __syncthreads();
    cur ^= 1;
  }
  const int nb = n0 + wc * 64;           // 64-col group = one head-slice of q, k, or v
  const bool isqk = (nb < 2048);
#pragma unroll
  for (int i = 0; i < 2; ++i)
#pragma unroll
    for (int j2 = 0; j2 < 2; ++j2)
#pragma unroll
      for (int r = 0; r < 4; ++r) {
        const int row = m0 + wr * 32 + i * 16 + lg * 4 + r;
        const int p = j2 * 16 + l15;     // head-local in [0,32)
        float y1 = acc[i][j2][r], y2 = acc[i][j2 + 2][r];
        if (isqk) {
          const float2 cs = tab[row * 32 + p];
          const float x1 = y1, x2 = y2;
          y1 = x1 * cs.x - x2 * cs.y;
          y2 = x1 * cs.y + x2 * cs.x;
        }
        const size_t base = (size_t)row * 3072 + nb + p;
        const u16 h1 = f2bf(y1);
        Ch[base] = h1; Cl[base] = f2bf(y1 - bf2f(h1));
        const u16 h2 = f2bf(y2);
        Ch[base + 32] = h2; Cl[base + 32] = f2bf(y2 - bf2f(h2));
      }
}

// ================================================= Wo GEMM: 128x128, split-bf16, dbuf, XCD-swz, Kx4
__global__ __launch_bounds__(256) void gemm_wo(const u16* __restrict__ A2,
    const u16* __restrict__ Bt2, float* __restrict__ Pout) {
  constexpr int N = 1024;
  __shared__ u16 As[2][128 * 32];
  __shared__ u16 Bs[2][128 * 32];
  const int b = blockIdx.x;
  const int xcd = b & 7, ii = b >> 3;
  const int n0 = xcd * 128;
  const int m0 = (ii & 15) * 128;
  const int ks = ii >> 4;
  const int kk0 = ks * 24, kk1 = kk0 + 24;
  const int tid = threadIdx.x, wv = tid >> 6, lane = tid & 63;
  const int l15 = lane & 15, lg = lane >> 4;
  const int wr = wv >> 1, wc = wv & 1;
  const int sr = lane >> 2, sk = (lane & 3) * 16;
  const u16* aptr[2]; const u16* bptr[2];
#pragma unroll
  for (int i = 0; i < 2; ++i) {
    aptr[i] = A2 + (size_t)(m0 + (wv * 2 + i) * 16 + sr) * 2048;
    bptr[i] = Bt2 + (size_t)(n0 + (wv * 2 + i) * 16 + sr) * 2048;
  }
  auto STAGE = [&](int buf, int kk) {
    const int t = kk * 32;
    int ka, kb;
    if (t < 1024)      { ka = t;        kb = t; }
    else if (t < 2048) { ka = t;        kb = t - 1024; }
    else               { ka = t - 2048; kb = t - 1024; }
#pragma unroll
    for (int i = 0; i < 2; ++i) {
      gl_lds16((const char*)(aptr[i] + ka) + sk, (char*)As + buf * 8192 + (wv * 2 + i) * 1024);
      gl_lds16((const char*)(bptr[i] + kb) + sk, (char*)Bs + buf * 8192 + (wv * 2 + i) * 1024);
    }
  };
  f32x4 acc[4][4] = {};
  STAGE(0, kk0);
  __syncthreads();
  int cur = 0;
  for (int kk = kk0; kk < kk1; ++kk) {
    if (kk + 1 < kk1) STAGE(cur ^ 1, kk + 1);
    const u16* Ab = (const u16*)As + cur * 4096;
    const u16* Bb = (const u16*)Bs + cur * 4096;
    short8 a[4], bb[4];
#pragma unroll
    for (int i = 0; i < 4; ++i)
      a[i] = *(const short8*)(const void*)(Ab + (size_t)(wr * 64 + i * 16 + l15) * 32 + lg * 8);
#pragma unroll
    for (int j = 0; j < 4; ++j)
      bb[j] = *(const short8*)(const void*)(Bb + (size_t)(wc * 64 + j * 16 + l15) * 32 + lg * 8);
    __builtin_amdgcn_s_setprio(1);
#pragma unroll
    for (int i = 0; i < 4; ++i)
#pragma unroll
      for (int j = 0; j < 4; ++j) acc[i][j] = mfma16(a[i], bb[j], acc[i][j]);
    __builtin_amdgcn_s_setprio(0);
    __syncthreads();
    cur ^= 1;
  }
  float* P = Pout + (size_t)ks * S * N;
#pragma unroll
  for (int i = 0; i < 4; ++i)
#pragma unroll
    for (int j = 0; j < 4; ++j)
#pragma unroll
      for (int r = 0; r < 4; ++r) {
        const int row = m0 + wr * 64 + i * 16 + lg * 4 + r;
        const int col = n0 + wc * 64 + j * 16 + l15;
        P[(size_t)row * N + col] = acc[i][j][r];
      }
}

// ================================================= MFMA flash attention: swapped QK^T, split-K x4,
// single-buffer K hi+lo in LDS, two-pass PV. 44KB LDS -> 3 blocks/CU. grid 2048
__global__ __launch_bounds__(256, 3) void attn_mfma(const u16* __restrict__ Qh,
    const u16* __restrict__ Ql, float* __restrict__ Opart, float2* __restrict__ ml) {
  const int b = blockIdx.x;
  const int head = (b & 7) + 8 * ((b >> 3) & 1);
  const int qb = 31 - ((b >> 4) & 31);
  const int sp = (b >> 9) & 3;
  const int q0 = qb * 64;
  const int ktiles = qb + 1;
  const int kbase = ktiles >> 2, krem = ktiles & 3;
  const int t0 = sp * kbase + (sp < krem ? sp : krem);
  const int t1 = t0 + kbase + (sp < krem ? 1 : 0);
  const int tid = threadIdx.x, w = tid >> 6, lane = tid & 63;
  const int l15 = lane & 15, lg = lane >> 4;
  __shared__ u16 Kh[64 * 64];
  __shared__ u16 Kl[64 * 64];
  __shared__ __align__(16) u16 Vth[64 * 72];
  __shared__ __align__(16) u16 Vtl[64 * 72];
  __shared__ __align__(16) u16 Pp[4][16 * 72];

  short8 qh[2], qlo[2];
  {
    const size_t qbase = (size_t)(q0 + w * 16 + l15) * 3072 + head * 64;
    qh[0]  = *(const short8*)(const void*)(Qh + qbase + lg * 8);
    qh[1]  = *(const short8*)(const void*)(Qh + qbase + 32 + lg * 8);
    qlo[0] = *(const short8*)(const void*)(Ql + qbase + lg * 8);
    qlo[1] = *(const short8*)(const void*)(Ql + qbase + 32 + lg * 8);
  }
  f32x4 oacc[4] = {};
  float m_run = -__builtin_inff(), l_run = 0.f;
  const int qrow0 = q0 + w * 16 + lg * 4;
  const int qcol  = q0 + w * 16 + l15;

  const int vhl = tid >> 7, rem = tid & 127;
  const int vkq = rem & 15, vdg = rem >> 4;
  const u16* vbase = (vhl ? Ql : Qh) + 2048 + head * 64 + vdg * 8;
  u16* vdst = vhl ? Vtl : Vth;
  short8 vr[4];

  auto STAGEK = [&](int kt) {
#pragma unroll
    for (int i = 0; i < 2; ++i) {
      const int inst = w * 2 + i;
      const int key = inst * 8 + (lane >> 3);
      const int db = ((lane & 7) * 16) ^ ((key & 7) << 4);
      gl_lds16((const char*)(Qh + (size_t)(kt * 64 + key) * 3072 + 1024 + head * 64) + db,
               (char*)Kh + inst * 1024);
      gl_lds16((const char*)(Ql + (size_t)(kt * 64 + key) * 3072 + 1024 + head * 64) + db,
               (char*)Kl + inst * 1024);
    }
  };
  auto VLOAD = [&](int kt) {
    const u16* vs = vbase + (size_t)(kt * 64 + vkq * 4) * 3072;
    vr[0] = *(const short8*)(const void*)vs;
    vr[1] = *(const short8*)(const void*)(vs + 3072);
    vr[2] = *(const short8*)(const void*)(vs + 6144);
    vr[3] = *(const short8*)(const void*)(vs + 9216);
  };
  auto VWRITE = [&]() {
#pragma unroll
    for (int jj = 0; jj < 8; ++jj) {
      const u64 pk = (u64)(u16)vr[0][jj] | ((u64)(u16)vr[1][jj] << 16) |
                     ((u64)(u16)vr[2][jj] << 32) | ((u64)(u16)vr[3][jj] << 48);
      *(u64*)(void*)(vdst + (vdg * 8 + jj) * 72 + vkq * 4) = pk;
    }
  };

  if (t0 < t1) {
    STAGEK(t0);
    VLOAD(t0);
    VWRITE();
    __syncthreads();
  }
  for (int t = t0; t < t1; ++t) {
    const int k0 = t * 64;
    const bool more = (t + 1 < t1);
    f32x4 sacc[4];
    __builtin_amdgcn_s_setprio(1);
#pragma unroll
    for (int nt = 0; nt < 4; ++nt) {
      const int key = nt * 16 + l15;
      const char* kbh = (const char*)Kh + key * 128;
      const char* kbl = (const char*)Kl + key * 128;
      const int sw = (key & 7) << 4;
      const short8 kh0 = *(const short8*)(const void*)(kbh + ((lg * 16) ^ sw));
      const short8 kh1 = *(const short8*)(const void*)(kbh + ((64 + lg * 16) ^ sw));
      const short8 kl0 = *(const short8*)(const void*)(kbl + ((lg * 16) ^ sw));
      const short8 kl1 = *(const short8*)(const void*)(kbl + ((64 + lg * 16) ^ sw));
      f32x4 s = {};
      s = mfma16(kh0, qh[0], s);  s = mfma16(kh1, qh[1], s);
      s = mfma16(kh0, qlo[0], s); s = mfma16(kh1, qlo[1], s);
      s = mfma16(kl0, qh[0], s);  s = mfma16(kl1, qh[1], s);
      sacc[nt] = s;
    }
    __builtin_amdgcn_s_setprio(0);
    __syncthreads();                  // B1: K reads done
    if (more) { STAGEK(t + 1); VLOAD(t + 1); }
#pragma unroll
    for (int nt = 0; nt < 4; ++nt)
#pragma unroll
      for (int r = 0; r < 4; ++r) sacc[nt][r] *= SCL2;
    if (t == qb) {
#pragma unroll
      for (int nt = 0; nt < 4; ++nt) {
        const int keyb = k0 + nt * 16 + lg * 4;
#pragma unroll
        for (int r = 0; r < 4; ++r)
          if (keyb + r > qcol) sacc[nt][r] = -__builtin_inff();
      }
    }
    float mx = sacc[0][0];
#pragma unroll
    for (int nt = 0; nt < 4; ++nt)
#pragma unroll
      for (int r = 0; r < 4; ++r) mx = fmaxf(mx, sacc[nt][r]);
    mx = fmaxf(mx, __shfl_xor(mx, 16, 64));
    mx = fmaxf(mx, __shfl_xor(mx, 32, 64));
    const bool grow = mx > m_run + 8.f;
    if (__any(grow)) {
      const float m_new = fmaxf(m_run, mx);
      const float fac = __builtin_amdgcn_exp2f(m_run - m_new);
      m_run = m_new;
      l_run *= fac;
      float facB[4];
#pragma unroll
      for (int r = 0; r < 4; ++r) facB[r] = __shfl(fac, lg * 4 + r, 64);
#pragma unroll
      for (int nd = 0; nd < 4; ++nd)
#pragma unroll
        for (int r = 0; r < 4; ++r) oacc[nd][r] *= facB[r];
    }
    float ls = 0.f;
#pragma unroll
    for (int nt = 0; nt < 4; ++nt)
#pragma unroll
      for (int r = 0; r < 4; ++r) {
        sacc[nt][r] = __builtin_amdgcn_exp2f(sacc[nt][r] - m_run);
        ls += sacc[nt][r];
      }
    ls += __shfl_xor(ls, 16, 64);
    ls += __shfl_xor(ls, 32, 64);
    l_run += ls;
    u16* prow = &Pp[w][l15 * 72];
#pragma unroll
    for (int nt = 0; nt < 4; ++nt) {
      const u64 pk = (u64)(__float_as_uint(sacc[nt][0]) >> 16) |
                     ((u64)(__float_as_uint(sacc[nt][1]) >> 16) << 16) |
                     ((u64)(__float_as_uint(sacc[nt][2]) >> 16) << 32) |
                     ((u64)(__float_as_uint(sacc[nt][3]) >> 16) << 48);
      *(u64*)(void*)(prow + nt * 16 + lg * 4) = pk;
    }
    __builtin_amdgcn_s_setprio(1);
#pragma unroll
    for (int kk2 = 0; kk2 < 2; ++kk2) {
      const short8 pa = *(const short8*)(const void*)((const char*)prow + kk2 * 64 + lg * 16);
#pragma unroll
      for (int nd = 0; nd < 4; ++nd) {
        const short8 vbh = *(const short8*)(const void*)((const char*)Vth + (nd * 16 + l15) * 144 + kk2 * 64 + lg * 16);
        const short8 vbl = *(const short8*)(const void*)((const char*)Vtl + (nd * 16 + l15) * 144 + kk2 * 64 + lg * 16);
        oacc[nd] = mfma16(pa, vbh, oacc[nd]);
        oacc[nd] = mfma16(pa, vbl, oacc[nd]);
      }
    }
    __builtin_amdgcn_s_setprio(0);
    asm volatile("" ::: "memory");
#pragma unroll
    for (int nt = 0; nt < 4; ++nt) {
      float lo[4];
#pragma unroll
      for (int r = 0; r < 4; ++r)
        lo[r] = sacc[nt][r] - __uint_as_float(__float_as_uint(sacc[nt][r]) & 0xFFFF0000u);
      const u64 pk = (u64)(__float_as_uint(lo[0]) >> 16) |
                     ((u64)(__float_as_uint(lo[1]) >> 16) << 16) |
                     ((u64)(__float_as_uint(lo[2]) >> 16) << 32) |
                     ((u64)(__float_as_uint(lo[3]) >> 16) << 48);
      *(u64*)(void*)(prow + nt * 16 + lg * 4) = pk;
    }
    asm volatile("" ::: "memory");
    __builtin_amdgcn_s_setprio(1);
#pragma unroll
    for (int kk2 = 0; kk2 < 2; ++kk2) {
      const short8 pa = *(const short8*)(const void*)((const char*)prow + kk2 * 64 + lg * 16);
#pragma unroll
      for (int nd = 0; nd < 4; ++nd) {
        const short8 vbh = *(const short8*)(const void*)((const char*)Vth + (nd * 16 + l15) * 144 + kk2 * 64 + lg * 16);
        oacc[nd] = mfma16(pa, vbh, oacc[nd]);
      }
    }
    __builtin_amdgcn_s_setprio(0);
    __syncthreads();                  // B2
    if (more) VWRITE();
  }
  float* Op = Opart + (size_t)sp * S * 1024;
#pragma unroll
  for (int nd = 0; nd < 4; ++nd)
#pragma unroll
    for (int r = 0; r < 4; ++r)
      Op[(size_t)(qrow0 + r) * 1024 + head * 64 + nd * 16 + l15] = oacc[nd][r];
  if (lg == 0) {
    ml[((size_t)sp * S + q0 + w * 16 + l15) * NH + head] = make_float2(m_run, l_run);
  }
}

// ================================================= combine 4 split-K attention partials
__global__ __launch_bounds__(256) void attn_combine(const float* __restrict__ Op,
    const float2* __restrict__ ml, u16* __restrict__ OA2) {
  const int t = blockIdx.x, tid = threadIdx.x;
  const int h = tid >> 4, dq = (tid & 15) * 4;
  float2 a[4];
  float M = -__builtin_inff();
#pragma unroll
  for (int c = 0; c < 4; ++c) {
    a[c] = ml[((size_t)c * S + t) * NH + h];
    if (a[c].y > 0.f) M = fmaxf(M, a[c].x);
  }
  float e[4], denom = 0.f;
#pragma unroll
  for (int c = 0; c < 4; ++c) {
    e[c] = (a[c].y > 0.f) ? exp2f(a[c].x - M) : 0.f;
    denom += e[c] * a[c].y;
  }
  const float inv = 1.f / denom;
  float ov[4] = {0.f, 0.f, 0.f, 0.f};
#pragma unroll
  for (int c = 0; c < 4; ++c) {
    const float4 v = *(const float4*)(Op + ((size_t)c * S + t) * 1024 + h * 64 + dq);
    ov[0] += e[c] * v.x; ov[1] += e[c] * v.y; ov[2] += e[c] * v.z; ov[3] += e[c] * v.w;
  }
  u64 hw = 0, lw = 0;
#pragma unroll
  for (int c2 = 0; c2 < 4; ++c2) {
    const float o = ov[c2] * inv;
    const u16 hb = f2bf(o);
    hw |= (u64)hb << (c2 * 16);
    lw |= (u64)f2bf(o - bf2f(hb)) << (c2 * 16);
  }
  const size_t idx = (size_t)t * 2048 + h * 64 + dq;
  *(u64*)(void*)(OA2 + idx) = hw;
  *(u64*)(void*)(OA2 + idx + 1024) = lw;
}

// ================================================= res2 (4 partials) + rmsnorm2 + gate (no atomics)
__global__ __launch_bounds__(256) void rmsnorm_res2_gate(const float* __restrict__ hidden,
    const float* __restrict__ p01, const float* __restrict__ w2, const float* __restrict__ GW,
    float* __restrict__ out, u16* __restrict__ yb,
    int* __restrict__ top2, float2* __restrict__ topw) {
  const int t = blockIdx.x;
  const int d0 = threadIdx.x * 4;
  const size_t base = (size_t)t * D + d0;
  const float4 h4 = *(const float4*)(hidden + base);
  const float4 a4 = *(const float4*)(p01 + base);
  const float4 b4 = *(const float4*)(p01 + (size_t)S * D + base);
  const float4 c4 = *(const float4*)(p01 + 2 * (size_t)S * D + base);
  const float4 e4 = *(const float4*)(p01 + 3 * (size_t)S * D + base);
  float v[4] = {h4.x + a4.x + b4.x + c4.x + e4.x, h4.y + a4.y + b4.y + c4.y + e4.y,
                h4.z + a4.z + b4.z + c4.z + e4.z, h4.w + a4.w + b4.w + c4.w + e4.w};
  float ss = v[0] * v[0] + v[1] * v[1] + v[2] * v[2] + v[3] * v[3];
#pragma unroll
  for (int m = 32; m >= 1; m >>= 1) ss += __shfl_xor(ss, m, 64);
  __shared__ float red[4];
  if ((threadIdx.x & 63) == 0) red[threadIdx.x >> 6] = ss;
  __syncthreads();
  const float rs = rsqrtf((red[0] + red[1] + red[2] + red[3]) * (1.f / (float)D) + EPS);
  const float4 w4 = *(const float4*)(w2 + d0);
  const float y[4] = {v[0] * rs * w4.x, v[1] * rs * w4.y, v[2] * rs * w4.z, v[3] * rs * w4.w};
  *(float4*)(out + base) = make_float4(v[0], v[1], v[2], v[3]);
  *(u64*)(void*)(yb + base) = pack4bf(y[0], y[1], y[2], y[3]);
  float lg[8] = {};
#pragma unroll
  for (int j = 0; j < 4; ++j) {
    const float4 g0 = *(const float4*)(GW + (d0 + j) * 8);
    const float4 g1 = *(const float4*)(GW + (d0 + j) * 8 + 4);
    lg[0] += y[j] * g0.x; lg[1] += y[j] * g0.y; lg[2] += y[j] * g0.z; lg[3] += y[j] * g0.w;
    lg[4] += y[j] * g1.x; lg[5] += y[j] * g1.y; lg[6] += y[j] * g1.z; lg[7] += y[j] * g1.w;
  }
#pragma unroll
  for (int e = 0; e < 8; ++e)
#pragma unroll
    for (int m = 32; m >= 1; m >>= 1) lg[e] += __shfl_xor(lg[e], m, 64);
  __shared__ float wred[4][8];
  if ((threadIdx.x & 63) == 0)
#pragma unroll
    for (int e = 0; e < 8; ++e) wred[threadIdx.x >> 6][e] = lg[e];
  __syncthreads();
  if (threadIdx.x == 0) {
    float L[8];
#pragma unroll
    for (int e = 0; e < 8; ++e) L[e] = wred[0][e] + wred[1][e] + wred[2][e] + wred[3][e];
    int i0 = 0; float v0 = L[0];
    for (int i = 1; i < 8; ++i) if (L[i] > v0) { v0 = L[i]; i0 = i; }
    int i1 = -1; float v1 = -__builtin_inff();
    for (int i = 0; i < 8; ++i) if (i != i0 && L[i] > v1) { v1 = L[i]; i1 = i; }
    const float e1 = expf(v1 - v0);
    const float inv = 1.f / (1.f + e1);
    top2[t] = i0 | (i1 << 4);
    topw[t] = make_float2(inv, e1 * inv);
  }
}

// ================================================= scatter compact: deterministic prefix-scan
__global__ __launch_bounds__(1024) void scatter_compact(const int* __restrict__ top2,
    const float2* __restrict__ topw, int* __restrict__ counts,
    int* __restrict__ tok_map, float* __restrict__ w_map) {
  const int tid = threadIdx.x;
  __shared__ u64 s0[1024], s1[1024];
  int e_[2][2]; float w_[2][2];
  u64 c0 = 0, c1 = 0;
#pragma unroll
  for (int k = 0; k < 2; ++k) {
    const int t = tid * 2 + k;
    const int pk = top2[t];
    const float2 wv = topw[t];
    e_[k][0] = pk & 15; e_[k][1] = (pk >> 4) & 15;
    w_[k][0] = wv.x;    w_[k][1] = wv.y;
#pragma unroll
    for (int s = 0; s < 2; ++s) {
      const int e = e_[k][s];
      if (e < 4) c0 += 1ull << (e * 16); else c1 += 1ull << ((e - 4) * 16);
    }
  }
  s0[tid] = c0; s1[tid] = c1;
  __syncthreads();
  for (int off = 1; off < 1024; off <<= 1) {
    const u64 a0 = (tid >= off) ? s0[tid - off] : 0;
    const u64 a1 = (tid >= off) ? s1[tid - off] : 0;
    __syncthreads();
    s0[tid] += a0; s1[tid] += a1;
    __syncthreads();
  }
  if (tid == 1023) {
#pragma unroll
    for (int e = 0; e < 4; ++e) counts[e] = (int)((s0[1023] >> (e * 16)) & 0xFFFF);
#pragma unroll
    for (int e = 4; e < 8; ++e) counts[e] = (int)((s1[1023] >> ((e - 4) * 16)) & 0xFFFF);
  }
  u64 l0 = s0[tid] - c0, l1 = s1[tid] - c1;
#pragma unroll
  for (int k = 0; k < 2; ++k) {
    const int t = tid * 2 + k;
#pragma unroll
    for (int s = 0; s < 2; ++s) {
      const int e = e_[k][s];
      int p;
      if (e < 4) { p = (int)((l0 >> (e * 16)) & 0xFFFF); l0 += 1ull << (e * 16); }
      else       { p = (int)((l1 >> ((e - 4) * 16)) & 0xFFFF); l1 += 1ull << ((e - 4) * 16); }
      tok_map[e * S + p] = t | (s << 16);
      w_map[e * S + p] = w_[k][s];
    }
  }
}

// ================================================= MoE gate/up GEMM: 128x64 tile, dual-B, dbuf
__global__ __launch_bounds__(256) void moe_gu(const u16* __restrict__ Yb,
    const u16* __restrict__ Wgb, const u16* __restrict__ Wub, u16* __restrict__ Hb,
    const int* __restrict__ counts, const int* __restrict__ tokmap) {
  const int b = blockIdx.x;
  const int e = b & 7, ii = b >> 3;
  const int n0 = (ii & 15) * 64;
  const int m0 = (ii >> 4) * 128;
  const int cnt = counts[e];
  if (m0 >= cnt) return;
  __shared__ u16 SH[2][16 * 512];
  const int tid = threadIdx.x, wv = tid >> 6, lane = tid & 63;
  const int l15 = lane & 15, lg = lane >> 4;
  const int wr = wv >> 1, wc = wv & 1;
  const int sr = lane >> 2, sk = (lane & 3) * 16;
  const u16* B1 = Wgb + (size_t)e * 1048576;
  const u16* B2 = Wub + (size_t)e * 1048576;
  const u16* cp[4];
#pragma unroll
  for (int i = 0; i < 4; ++i) {
    const int c = wv * 4 + i;
    if (c < 8) {
      const int arow = m0 + c * 16 + sr;
      const int tok = tokmap[e * S + arow] & 2047;
      cp[i] = Yb + (size_t)tok * 1024;
    } else if (c < 12) {
      cp[i] = B1 + (size_t)(n0 + (c - 8) * 16 + sr) * 1024;
    } else {
      cp[i] = B2 + (size_t)(n0 + (c - 12) * 16 + sr) * 1024;
    }
  }
  auto STAGE = [&](int buf, int k) {
#pragma unroll
    for (int i = 0; i < 4; ++i) {
      const int c = wv * 4 + i;
      gl_lds16((const char*)(cp[i] + k) + sk, (char*)SH + buf * 16384 + c * 1024);
    }
  };
  f32x4 acc1[4][2] = {};
  f32x4 acc2[4][2] = {};
  STAGE(0, 0);
  __syncthreads();
  int cur = 0;
  for (int kk = 0; kk < 32; ++kk) {
    if (kk < 31) STAGE(cur ^ 1, (kk + 1) * 32);
    const u16* Sb = (const u16*)SH + cur * 8192;
    short8 a[4], b1f[2], b2f[2];
#pragma unroll
    for (int i = 0; i < 4; ++i)
      a[i] = *(const short8*)(const void*)(Sb + (size_t)(wr * 64 + i * 16 + l15) * 32 + lg * 8);
#pragma unroll
    for (int j = 0; j < 2; ++j) {
      b1f[j] = *(const short8*)(const void*)(Sb + 4096 + (size_t)(wc * 32 + j * 16 + l15) * 32 + lg * 8);
      b2f[j] = *(const short8*)(const void*)(Sb + 6144 + (size_t)(wc * 32 + j * 16 + l15) * 32 + lg * 8);
    }
    __builtin_amdgcn_s_setprio(1);
#pragma unroll
    for (int i = 0; i < 4; ++i)
#pragma unroll
      for (int j = 0; j < 2; ++j) {
        acc1[i][j] = mfma16(a[i], b1f[j], acc1[i][j]);
        acc2[i][j] = mfma16(a[i], b2f[j], acc2[i][j]);
      }
    __builtin_amdgcn_s_setprio(0);
    __syncthreads();
    cur ^= 1;
  }
#pragma unroll
  for (int i = 0; i < 4; ++i)
#pragma unroll
    for (int j = 0; j < 2; ++j)
#pragma unroll
      for (int r = 0; r < 4; ++r) {
        const int row = m0 + wr * 64 + i * 16 + lg * 4 + r;
        if (row < cnt) {
          const float g = acc1[i][j][r];
          const float u = acc2[i][j][r];
          const float sig = __builtin_amdgcn_rcpf(1.f + __builtin_amdgcn_exp2f(-g * LOG2E));
          Hb[((size_t)e * 2048 + row) * 1024 + n0 + wc * 32 + j * 16 + l15] = f2bf(u * g * sig);
        }
      }
}

// ================================================= MoE down GEMM: split-K x2 -> 4 bf16 slot planes
__global__ __launch_bounds__(256) void moe_down(const u16* __restrict__ Hb,
    const u16* __restrict__ Wdb, u16* __restrict__ slotp,
    const int* __restrict__ counts, const int* __restrict__ tokmap,
    const float* __restrict__ wmap) {
  const int b = blockIdx.x;
  const int e = b & 7, ii = b >> 3;
  const int m0 = (ii & 15) * 128;
  const int n0 = ((ii >> 4) & 7) * 128;
  const int ks = ii >> 7;
  const int cnt = counts[e];
  if (m0 >= cnt) return;
  __shared__ u16 As[2][128 * 32];
  __shared__ u16 Bs[2][128 * 32];
  const int tid = threadIdx.x, wv = tid >> 6, lane = tid & 63;
  const int l15 = lane & 15, lg = lane >> 4;
  const int wr = wv >> 1, wc = wv & 1;
  const int sr = lane >> 2, sk = (lane & 3) * 16;
  const u16* B = Wdb + (size_t)e * 1048576;
  const u16* aptr[2]; const u16* bptr[2];
#pragma unroll
  for (int i = 0; i < 2; ++i) {
    aptr[i] = Hb + ((size_t)e * 2048 + m0 + (wv * 2 + i) * 16 + sr) * 1024;
    bptr[i] = B + (size_t)(n0 + (wv * 2 + i) * 16 + sr) * 1024;
  }
  auto STAGE = [&](int buf, int k) {
#pragma unroll
    for (int i = 0; i < 2; ++i) {
      gl_lds16((const char*)(aptr[i] + k) + sk, (char*)As + buf * 8192 + (wv * 2 + i) * 1024);
      gl_lds16((const char*)(bptr[i] + k) + sk, (char*)Bs + buf * 8192 + (wv * 2 + i) * 1024);
    }
  };
  f32x4 acc[4][4] = {};
  const int kb0 = ks * 16, kb1 = kb0 + 16;
  STAGE(0, kb0 * 32);
  __syncthreads();
  int cur = 0;
  for (int kk = kb0; kk < kb1; ++kk) {
    if (kk + 1 < kb1) STAGE(cur ^ 1, (kk + 1) * 32);
    const u16* Ab = (const u16*)As + cur * 4096;
    const u16* Bb = (const u16*)Bs + cur * 4096;
    short8 a[4], bb[4];
#pragma unroll
    for (int i = 0; i < 4; ++i)
      a[i] = *(const short8*)(const void*)(Ab + (size_t)(wr * 64 + i * 16 + l15) * 32 + lg * 8);
#pragma unroll
    for (int j = 0; j < 4; ++j)
      bb[j] = *(const short8*)(const void*)(Bb + (size_t)(wc * 64 + j * 16 + l15) * 32 + lg * 8);
    __builtin_amdgcn_s_setprio(1);
#pragma unroll
    for (int i = 0; i < 4; ++i)
#pragma unroll
      for (int j = 0; j < 4; ++j) acc[i][j] = mfma16(a[i], bb[j], acc[i][j]);
    __builtin_amdgcn_s_setprio(0);
    __syncthreads();
    cur ^= 1;
  }
#pragma unroll
  for (int i = 0; i < 4; ++i)
#pragma unroll
    for (int j = 0; j < 4; ++j)
#pragma unroll
      for (int r = 0; r < 4; ++r) {
        const int row = m0 + wr * 64 + i * 16 + lg * 4 + r;
        if (row < cnt) {
          const int raw = tokmap[e * S + row];
          const int t = raw & 2047;
          const int sl = (raw >> 16) & 1;
          const float wgt = wmap[e * S + row];
          slotp[((size_t)(sl * 2 + ks) * S + t) * 1024 + n0 + wc * 64 + j * 16 + l15] =
              f2bf(wgt * acc[i][j][r]);
        }
      }
}

// ================================================= final add: out += sum of 4 slot planes
__global__ __launch_bounds__(256) void final_add(float* __restrict__ out,
    const u16* __restrict__ sp) {
  const size_t i = ((size_t)blockIdx.x * 256 + threadIdx.x) * 4;
  float4 o = *(float4*)(out + i);
#pragma unroll
  for (int c = 0; c < 4; ++c) {
    const u64 a = *(const u64*)(sp + (size_t)c * S * D + i);
    o.x += bf2f((u16)(a));
    o.y += bf2f((u16)(a >> 16));
    o.z += bf2f((u16)(a >> 32));
    o.w += bf2f((u16)(a >> 48));
  }
  *(float4*)(out + i) = o;
}

// ================================================= launch
extern "C" void kernel_launch(void* const* d_in, const int* in_sizes, int n_in,
                              void* d_out, int out_size, void* d_ws, size_t ws_size,
                              hipStream_t stream) {
  const int*   positions = (const int*)d_in[0];
  const float* hidden    = (const float*)d_in[1];
  const float* ln1_w  = (const float*)d_in[3];
  const float* ln2_w  = (const float*)d_in[4];
  const float* wqkv   = (const float*)d_in[5];
  const float* wo     = (const float*)d_in[6];
  const float* gate_w = (const float*)d_in[7];
  const float* wg     = (const float*)d_in[8];
  const float* wu     = (const float*)d_in[9];
  const float* wd     = (const float*)d_in[10];
  float* out = (float*)d_out;

  char* ws = (char*)d_ws;
  const size_t MB = 1ull << 20;
  u16* wqkvT2 = (u16*)(ws);                 // 12MB (dead after gemm_qkv)
  u16* OA2    = (u16*)(ws);                 // 8MB  (after attn)
  u16* woT2   = (u16*)(ws + 12 * MB);       // 4MB
  u16* wgT    = (u16*)(ws + 16 * MB);       // 16MB
  u16* wuT    = (u16*)(ws + 32 * MB);       // 16MB
  u16* wdT    = (u16*)(ws + 48 * MB);       // 16MB
  float2* ropetab = (float2*)(ws + 64 * MB);            // 512KB
  float2* ml      = (float2*)(ws + 64 * MB + 524288);   // 1MB (4 splits)
  char* mapb = ws + 64 * MB + 1572864;
  int*   counts   = (int*)mapb;
  int*   tok_map  = (int*)(mapb + 512);
  float* w_map    = (float*)(mapb + 512 + 65536);
  int*   top2     = (int*)(mapb + 512 + 131072);
  float2* topw    = (float2*)(mapb + 512 + 139264);
  u16* xn2    = (u16*)(ws + 66 * MB);       // 8MB  (ph1-2)
  u16* yb     = (u16*)(ws + 66 * MB);       // 4MB  (ph6+)
  float* Opart  = (float*)(ws + 78 * MB);   // 32MB (ph4)
  float* p01    = (float*)(ws + 78 * MB);   // 32MB (ph5-6)
  u16* Hb     = (u16*)(ws + 78 * MB);       // 32MB (ph7)
  u16* QKVh   = (u16*)(ws + 110 * MB);      // 12MB (ph2-4)
  u16* QKVl   = (u16*)(ws + 122 * MB);      // 12MB (ph2-4)
  u16* slotp  = (u16*)(ws + 110 * MB);      // 16MB (ph7-8, QKV dead)

  prep_kernel<<<9472, 256, 0, stream>>>(wqkv, wo, wg, wu, wd, positions, hidden, ln1_w,
                                        wqkvT2, woT2, wgT, wuT, wdT, ropetab, xn2);
  gemm_qkv<<<768, 256, 0, stream>>>(xn2, wqkvT2, ropetab, QKVh, QKVl);
  attn_mfma<<<2048, 256, 0, stream>>>(QKVh, QKVl, Opart, ml);
  attn_combine<<<S, 256, 0, stream>>>(Opart, ml, OA2);
  gemm_wo<<<512, 256, 0, stream>>>(OA2, woT2, p01);
  rmsnorm_res2_gate<<<S, 256, 0, stream>>>(hidden, p01, ln2_w, gate_w, out, yb, top2, topw);
  scatter_compact<<<1, 1024, 0, stream>>>(top2, topw, counts, tok_map, w_map);
  moe_gu<<<2048, 256, 0, stream>>>(yb, wgT, wuT, Hb, counts, tok_map);
  moe_down<<<2048, 256, 0, stream>>>(Hb, wdT, slotp, counts, tok_map, w_map);
  final_add<<<2048, 256, 0, stream>>>(out, slotp);
}

// Round 15
// 278.047 us; speedup vs baseline: 1.0143x; 1.0143x over previous
//
#include <hip/hip_runtime.h>
#include <math.h>

constexpr int S  = 2048;
constexpr int D  = 1024;
constexpr int NH = 16;
constexpr int NE = 8;
constexpr float EPS   = 1e-6f;
constexpr float THETA = 10000.0f;
constexpr float SCL2  = 0.125f * 1.4426950408889634f;  // attn scale * log2(e)
constexpr float LOG2E = 1.4426950408889634f;

typedef unsigned short u16;
typedef unsigned int   u32;
typedef unsigned long long u64;
typedef __attribute__((ext_vector_type(8))) short short8;
typedef __attribute__((ext_vector_type(4))) float f32x4;

__device__ __forceinline__ u16 f2bf(float x) {
  union { float f; u32 u; } v; v.f = x;
  u32 r = (v.u + 0x7FFFu + ((v.u >> 16) & 1u)) >> 16;
  return (u16)r;
}
__device__ __forceinline__ float bf2f(u16 h) {
  union { u32 u; float f; } v; v.u = ((u32)h) << 16;
  return v.f;
}
__device__ __forceinline__ f32x4 mfma16(short8 a, short8 b, f32x4 c) {
  return __builtin_amdgcn_mfma_f32_16x16x32_bf16(a, b, c, 0, 0, 0);
}
__device__ __forceinline__ void gl_lds16(const void* g, void* l) {
  __builtin_amdgcn_global_load_lds((const __attribute__((address_space(1))) u32*)g,
                                   (__attribute__((address_space(3))) u32*)l, 16, 0, 0);
}
__device__ __forceinline__ u64 pack4bf(float a, float b, float c, float d) {
  return (u64)f2bf(a) | ((u64)f2bf(b) << 16) | ((u64)f2bf(c) << 32) | ((u64)f2bf(d) << 48);
}

// ================================================= unified prep kernel
// [0,7168): weight transposes; [7168,7424): rope tab; [7424,9472): rmsnorm_split rows
__global__ __launch_bounds__(256) void prep_kernel(const float* __restrict__ wqkv,
    const float* __restrict__ wo, const float* __restrict__ wg, const float* __restrict__ wu,
    const float* __restrict__ wd, const int* __restrict__ positions,
    const float* __restrict__ hidden, const float* __restrict__ ln1_w,
    u16* __restrict__ wqkvT2, u16* __restrict__ woT2, u16* __restrict__ wgT,
    u16* __restrict__ wuT, u16* __restrict__ wdT, float2* __restrict__ ropetab,
    u16* __restrict__ xn2) {
  const int b = blockIdx.x;
  const int tid = threadIdx.x;
  if (b >= 7424) {  // rmsnorm_split
    const int t = b - 7424;
    const float* xr = hidden + (size_t)t * D;
    float v[4]; float ss = 0.f;
#pragma unroll
    for (int i = 0; i < 4; ++i) { v[i] = xr[tid + i * 256]; ss += v[i] * v[i]; }
#pragma unroll
    for (int m = 32; m >= 1; m >>= 1) ss += __shfl_xor(ss, m, 64);
    __shared__ float red[4];
    if ((tid & 63) == 0) red[tid >> 6] = ss;
    __syncthreads();
    const float rs = rsqrtf((red[0] + red[1] + red[2] + red[3]) * (1.f / (float)D) + EPS);
#pragma unroll
    for (int i = 0; i < 4; ++i) {
      const int d = tid + i * 256;
      const float y = v[i] * rs * ln1_w[d];
      const u16 h = f2bf(y);
      xn2[(size_t)t * 2048 + d] = h;
      xn2[(size_t)t * 2048 + 1024 + d] = f2bf(y - bf2f(h));
    }
    return;
  }
  if (b >= 7168) {  // rope table
    const int idx = (b - 7168) * 256 + tid;
    const int t = idx >> 5, p = idx & 31;
    const float inv = powf(THETA, -(float)p * (1.f / 32.f));
    const float fr = (float)positions[t] * inv;
    float sn, cs; sincosf(fr, &sn, &cs);
    ropetab[idx] = make_float2(cs, sn);
    return;
  }
  __shared__ float t_[64][65];
  const float* W; u16* out; int N, n0, k0; bool split;
  if (b < 768) {
    W = wqkv; out = wqkvT2; N = 3072; split = true;
    n0 = (b % 48) * 64; k0 = (b / 48) * 64;
  } else if (b < 1024) {
    W = wo; out = woT2; N = 1024; split = true;
    const int r = b - 768; n0 = (r & 15) * 64; k0 = (r >> 4) * 64;
  } else {
    int r;
    if (b < 3072)      { r = b - 1024; const int e = r >> 8; W = wg + (size_t)e * 1048576; out = wgT + (size_t)e * 1048576; }
    else if (b < 5120) { r = b - 3072; const int e = r >> 8; W = wu + (size_t)e * 1048576; out = wuT + (size_t)e * 1048576; }
    else               { r = b - 5120; const int e = r >> 8; W = wd + (size_t)e * 1048576; out = wdT + (size_t)e * 1048576; }
    N = 1024; split = false;
    r &= 255; n0 = (r & 15) * 64; k0 = (r >> 4) * 64;
  }
  const int rr = tid >> 4, c4 = (tid & 15) * 4;
#pragma unroll
  for (int i = 0; i < 4; ++i) {
    const float4 v = *(const float4*)(W + (size_t)(k0 + rr + i * 16) * N + n0 + c4);
    t_[rr + i * 16][c4 + 0] = v.x; t_[rr + i * 16][c4 + 1] = v.y;
    t_[rr + i * 16][c4 + 2] = v.z; t_[rr + i * 16][c4 + 3] = v.w;
  }
  __syncthreads();
  if (split) {
#pragma unroll
    for (int i = 0; i < 4; ++i) {
      const int n = n0 + rr + i * 16;
      u16* oh = out + (size_t)n * 2048 + k0 + c4;
      const float v0 = t_[c4 + 0][rr + i * 16], v1 = t_[c4 + 1][rr + i * 16];
      const float v2 = t_[c4 + 2][rr + i * 16], v3 = t_[c4 + 3][rr + i * 16];
      *(u64*)(void*)oh = pack4bf(v0, v1, v2, v3);
      *(u64*)(void*)(oh + 1024) = pack4bf(v0 - bf2f(f2bf(v0)), v1 - bf2f(f2bf(v1)),
                                          v2 - bf2f(f2bf(v2)), v3 - bf2f(f2bf(v3)));
    }
  } else {
#pragma unroll
    for (int i = 0; i < 4; ++i) {
      const int n = n0 + rr + i * 16;
      u16* o = out + (size_t)n * 1024 + k0 + c4;
      *(u64*)(void*)o = pack4bf(t_[c4 + 0][rr + i * 16], t_[c4 + 1][rr + i * 16],
                                t_[c4 + 2][rr + i * 16], t_[c4 + 3][rr + i * 16]);
    }
  }
}

// ================================================= QKV GEMM: 128x128, split-bf16, dbuf, XCD-swz,
// split-K x2 -> f32 partial planes (plain stores). grid 768
__global__ __launch_bounds__(256) void gemm_qkv(const u16* __restrict__ A2,
    const u16* __restrict__ Bt2, float* __restrict__ Cpart) {
  __shared__ u16 As[2][128 * 32];
  __shared__ u16 Bs[2][128 * 32];
  const int b = blockIdx.x;
  const int xcd = b & 7, ii = b >> 3;
  const int m0 = (ii & 15) * 128;
  const int np = (ii >> 4) % 3, ks = (ii >> 4) / 3;
  const int n0 = (xcd * 3 + np) * 128;
  const int kk0 = ks * 48, kk1 = kk0 + 48;
  const int tid = threadIdx.x, wv = tid >> 6, lane = tid & 63;
  const int l15 = lane & 15, lg = lane >> 4;
  const int wr = wv >> 1, wc = wv & 1;
  const int sr = lane >> 2, sk = (lane & 3) * 16;
  const u16* aptr[2]; const u16* bptr[2];
#pragma unroll
  for (int i = 0; i < 2; ++i) {
    aptr[i] = A2 + (size_t)(m0 + (wv * 2 + i) * 16 + sr) * 2048;
    bptr[i] = Bt2 + (size_t)(n0 + (wv * 2 + i) * 16 + sr) * 2048;
  }
  auto STAGE = [&](int buf, int kk) {
    const int t = kk * 32;
    int ka, kb;
    if (t < 1024)      { ka = t;        kb = t; }
    else if (t < 2048) { ka = t;        kb = t - 1024; }
    else               { ka = t - 2048; kb = t - 1024; }
#pragma unroll
    for (int i = 0; i < 2; ++i) {
      gl_lds16((const char*)(aptr[i] + ka) + sk, (char*)As + buf * 8192 + (wv * 2 + i) * 1024);
      gl_lds16((const char*)(bptr[i] + kb) + sk, (char*)Bs + buf * 8192 + (wv * 2 + i) * 1024);
    }
  };
  f32x4 acc[4][4] = {};
  STAGE(0, kk0);
  __syncthreads();
  int cur = 0;
  for (int kk = kk0; kk < kk1; ++kk) {
    if (kk + 1 < kk1) STAGE(cur ^ 1, kk + 1);
    const u16* Ab = (const u16*)As + cur * 4096;
    const u16* Bb = (const u16*)Bs + cur * 4096;
    short8 a[4], bb[4];
#pragma unroll
    for (int i = 0; i < 4; ++i)
      a[i] = *(const short8*)(const void*)(Ab + (size_t)(wr * 64 + i * 16 + l15) * 32 + lg * 8);
#pragma unroll
    for (int j = 0; j < 4; ++j)
      bb[j] = *(const short8*)(const void*)(Bb + (size_t)(wc * 64 + j * 16 + l15) * 32 + lg * 8);
    __builtin_amdgcn_s_setprio(1);
#pragma unroll
    for (int i = 0; i < 4; ++i)
#pragma unroll
      for (int j = 0; j < 4; ++j) acc[i][j] = mfma16(a[i], bb[j], acc[i][j]);
    __builtin_amdgcn_s_setprio(0);
    __syncthreads();
    cur ^= 1;
  }
  float* P = Cpart + (size_t)ks * S * 3072;
#pragma unroll
  for (int i = 0; i < 4; ++i)
#pragma unroll
    for (int j = 0; j < 4; ++j)
#pragma unroll
      for (int r = 0; r < 4; ++r) {
        const int row = m0 + wr * 64 + i * 16 + lg * 4 + r;
        const int col = n0 + wc * 64 + j * 16 + l15;
        P[(size_t)row * 3072 + col] = acc[i][j][r];
      }
}

// ================================================= QKV combine: sum 2 planes + rope + hi/lo split
__global__ __launch_bounds__(256) void qkv_combine(const float* __restrict__ Cp,
    const float2* __restrict__ tab, u16* __restrict__ Ch, u16* __restrict__ Cl) {
  const int t = blockIdx.x, tid = threadIdx.x;
  const float* r0 = Cp + (size_t)t * 3072;
  const float* r1 = r0 + (size_t)S * 3072;
  const size_t ob = (size_t)t * 3072;
#pragma unroll
  for (int i = 0; i < 4; ++i) {  // q,k pairs
    const int pi = tid + i * 256;
    const int h = pi >> 5, p = pi & 31;
    const int col = h * 64 + p;
    const float x1 = r0[col] + r1[col];
    const float x2 = r0[col + 32] + r1[col + 32];
    const float2 cs = tab[t * 32 + p];
    const float y1 = x1 * cs.x - x2 * cs.y;
    const float y2 = x1 * cs.y + x2 * cs.x;
    const u16 h1 = f2bf(y1);
    Ch[ob + col] = h1; Cl[ob + col] = f2bf(y1 - bf2f(h1));
    const u16 h2 = f2bf(y2);
    Ch[ob + col + 32] = h2; Cl[ob + col + 32] = f2bf(y2 - bf2f(h2));
  }
#pragma unroll
  for (int i = 0; i < 4; ++i) {  // v
    const int col = 2048 + tid + i * 256;
    const float y = r0[col] + r1[col];
    const u16 h = f2bf(y);
    Ch[ob + col] = h; Cl[ob + col] = f2bf(y - bf2f(h));
  }
}

// ================================================= Wo GEMM: 128x128, split-bf16, dbuf, XCD-swz, Kx4
__global__ __launch_bounds__(256) void gemm_wo(const u16* __restrict__ A2,
    const u16* __restrict__ Bt2, float* __restrict__ Pout) {
  constexpr int N = 1024;
  __shared__ u16 As[2][128 * 32];
  __shared__ u16 Bs[2][128 * 32];
  const int b = blockIdx.x;
  const int xcd = b & 7, ii = b >> 3;
  const int n0 = xcd * 128;
  const int m0 = (ii & 15) * 128;
  const int ks = ii >> 4;
  const int kk0 = ks * 24, kk1 = kk0 + 24;
  const int tid = threadIdx.x, wv = tid >> 6, lane = tid & 63;
  const int l15 = lane & 15, lg = lane >> 4;
  const int wr = wv >> 1, wc = wv & 1;
  const int sr = lane >> 2, sk = (lane & 3) * 16;
  const u16* aptr[2]; const u16* bptr[2];
#pragma unroll
  for (int i = 0; i < 2; ++i) {
    aptr[i] = A2 + (size_t)(m0 + (wv * 2 + i) * 16 + sr) * 2048;
    bptr[i] = Bt2 + (size_t)(n0 + (wv * 2 + i) * 16 + sr) * 2048;
  }
  auto STAGE = [&](int buf, int kk) {
    const int t = kk * 32;
    int ka, kb;
    if (t < 1024)      { ka = t;        kb = t; }
    else if (t < 2048) { ka = t;        kb = t - 1024; }
    else               { ka = t - 2048; kb = t - 1024; }
#pragma unroll
    for (int i = 0; i < 2; ++i) {
      gl_lds16((const char*)(aptr[i] + ka) + sk, (char*)As + buf * 8192 + (wv * 2 + i) * 1024);
      gl_lds16((const char*)(bptr[i] + kb) + sk, (char*)Bs + buf * 8192 + (wv * 2 + i) * 1024);
    }
  };
  f32x4 acc[4][4] = {};
  STAGE(0, kk0);
  __syncthreads();
  int cur = 0;
  for (int kk = kk0; kk < kk1; ++kk) {
    if (kk + 1 < kk1) STAGE(cur ^ 1, kk + 1);
    const u16* Ab = (const u16*)As + cur * 4096;
    const u16* Bb = (const u16*)Bs + cur * 4096;
    short8 a[4], bb[4];
#pragma unroll
    for (int i = 0; i < 4; ++i)
      a[i] = *(const short8*)(const void*)(Ab + (size_t)(wr * 64 + i * 16 + l15) * 32 + lg * 8);
#pragma unroll
    for (int j = 0; j < 4; ++j)
      bb[j] = *(const short8*)(const void*)(Bb + (size_t)(wc * 64 + j * 16 + l15) * 32 + lg * 8);
    __builtin_amdgcn_s_setprio(1);
#pragma unroll
    for (int i = 0; i < 4; ++i)
#pragma unroll
      for (int j = 0; j < 4; ++j) acc[i][j] = mfma16(a[i], bb[j], acc[i][j]);
    __builtin_amdgcn_s_setprio(0);
    __syncthreads();
    cur ^= 1;
  }
  float* P = Pout + (size_t)ks * S * N;
#pragma unroll
  for (int i = 0; i < 4; ++i)
#pragma unroll
    for (int j = 0; j < 4; ++j)
#pragma unroll
      for (int r = 0; r < 4; ++r) {
        const int row = m0 + wr * 64 + i * 16 + lg * 4 + r;
        const int col = n0 + wc * 64 + j * 16 + l15;
        P[(size_t)row * N + col] = acc[i][j][r];
      }
}

// ================================================= MFMA flash attention: swapped QK^T, split-K x4,
// single-buffer K hi+lo in LDS, two-pass PV. 44KB LDS -> 3 blocks/CU. grid 2048
__global__ __launch_bounds__(256, 3) void attn_mfma(const u16* __restrict__ Qh,
    const u16* __restrict__ Ql, float* __restrict__ Opart, float2* __restrict__ ml) {
  const int b = blockIdx.x;
  const int head = (b & 7) + 8 * ((b >> 3) & 1);
  const int qb = 31 - ((b >> 4) & 31);
  const int sp = (b >> 9) & 3;
  const int q0 = qb * 64;
  const int ktiles = qb + 1;
  const int kbase = ktiles >> 2, krem = ktiles & 3;
  const int t0 = sp * kbase + (sp < krem ? sp : krem);
  const int t1 = t0 + kbase + (sp < krem ? 1 : 0);
  const int tid = threadIdx.x, w = tid >> 6, lane = tid & 63;
  const int l15 = lane & 15, lg = lane >> 4;
  __shared__ u16 Kh[64 * 64];
  __shared__ u16 Kl[64 * 64];
  __shared__ __align__(16) u16 Vth[64 * 72];
  __shared__ __align__(16) u16 Vtl[64 * 72];
  __shared__ __align__(16) u16 Pp[4][16 * 72];

  short8 qh[2], qlo[2];
  {
    const size_t qbase = (size_t)(q0 + w * 16 + l15) * 3072 + head * 64;
    qh[0]  = *(const short8*)(const void*)(Qh + qbase + lg * 8);
    qh[1]  = *(const short8*)(const void*)(Qh + qbase + 32 + lg * 8);
    qlo[0] = *(const short8*)(const void*)(Ql + qbase + lg * 8);
    qlo[1] = *(const short8*)(const void*)(Ql + qbase + 32 + lg * 8);
  }
  f32x4 oacc[4] = {};
  float m_run = -__builtin_inff(), l_run = 0.f;
  const int qrow0 = q0 + w * 16 + lg * 4;
  const int qcol  = q0 + w * 16 + l15;

  const int vhl = tid >> 7, rem = tid & 127;
  const int vkq = rem & 15, vdg = rem >> 4;
  const u16* vbase = (vhl ? Ql : Qh) + 2048 + head * 64 + vdg * 8;
  u16* vdst = vhl ? Vtl : Vth;
  short8 vr[4];

  auto STAGEK = [&](int kt) {
#pragma unroll
    for (int i = 0; i < 2; ++i) {
      const int inst = w * 2 + i;
      const int key = inst * 8 + (lane >> 3);
      const int db = ((lane & 7) * 16) ^ ((key & 7) << 4);
      gl_lds16((const char*)(Qh + (size_t)(kt * 64 + key) * 3072 + 1024 + head * 64) + db,
               (char*)Kh + inst * 1024);
      gl_lds16((const char*)(Ql + (size_t)(kt * 64 + key) * 3072 + 1024 + head * 64) + db,
               (char*)Kl + inst * 1024);
    }
  };
  auto VLOAD = [&](int kt) {
    const u16* vs = vbase + (size_t)(kt * 64 + vkq * 4) * 3072;
    vr[0] = *(const short8*)(const void*)vs;
    vr[1] = *(const short8*)(const void*)(vs + 3072);
    vr[2] = *(const short8*)(const void*)(vs + 6144);
    vr[3] = *(const short8*)(const void*)(vs + 9216);
  };
  auto VWRITE = [&]() {
#pragma unroll
    for (int jj = 0; jj < 8; ++jj) {
      const u64 pk = (u64)(u16)vr[0][jj] | ((u64)(u16)vr[1][jj] << 16) |
                     ((u64)(u16)vr[2][jj] << 32) | ((u64)(u16)vr[3][jj] << 48);
      *(u64*)(void*)(vdst + (vdg * 8 + jj) * 72 + vkq * 4) = pk;
    }
  };

  if (t0 < t1) {
    STAGEK(t0);
    VLOAD(t0);
    VWRITE();
    __syncthreads();
  }
  for (int t = t0; t < t1; ++t) {
    const int k0 = t * 64;
    const bool more = (t + 1 < t1);
    f32x4 sacc[4];
    __builtin_amdgcn_s_setprio(1);
#pragma unroll
    for (int nt = 0; nt < 4; ++nt) {
      const int key = nt * 16 + l15;
      const char* kbh = (const char*)Kh + key * 128;
      const char* kbl = (const char*)Kl + key * 128;
      const int sw = (key & 7) << 4;
      const short8 kh0 = *(const short8*)(const void*)(kbh + ((lg * 16) ^ sw));
      const short8 kh1 = *(const short8*)(const void*)(kbh + ((64 + lg * 16) ^ sw));
      const short8 kl0 = *(const short8*)(const void*)(kbl + ((lg * 16) ^ sw));
      const short8 kl1 = *(const short8*)(const void*)(kbl + ((64 + lg * 16) ^ sw));
      f32x4 s = {};
      s = mfma16(kh0, qh[0], s);  s = mfma16(kh1, qh[1], s);
      s = mfma16(kh0, qlo[0], s); s = mfma16(kh1, qlo[1], s);
      s = mfma16(kl0, qh[0], s);  s = mfma16(kl1, qh[1], s);
      sacc[nt] = s;
    }
    __builtin_amdgcn_s_setprio(0);
    __syncthreads();                  // B1: K reads done
    if (more) { STAGEK(t + 1); VLOAD(t + 1); }
#pragma unroll
    for (int nt = 0; nt < 4; ++nt)
#pragma unroll
      for (int r = 0; r < 4; ++r) sacc[nt][r] *= SCL2;
    if (t == qb) {
#pragma unroll
      for (int nt = 0; nt < 4; ++nt) {
        const int keyb = k0 + nt * 16 + lg * 4;
#pragma unroll
        for (int r = 0; r < 4; ++r)
          if (keyb + r > qcol) sacc[nt][r] = -__builtin_inff();
      }
    }
    float mx = sacc[0][0];
#pragma unroll
    for (int nt = 0; nt < 4; ++nt)
#pragma unroll
      for (int r = 0; r < 4; ++r) mx = fmaxf(mx, sacc[nt][r]);
    mx = fmaxf(mx, __shfl_xor(mx, 16, 64));
    mx = fmaxf(mx, __shfl_xor(mx, 32, 64));
    const bool grow = mx > m_run + 8.f;
    if (__any(grow)) {
      const float m_new = fmaxf(m_run, mx);
      const float fac = __builtin_amdgcn_exp2f(m_run - m_new);
      m_run = m_new;
      l_run *= fac;
      float facB[4];
#pragma unroll
      for (int r = 0; r < 4; ++r) facB[r] = __shfl(fac, lg * 4 + r, 64);
#pragma unroll
      for (int nd = 0; nd < 4; ++nd)
#pragma unroll
        for (int r = 0; r < 4; ++r) oacc[nd][r] *= facB[r];
    }
    float ls = 0.f;
#pragma unroll
    for (int nt = 0; nt < 4; ++nt)
#pragma unroll
      for (int r = 0; r < 4; ++r) {
        sacc[nt][r] = __builtin_amdgcn_exp2f(sacc[nt][r] - m_run);
        ls += sacc[nt][r];
      }
    ls += __shfl_xor(ls, 16, 64);
    ls += __shfl_xor(ls, 32, 64);
    l_run += ls;
    u16* prow = &Pp[w][l15 * 72];
#pragma unroll
    for (int nt = 0; nt < 4; ++nt) {
      const u64 pk = (u64)(__float_as_uint(sacc[nt][0]) >> 16) |
                     ((u64)(__float_as_uint(sacc[nt][1]) >> 16) << 16) |
                     ((u64)(__float_as_uint(sacc[nt][2]) >> 16) << 32) |
                     ((u64)(__float_as_uint(sacc[nt][3]) >> 16) << 48);
      *(u64*)(void*)(prow + nt * 16 + lg * 4) = pk;
    }
    __builtin_amdgcn_s_setprio(1);
#pragma unroll
    for (int kk2 = 0; kk2 < 2; ++kk2) {
      const short8 pa = *(const short8*)(const void*)((const char*)prow + kk2 * 64 + lg * 16);
#pragma unroll
      for (int nd = 0; nd < 4; ++nd) {
        const short8 vbh = *(const short8*)(const void*)((const char*)Vth + (nd * 16 + l15) * 144 + kk2 * 64 + lg * 16);
        const short8 vbl = *(const short8*)(const void*)((const char*)Vtl + (nd * 16 + l15) * 144 + kk2 * 64 + lg * 16);
        oacc[nd] = mfma16(pa, vbh, oacc[nd]);
        oacc[nd] = mfma16(pa, vbl, oacc[nd]);
      }
    }
    __builtin_amdgcn_s_setprio(0);
    asm volatile("" ::: "memory");
#pragma unroll
    for (int nt = 0; nt < 4; ++nt) {
      float lo[4];
#pragma unroll
      for (int r = 0; r < 4; ++r)
        lo[r] = sacc[nt][r] - __uint_as_float(__float_as_uint(sacc[nt][r]) & 0xFFFF0000u);
      const u64 pk = (u64)(__float_as_uint(lo[0]) >> 16) |
                     ((u64)(__float_as_uint(lo[1]) >> 16) << 16) |
                     ((u64)(__float_as_uint(lo[2]) >> 16) << 32) |
                     ((u64)(__float_as_uint(lo[3]) >> 16) << 48);
      *(u64*)(void*)(prow + nt * 16 + lg * 4) = pk;
    }
    asm volatile("" ::: "memory");
    __builtin_amdgcn_s_setprio(1);
#pragma unroll
    for (int kk2 = 0; kk2 < 2; ++kk2) {
      const short8 pa = *(const short8*)(const void*)((const char*)prow + kk2 * 64 + lg * 16);
#pragma unroll
      for (int nd = 0; nd < 4; ++nd) {
        const short8 vbh = *(const short8*)(const void*)((const char*)Vth + (nd * 16 + l15) * 144 + kk2 * 64 + lg * 16);
        oacc[nd] = mfma16(pa, vbh, oacc[nd]);
      }
    }
    __builtin_amdgcn_s_setprio(0);
    __syncthreads();                  // B2
    if (more) VWRITE();
  }
  float* Op = Opart + (size_t)sp * S * 1024;
#pragma unroll
  for (int nd = 0; nd < 4; ++nd)
#pragma unroll
    for (int r = 0; r < 4; ++r)
      Op[(size_t)(qrow0 + r) * 1024 + head * 64 + nd * 16 + l15] = oacc[nd][r];
  if (lg == 0) {
    ml[((size_t)sp * S + q0 + w * 16 + l15) * NH + head] = make_float2(m_run, l_run);
  }
}

// ================================================= combine 4 split-K attention partials
__global__ __launch_bounds__(256) void attn_combine(const float* __restrict__ Op,
    const float2* __restrict__ ml, u16* __restrict__ OA2) {
  const int t = blockIdx.x, tid = threadIdx.x;
  const int h = tid >> 4, dq = (tid & 15) * 4;
  float2 a[4];
  float M = -__builtin_inff();
#pragma unroll
  for (int c = 0; c < 4; ++c) {
    a[c] = ml[((size_t)c * S + t) * NH + h];
    if (a[c].y > 0.f) M = fmaxf(M, a[c].x);
  }
  float e[4], denom = 0.f;
#pragma unroll
  for (int c = 0; c < 4; ++c) {
    e[c] = (a[c].y > 0.f) ? exp2f(a[c].x - M) : 0.f;
    denom += e[c] * a[c].y;
  }
  const float inv = 1.f / denom;
  float ov[4] = {0.f, 0.f, 0.f, 0.f};
#pragma unroll
  for (int c = 0; c < 4; ++c) {
    const float4 v = *(const float4*)(Op + ((size_t)c * S + t) * 1024 + h * 64 + dq);
    ov[0] += e[c] * v.x; ov[1] += e[c] * v.y; ov[2] += e[c] * v.z; ov[3] += e[c] * v.w;
  }
#pragma unroll
  for (int c2 = 0; c2 < 4; ++c2) {
    const float o = ov[c2] * inv;
    const size_t idx = (size_t)t * 2048 + h * 64 + dq + c2;
    const u16 hb = f2bf(o);
    OA2[idx] = hb;
    OA2[idx + 1024] = f2bf(o - bf2f(hb));
  }
}

// ================================================= res2 (4 partials) + rmsnorm2 + gate (no atomics)
__global__ __launch_bounds__(256) void rmsnorm_res2_gate(const float* __restrict__ hidden,
    const float* __restrict__ p01, const float* __restrict__ w2, const float* __restrict__ GW,
    float* __restrict__ out, u16* __restrict__ yb,
    int* __restrict__ top2, float2* __restrict__ topw) {
  const int t = blockIdx.x;
  const int d0 = threadIdx.x * 4;
  const size_t base = (size_t)t * D + d0;
  const float4 h4 = *(const float4*)(hidden + base);
  const float4 a4 = *(const float4*)(p01 + base);
  const float4 b4 = *(const float4*)(p01 + (size_t)S * D + base);
  const float4 c4 = *(const float4*)(p01 + 2 * (size_t)S * D + base);
  const float4 e4 = *(const float4*)(p01 + 3 * (size_t)S * D + base);
  float v[4] = {h4.x + a4.x + b4.x + c4.x + e4.x, h4.y + a4.y + b4.y + c4.y + e4.y,
                h4.z + a4.z + b4.z + c4.z + e4.z, h4.w + a4.w + b4.w + c4.w + e4.w};
  float ss = v[0] * v[0] + v[1] * v[1] + v[2] * v[2] + v[3] * v[3];
#pragma unroll
  for (int m = 32; m >= 1; m >>= 1) ss += __shfl_xor(ss, m, 64);
  __shared__ float red[4];
  if ((threadIdx.x & 63) == 0) red[threadIdx.x >> 6] = ss;
  __syncthreads();
  const float rs = rsqrtf((red[0] + red[1] + red[2] + red[3]) * (1.f / (float)D) + EPS);
  const float4 w4 = *(const float4*)(w2 + d0);
  const float y[4] = {v[0] * rs * w4.x, v[1] * rs * w4.y, v[2] * rs * w4.z, v[3] * rs * w4.w};
  *(float4*)(out + base) = make_float4(v[0], v[1], v[2], v[3]);
  *(u64*)(void*)(yb + base) = pack4bf(y[0], y[1], y[2], y[3]);
  float lg[8] = {};
#pragma unroll
  for (int j = 0; j < 4; ++j) {
    const float4 g0 = *(const float4*)(GW + (d0 + j) * 8);
    const float4 g1 = *(const float4*)(GW + (d0 + j) * 8 + 4);
    lg[0] += y[j] * g0.x; lg[1] += y[j] * g0.y; lg[2] += y[j] * g0.z; lg[3] += y[j] * g0.w;
    lg[4] += y[j] * g1.x; lg[5] += y[j] * g1.y; lg[6] += y[j] * g1.z; lg[7] += y[j] * g1.w;
  }
#pragma unroll
  for (int e = 0; e < 8; ++e)
#pragma unroll
    for (int m = 32; m >= 1; m >>= 1) lg[e] += __shfl_xor(lg[e], m, 64);
  __shared__ float wred[4][8];
  if ((threadIdx.x & 63) == 0)
#pragma unroll
    for (int e = 0; e < 8; ++e) wred[threadIdx.x >> 6][e] = lg[e];
  __syncthreads();
  if (threadIdx.x == 0) {
    float L[8];
#pragma unroll
    for (int e = 0; e < 8; ++e) L[e] = wred[0][e] + wred[1][e] + wred[2][e] + wred[3][e];
    int i0 = 0; float v0 = L[0];
    for (int i = 1; i < 8; ++i) if (L[i] > v0) { v0 = L[i]; i0 = i; }
    int i1 = -1; float v1 = -__builtin_inff();
    for (int i = 0; i < 8; ++i) if (i != i0 && L[i] > v1) { v1 = L[i]; i1 = i; }
    const float e1 = expf(v1 - v0);
    const float inv = 1.f / (1.f + e1);
    top2[t] = i0 | (i1 << 4);
    topw[t] = make_float2(inv, e1 * inv);
  }
}

// ================================================= scatter compact: deterministic prefix-scan
__global__ __launch_bounds__(1024) void scatter_compact(const int* __restrict__ top2,
    const float2* __restrict__ topw, int* __restrict__ counts,
    int* __restrict__ tok_map, float* __restrict__ w_map) {
  const int tid = threadIdx.x;
  __shared__ u64 s0[1024], s1[1024];
  int e_[2][2]; float w_[2][2];
  u64 c0 = 0, c1 = 0;
#pragma unroll
  for (int k = 0; k < 2; ++k) {
    const int t = tid * 2 + k;
    const int pk = top2[t];
    const float2 wv = topw[t];
    e_[k][0] = pk & 15; e_[k][1] = (pk >> 4) & 15;
    w_[k][0] = wv.x;    w_[k][1] = wv.y;
#pragma unroll
    for (int s = 0; s < 2; ++s) {
      const int e = e_[k][s];
      if (e < 4) c0 += 1ull << (e * 16); else c1 += 1ull << ((e - 4) * 16);
    }
  }
  s0[tid] = c0; s1[tid] = c1;
  __syncthreads();
  for (int off = 1; off < 1024; off <<= 1) {
    const u64 a0 = (tid >= off) ? s0[tid - off] : 0;
    const u64 a1 = (tid >= off) ? s1[tid - off] : 0;
    __syncthreads();
    s0[tid] += a0; s1[tid] += a1;
    __syncthreads();
  }
  if (tid == 1023) {
#pragma unroll
    for (int e = 0; e < 4; ++e) counts[e] = (int)((s0[1023] >> (e * 16)) & 0xFFFF);
#pragma unroll
    for (int e = 4; e < 8; ++e) counts[e] = (int)((s1[1023] >> ((e - 4) * 16)) & 0xFFFF);
  }
  u64 l0 = s0[tid] - c0, l1 = s1[tid] - c1;
#pragma unroll
  for (int k = 0; k < 2; ++k) {
    const int t = tid * 2 + k;
#pragma unroll
    for (int s = 0; s < 2; ++s) {
      const int e = e_[k][s];
      int p;
      if (e < 4) { p = (int)((l0 >> (e * 16)) & 0xFFFF); l0 += 1ull << (e * 16); }
      else       { p = (int)((l1 >> ((e - 4) * 16)) & 0xFFFF); l1 += 1ull << ((e - 4) * 16); }
      tok_map[e * S + p] = t | (s << 16);
      w_map[e * S + p] = w_[k][s];
    }
  }
}

// ================================================= MoE gate/up GEMM: 128x64 tile, dual-B, dbuf
__global__ __launch_bounds__(256) void moe_gu(const u16* __restrict__ Yb,
    const u16* __restrict__ Wgb, const u16* __restrict__ Wub, u16* __restrict__ Hb,
    const int* __restrict__ counts, const int* __restrict__ tokmap) {
  const int b = blockIdx.x;
  const int e = b & 7, ii = b >> 3;
  const int n0 = (ii & 15) * 64;
  const int m0 = (ii >> 4) * 128;
  const int cnt = counts[e];
  if (m0 >= cnt) return;
  __shared__ u16 SH[2][16 * 512];
  const int tid = threadIdx.x, wv = tid >> 6, lane = tid & 63;
  const int l15 = lane & 15, lg = lane >> 4;
  const int wr = wv >> 1, wc = wv & 1;
  const int sr = lane >> 2, sk = (lane & 3) * 16;
  const u16* B1 = Wgb + (size_t)e * 1048576;
  const u16* B2 = Wub + (size_t)e * 1048576;
  const u16* cp[4];
#pragma unroll
  for (int i = 0; i < 4; ++i) {
    const int c = wv * 4 + i;
    if (c < 8) {
      const int arow = m0 + c * 16 + sr;
      const int tok = tokmap[e * S + arow] & 2047;
      cp[i] = Yb + (size_t)tok * 1024;
    } else if (c < 12) {
      cp[i] = B1 + (size_t)(n0 + (c - 8) * 16 + sr) * 1024;
    } else {
      cp[i] = B2 + (size_t)(n0 + (c - 12) * 16 + sr) * 1024;
    }
  }
  auto STAGE = [&](int buf, int k) {
#pragma unroll
    for (int i = 0; i < 4; ++i) {
      const int c = wv * 4 + i;
      gl_lds16((const char*)(cp[i] + k) + sk, (char*)SH + buf * 16384 + c * 1024);
    }
  };
  f32x4 acc1[4][2] = {};
  f32x4 acc2[4][2] = {};
  STAGE(0, 0);
  __syncthreads();
  int cur = 0;
  for (int kk = 0; kk < 32; ++kk) {
    if (kk < 31) STAGE(cur ^ 1, (kk + 1) * 32);
    const u16* Sb = (const u16*)SH + cur * 8192;
    short8 a[4], b1f[2], b2f[2];
#pragma unroll
    for (int i = 0; i < 4; ++i)
      a[i] = *(const short8*)(const void*)(Sb + (size_t)(wr * 64 + i * 16 + l15) * 32 + lg * 8);
#pragma unroll
    for (int j = 0; j < 2; ++j) {
      b1f[j] = *(const short8*)(const void*)(Sb + 4096 + (size_t)(wc * 32 + j * 16 + l15) * 32 + lg * 8);
      b2f[j] = *(const short8*)(const void*)(Sb + 6144 + (size_t)(wc * 32 + j * 16 + l15) * 32 + lg * 8);
    }
    __builtin_amdgcn_s_setprio(1);
#pragma unroll
    for (int i = 0; i < 4; ++i)
#pragma unroll
      for (int j = 0; j < 2; ++j) {
        acc1[i][j] = mfma16(a[i], b1f[j], acc1[i][j]);
        acc2[i][j] = mfma16(a[i], b2f[j], acc2[i][j]);
      }
    __builtin_amdgcn_s_setprio(0);
    __syncthreads();
    cur ^= 1;
  }
#pragma unroll
  for (int i = 0; i < 4; ++i)
#pragma unroll
    for (int j = 0; j < 2; ++j)
#pragma unroll
      for (int r = 0; r < 4; ++r) {
        const int row = m0 + wr * 64 + i * 16 + lg * 4 + r;
        if (row < cnt) {
          const float g = acc1[i][j][r];
          const float u = acc2[i][j][r];
          const float sig = __builtin_amdgcn_rcpf(1.f + __builtin_amdgcn_exp2f(-g * LOG2E));
          Hb[((size_t)e * 2048 + row) * 1024 + n0 + wc * 32 + j * 16 + l15] = f2bf(u * g * sig);
        }
      }
}

// ================================================= MoE down GEMM: split-K x2 -> 4 bf16 slot planes
__global__ __launch_bounds__(256) void moe_down(const u16* __restrict__ Hb,
    const u16* __restrict__ Wdb, u16* __restrict__ slotp,
    const int* __restrict__ counts, const int* __restrict__ tokmap,
    const float* __restrict__ wmap) {
  const int b = blockIdx.x;
  const int e = b & 7, ii = b >> 3;
  const int m0 = (ii & 15) * 128;
  const int n0 = ((ii >> 4) & 7) * 128;
  const int ks = ii >> 7;
  const int cnt = counts[e];
  if (m0 >= cnt) return;
  __shared__ u16 As[2][128 * 32];
  __shared__ u16 Bs[2][128 * 32];
  const int tid = threadIdx.x, wv = tid >> 6, lane = tid & 63;
  const int l15 = lane & 15, lg = lane >> 4;
  const int wr = wv >> 1, wc = wv & 1;
  const int sr = lane >> 2, sk = (lane & 3) * 16;
  const u16* B = Wdb + (size_t)e * 1048576;
  const u16* aptr[2]; const u16* bptr[2];
#pragma unroll
  for (int i = 0; i < 2; ++i) {
    aptr[i] = Hb + ((size_t)e * 2048 + m0 + (wv * 2 + i) * 16 + sr) * 1024;
    bptr[i] = B + (size_t)(n0 + (wv * 2 + i) * 16 + sr) * 1024;
  }
  auto STAGE = [&](int buf, int k) {
#pragma unroll
    for (int i = 0; i < 2; ++i) {
      gl_lds16((const char*)(aptr[i] + k) + sk, (char*)As + buf * 8192 + (wv * 2 + i) * 1024);
      gl_lds16((const char*)(bptr[i] + k) + sk, (char*)Bs + buf * 8192 + (wv * 2 + i) * 1024);
    }
  };
  f32x4 acc[4][4] = {};
  const int kb0 = ks * 16, kb1 = kb0 + 16;
  STAGE(0, kb0 * 32);
  __syncthreads();
  int cur = 0;
  for (int kk = kb0; kk < kb1; ++kk) {
    if (kk + 1 < kb1) STAGE(cur ^ 1, (kk + 1) * 32);
    const u16* Ab = (const u16*)As + cur * 4096;
    const u16* Bb = (const u16*)Bs + cur * 4096;
    short8 a[4], bb[4];
#pragma unroll
    for (int i = 0; i < 4; ++i)
      a[i] = *(const short8*)(const void*)(Ab + (size_t)(wr * 64 + i * 16 + l15) * 32 + lg * 8);
#pragma unroll
    for (int j = 0; j < 4; ++j)
      bb[j] = *(const short8*)(const void*)(Bb + (size_t)(wc * 64 + j * 16 + l15) * 32 + lg * 8);
    __builtin_amdgcn_s_setprio(1);
#pragma unroll
    for (int i = 0; i < 4; ++i)
#pragma unroll
      for (int j = 0; j < 4; ++j) acc[i][j] = mfma16(a[i], bb[j], acc[i][j]);
    __builtin_amdgcn_s_setprio(0);
    __syncthreads();
    cur ^= 1;
  }
#pragma unroll
  for (int i = 0; i < 4; ++i)
#pragma unroll
    for (int j = 0; j < 4; ++j)
#pragma unroll
      for (int r = 0; r < 4; ++r) {
        const int row = m0 + wr * 64 + i * 16 + lg * 4 + r;
        if (row < cnt) {
          const int raw = tokmap[e * S + row];
          const int t = raw & 2047;
          const int sl = (raw >> 16) & 1;
          const float wgt = wmap[e * S + row];
          slotp[((size_t)(sl * 2 + ks) * S + t) * 1024 + n0 + wc * 64 + j * 16 + l15] =
              f2bf(wgt * acc[i][j][r]);
        }
      }
}

// ================================================= final add: out += sum of 4 slot planes
__global__ __launch_bounds__(256) void final_add(float* __restrict__ out,
    const u16* __restrict__ sp) {
  const size_t i = ((size_t)blockIdx.x * 256 + threadIdx.x) * 4;
  float4 o = *(float4*)(out + i);
#pragma unroll
  for (int c = 0; c < 4; ++c) {
    const u64 a = *(const u64*)(sp + (size_t)c * S * D + i);
    o.x += bf2f((u16)(a));
    o.y += bf2f((u16)(a >> 16));
    o.z += bf2f((u16)(a >> 32));
    o.w += bf2f((u16)(a >> 48));
  }
  *(float4*)(out + i) = o;
}

// ================================================= launch
extern "C" void kernel_launch(void* const* d_in, const int* in_sizes, int n_in,
                              void* d_out, int out_size, void* d_ws, size_t ws_size,
                              hipStream_t stream) {
  const int*   positions = (const int*)d_in[0];
  const float* hidden    = (const float*)d_in[1];
  const float* ln1_w  = (const float*)d_in[3];
  const float* ln2_w  = (const float*)d_in[4];
  const float* wqkv   = (const float*)d_in[5];
  const float* wo     = (const float*)d_in[6];
  const float* gate_w = (const float*)d_in[7];
  const float* wg     = (const float*)d_in[8];
  const float* wu     = (const float*)d_in[9];
  const float* wd     = (const float*)d_in[10];
  float* out = (float*)d_out;

  char* ws = (char*)d_ws;
  const size_t MB = 1ull << 20;
  u16* wqkvT2 = (u16*)(ws);
  u16* QKVh   = (u16*)(ws);
  u16* OA2    = (u16*)(ws);
  u16* woT2   = (u16*)(ws + 12 * MB);       // 4MB
  u16* wgT    = (u16*)(ws + 16 * MB);       // 16MB
  u16* wuT    = (u16*)(ws + 32 * MB);       // 16MB
  u16* wdT    = (u16*)(ws + 48 * MB);       // 16MB
  float2* ropetab = (float2*)(ws + 64 * MB);            // 512KB
  float2* ml      = (float2*)(ws + 64 * MB + 524288);   // 1MB
  char* mapb = ws + 64 * MB + 1572864;
  int*   counts   = (int*)mapb;
  int*   tok_map  = (int*)(mapb + 512);
  float* w_map    = (float*)(mapb + 512 + 65536);
  int*   top2     = (int*)(mapb + 512 + 131072);
  float2* topw    = (float2*)(mapb + 512 + 139264);
  u16* xn2    = (u16*)(ws + 66 * MB);       // 8MB  (ph1-2)
  u16* QKVl   = (u16*)(ws + 66 * MB);       // 12MB (ph3-4, xn2 dead)
  u16* yb     = (u16*)(ws + 66 * MB);       // 4MB  (ph6+, QKVl dead)
  float* Cpart  = (float*)(ws + 78 * MB);   // 48MB (ph2-3)
  float* Opart  = (float*)(ws + 78 * MB);   // 32MB (ph4, Cpart dead)
  float* p01    = (float*)(ws + 78 * MB);   // 32MB (ph5-6)
  u16* Hb     = (u16*)(ws + 78 * MB);       // 32MB (ph7)
  u16* slotp  = (u16*)(ws + 110 * MB);      // 16MB (ph7-8)

  prep_kernel<<<9472, 256, 0, stream>>>(wqkv, wo, wg, wu, wd, positions, hidden, ln1_w,
                                        wqkvT2, woT2, wgT, wuT, wdT, ropetab, xn2);
  gemm_qkv<<<768, 256, 0, stream>>>(xn2, wqkvT2, Cpart);
  qkv_combine<<<S, 256, 0, stream>>>(Cpart, ropetab, QKVh, QKVl);
  attn_mfma<<<2048, 256, 0, stream>>>(QKVh, QKVl, Opart, ml);
  attn_combine<<<S, 256, 0, stream>>>(Opart, ml, OA2);
  gemm_wo<<<512, 256, 0, stream>>>(OA2, woT2, p01);
  rmsnorm_res2_gate<<<S, 256, 0, stream>>>(hidden, p01, ln2_w, gate_w, out, yb, top2, topw);
  scatter_compact<<<1, 1024, 0, stream>>>(top2, topw, counts, tok_map, w_map);
  moe_gu<<<2048, 256, 0, stream>>>(yb, wgT, wuT, Hb, counts, tok_map);
  moe_down<<<2048, 256, 0, stream>>>(Hb, wdT, slotp, counts, tok_map, w_map);
  final_add<<<2048, 256, 0, stream>>>(out, slotp);
}

// Round 16
// 268.324 us; speedup vs baseline: 1.0510x; 1.0362x over previous
//
#include <hip/hip_runtime.h>
#include <math.h>

constexpr int S  = 2048;
constexpr int D  = 1024;
constexpr int NH = 16;
constexpr int NE = 8;
constexpr float EPS   = 1e-6f;
constexpr float THETA = 10000.0f;
constexpr float SCL2  = 0.125f * 1.4426950408889634f;  // attn scale * log2(e)
constexpr float LOG2E = 1.4426950408889634f;

typedef unsigned short u16;
typedef unsigned int   u32;
typedef unsigned long long u64;
typedef __attribute__((ext_vector_type(8))) short short8;
typedef __attribute__((ext_vector_type(4))) float f32x4;

__device__ __forceinline__ u16 f2bf(float x) {
  union { float f; u32 u; } v; v.f = x;
  u32 r = (v.u + 0x7FFFu + ((v.u >> 16) & 1u)) >> 16;
  return (u16)r;
}
__device__ __forceinline__ float bf2f(u16 h) {
  union { u32 u; float f; } v; v.u = ((u32)h) << 16;
  return v.f;
}
__device__ __forceinline__ f32x4 mfma16(short8 a, short8 b, f32x4 c) {
  return __builtin_amdgcn_mfma_f32_16x16x32_bf16(a, b, c, 0, 0, 0);
}
__device__ __forceinline__ void gl_lds16(const void* g, void* l) {
  __builtin_amdgcn_global_load_lds((const __attribute__((address_space(1))) u32*)g,
                                   (__attribute__((address_space(3))) u32*)l, 16, 0, 0);
}
__device__ __forceinline__ u64 pack4bf(float a, float b, float c, float d) {
  return (u64)f2bf(a) | ((u64)f2bf(b) << 16) | ((u64)f2bf(c) << 32) | ((u64)f2bf(d) << 48);
}

// ================================================= prep_early: wqkv transpose + rope + rmsnorm
// [0,768): wqkv split-T; [768,1024): rope tab; [1024,3072): rmsnorm_split rows
__global__ __launch_bounds__(256) void prep_early(const float* __restrict__ wqkv,
    const int* __restrict__ positions, const float* __restrict__ hidden,
    const float* __restrict__ ln1_w, u16* __restrict__ wqkvT2,
    float2* __restrict__ ropetab, u16* __restrict__ xn2) {
  const int b = blockIdx.x;
  const int tid = threadIdx.x;
  if (b >= 1024) {  // rmsnorm_split
    const int t = b - 1024;
    const float* xr = hidden + (size_t)t * D;
    float v[4]; float ss = 0.f;
#pragma unroll
    for (int i = 0; i < 4; ++i) { v[i] = xr[tid + i * 256]; ss += v[i] * v[i]; }
#pragma unroll
    for (int m = 32; m >= 1; m >>= 1) ss += __shfl_xor(ss, m, 64);
    __shared__ float red[4];
    if ((tid & 63) == 0) red[tid >> 6] = ss;
    __syncthreads();
    const float rs = rsqrtf((red[0] + red[1] + red[2] + red[3]) * (1.f / (float)D) + EPS);
#pragma unroll
    for (int i = 0; i < 4; ++i) {
      const int d = tid + i * 256;
      const float y = v[i] * rs * ln1_w[d];
      const u16 h = f2bf(y);
      xn2[(size_t)t * 2048 + d] = h;
      xn2[(size_t)t * 2048 + 1024 + d] = f2bf(y - bf2f(h));
    }
    return;
  }
  if (b >= 768) {  // rope table
    const int idx = (b - 768) * 256 + tid;
    const int t = idx >> 5, p = idx & 31;
    const float inv = powf(THETA, -(float)p * (1.f / 32.f));
    const float fr = (float)positions[t] * inv;
    float sn, cs; sincosf(fr, &sn, &cs);
    ropetab[idx] = make_float2(cs, sn);
    return;
  }
  // wqkv split-transpose: W[1024][3072] -> wqkvT2[3072][2048] (hi|lo)
  __shared__ float t_[64][65];
  const int n0 = (b % 48) * 64, k0 = (b / 48) * 64;
  const int rr = tid >> 4, c4 = (tid & 15) * 4;
#pragma unroll
  for (int i = 0; i < 4; ++i) {
    const float4 v = *(const float4*)(wqkv + (size_t)(k0 + rr + i * 16) * 3072 + n0 + c4);
    t_[rr + i * 16][c4 + 0] = v.x; t_[rr + i * 16][c4 + 1] = v.y;
    t_[rr + i * 16][c4 + 2] = v.z; t_[rr + i * 16][c4 + 3] = v.w;
  }
  __syncthreads();
#pragma unroll
  for (int i = 0; i < 4; ++i) {
    const int n = n0 + rr + i * 16;
    u16* oh = wqkvT2 + (size_t)n * 2048 + k0 + c4;
    const float v0 = t_[c4 + 0][rr + i * 16], v1 = t_[c4 + 1][rr + i * 16];
    const float v2 = t_[c4 + 2][rr + i * 16], v3 = t_[c4 + 3][rr + i * 16];
    *(u64*)(void*)oh = pack4bf(v0, v1, v2, v3);
    *(u64*)(void*)(oh + 1024) = pack4bf(v0 - bf2f(f2bf(v0)), v1 - bf2f(f2bf(v1)),
                                        v2 - bf2f(f2bf(v2)), v3 - bf2f(f2bf(v3)));
  }
}

// ================================================= QKV GEMM: 128x128, split-bf16, dbuf, XCD-swz,
// split-K x2 -> f32 partial planes (plain stores). grid 768
__global__ __launch_bounds__(256) void gemm_qkv(const u16* __restrict__ A2,
    const u16* __restrict__ Bt2, float* __restrict__ Cpart) {
  __shared__ u16 As[2][128 * 32];
  __shared__ u16 Bs[2][128 * 32];
  const int b = blockIdx.x;
  const int xcd = b & 7, ii = b >> 3;
  const int m0 = (ii & 15) * 128;
  const int np = (ii >> 4) % 3, ks = (ii >> 4) / 3;
  const int n0 = (xcd * 3 + np) * 128;
  const int kk0 = ks * 48, kk1 = kk0 + 48;
  const int tid = threadIdx.x, wv = tid >> 6, lane = tid & 63;
  const int l15 = lane & 15, lg = lane >> 4;
  const int wr = wv >> 1, wc = wv & 1;
  const int sr = lane >> 2, sk = (lane & 3) * 16;
  const u16* aptr[2]; const u16* bptr[2];
#pragma unroll
  for (int i = 0; i < 2; ++i) {
    aptr[i] = A2 + (size_t)(m0 + (wv * 2 + i) * 16 + sr) * 2048;
    bptr[i] = Bt2 + (size_t)(n0 + (wv * 2 + i) * 16 + sr) * 2048;
  }
  auto STAGE = [&](int buf, int kk) {
    const int t = kk * 32;
    int ka, kb;
    if (t < 1024)      { ka = t;        kb = t; }
    else if (t < 2048) { ka = t;        kb = t - 1024; }
    else               { ka = t - 2048; kb = t - 1024; }
#pragma unroll
    for (int i = 0; i < 2; ++i) {
      gl_lds16((const char*)(aptr[i] + ka) + sk, (char*)As + buf * 8192 + (wv * 2 + i) * 1024);
      gl_lds16((const char*)(bptr[i] + kb) + sk, (char*)Bs + buf * 8192 + (wv * 2 + i) * 1024);
    }
  };
  f32x4 acc[4][4] = {};
  STAGE(0, kk0);
  __syncthreads();
  int cur = 0;
  for (int kk = kk0; kk < kk1; ++kk) {
    if (kk + 1 < kk1) STAGE(cur ^ 1, kk + 1);
    const u16* Ab = (const u16*)As + cur * 4096;
    const u16* Bb = (const u16*)Bs + cur * 4096;
    short8 a[4], bb[4];
#pragma unroll
    for (int i = 0; i < 4; ++i)
      a[i] = *(const short8*)(const void*)(Ab + (size_t)(wr * 64 + i * 16 + l15) * 32 + lg * 8);
#pragma unroll
    for (int j = 0; j < 4; ++j)
      bb[j] = *(const short8*)(const void*)(Bb + (size_t)(wc * 64 + j * 16 + l15) * 32 + lg * 8);
    __builtin_amdgcn_s_setprio(1);
#pragma unroll
    for (int i = 0; i < 4; ++i)
#pragma unroll
      for (int j = 0; j < 4; ++j) acc[i][j] = mfma16(a[i], bb[j], acc[i][j]);
    __builtin_amdgcn_s_setprio(0);
    __syncthreads();
    cur ^= 1;
  }
  float* P = Cpart + (size_t)ks * S * 3072;
#pragma unroll
  for (int i = 0; i < 4; ++i)
#pragma unroll
    for (int j = 0; j < 4; ++j)
#pragma unroll
      for (int r = 0; r < 4; ++r) {
        const int row = m0 + wr * 64 + i * 16 + lg * 4 + r;
        const int col = n0 + wc * 64 + j * 16 + l15;
        P[(size_t)row * 3072 + col] = acc[i][j][r];
      }
}

// ================================================= QKV combine: sum 2 planes + rope + hi/lo split
__global__ __launch_bounds__(256) void qkv_combine(const float* __restrict__ Cp,
    const float2* __restrict__ tab, u16* __restrict__ Ch, u16* __restrict__ Cl) {
  const int t = blockIdx.x, tid = threadIdx.x;
  const float* r0 = Cp + (size_t)t * 3072;
  const float* r1 = r0 + (size_t)S * 3072;
  const size_t ob = (size_t)t * 3072;
#pragma unroll
  for (int i = 0; i < 4; ++i) {  // q,k pairs
    const int pi = tid + i * 256;
    const int h = pi >> 5, p = pi & 31;
    const int col = h * 64 + p;
    const float x1 = r0[col] + r1[col];
    const float x2 = r0[col + 32] + r1[col + 32];
    const float2 cs = tab[t * 32 + p];
    const float y1 = x1 * cs.x - x2 * cs.y;
    const float y2 = x1 * cs.y + x2 * cs.x;
    const u16 h1 = f2bf(y1);
    Ch[ob + col] = h1; Cl[ob + col] = f2bf(y1 - bf2f(h1));
    const u16 h2 = f2bf(y2);
    Ch[ob + col + 32] = h2; Cl[ob + col + 32] = f2bf(y2 - bf2f(h2));
  }
#pragma unroll
  for (int i = 0; i < 4; ++i) {  // v
    const int col = 2048 + tid + i * 256;
    const float y = r0[col] + r1[col];
    const u16 h = f2bf(y);
    Ch[ob + col] = h; Cl[ob + col] = f2bf(y - bf2f(h));
  }
}

// ================================================= Wo GEMM: 128x128, split-bf16, dbuf, XCD-swz, Kx4
__global__ __launch_bounds__(256) void gemm_wo(const u16* __restrict__ A2,
    const u16* __restrict__ Bt2, float* __restrict__ Pout) {
  constexpr int N = 1024;
  __shared__ u16 As[2][128 * 32];
  __shared__ u16 Bs[2][128 * 32];
  const int b = blockIdx.x;
  const int xcd = b & 7, ii = b >> 3;
  const int n0 = xcd * 128;
  const int m0 = (ii & 15) * 128;
  const int ks = ii >> 4;
  const int kk0 = ks * 24, kk1 = kk0 + 24;
  const int tid = threadIdx.x, wv = tid >> 6, lane = tid & 63;
  const int l15 = lane & 15, lg = lane >> 4;
  const int wr = wv >> 1, wc = wv & 1;
  const int sr = lane >> 2, sk = (lane & 3) * 16;
  const u16* aptr[2]; const u16* bptr[2];
#pragma unroll
  for (int i = 0; i < 2; ++i) {
    aptr[i] = A2 + (size_t)(m0 + (wv * 2 + i) * 16 + sr) * 2048;
    bptr[i] = Bt2 + (size_t)(n0 + (wv * 2 + i) * 16 + sr) * 2048;
  }
  auto STAGE = [&](int buf, int kk) {
    const int t = kk * 32;
    int ka, kb;
    if (t < 1024)      { ka = t;        kb = t; }
    else if (t < 2048) { ka = t;        kb = t - 1024; }
    else               { ka = t - 2048; kb = t - 1024; }
#pragma unroll
    for (int i = 0; i < 2; ++i) {
      gl_lds16((const char*)(aptr[i] + ka) + sk, (char*)As + buf * 8192 + (wv * 2 + i) * 1024);
      gl_lds16((const char*)(bptr[i] + kb) + sk, (char*)Bs + buf * 8192 + (wv * 2 + i) * 1024);
    }
  };
  f32x4 acc[4][4] = {};
  STAGE(0, kk0);
  __syncthreads();
  int cur = 0;
  for (int kk = kk0; kk < kk1; ++kk) {
    if (kk + 1 < kk1) STAGE(cur ^ 1, kk + 1);
    const u16* Ab = (const u16*)As + cur * 4096;
    const u16* Bb = (const u16*)Bs + cur * 4096;
    short8 a[4], bb[4];
#pragma unroll
    for (int i = 0; i < 4; ++i)
      a[i] = *(const short8*)(const void*)(Ab + (size_t)(wr * 64 + i * 16 + l15) * 32 + lg * 8);
#pragma unroll
    for (int j = 0; j < 4; ++j)
      bb[j] = *(const short8*)(const void*)(Bb + (size_t)(wc * 64 + j * 16 + l15) * 32 + lg * 8);
    __builtin_amdgcn_s_setprio(1);
#pragma unroll
    for (int i = 0; i < 4; ++i)
#pragma unroll
      for (int j = 0; j < 4; ++j) acc[i][j] = mfma16(a[i], bb[j], acc[i][j]);
    __builtin_amdgcn_s_setprio(0);
    __syncthreads();
    cur ^= 1;
  }
  float* P = Pout + (size_t)ks * S * N;
#pragma unroll
  for (int i = 0; i < 4; ++i)
#pragma unroll
    for (int j = 0; j < 4; ++j)
#pragma unroll
      for (int r = 0; r < 4; ++r) {
        const int row = m0 + wr * 64 + i * 16 + lg * 4 + r;
        const int col = n0 + wc * 64 + j * 16 + l15;
        P[(size_t)row * N + col] = acc[i][j][r];
      }
}

// ================================================= MERGED: flash attention (blocks < 2048) +
// late weight transposes (blocks >= 2048: 256 wo split-T + 6144 wg/wu/wd plain-T).
// Shared LDS pool 44032B carved for both paths. grid 8448
__global__ __launch_bounds__(256, 3) void attn_mfma(const u16* __restrict__ Qh,
    const u16* __restrict__ Ql, float* __restrict__ Opart, float2* __restrict__ ml,
    const float* __restrict__ wo, const float* __restrict__ wg,
    const float* __restrict__ wu, const float* __restrict__ wd,
    u16* __restrict__ woT2, u16* __restrict__ wgT, u16* __restrict__ wuT,
    u16* __restrict__ wdT) {
  __shared__ __align__(16) char smem[44032];
  const int bid = blockIdx.x;
  const int tid = threadIdx.x;

  if (bid >= 2048) {
    // ------------------- weight transpose path (reuses smem as float[64][65])
    float (*t_)[65] = (float (*)[65])smem;
    const int b2 = bid - 2048;
    const float* W; u16* out; bool split;
    int n0, k0;
    if (b2 < 256) {
      W = wo; out = woT2; split = true;
      n0 = (b2 & 15) * 64; k0 = (b2 >> 4) * 64;
    } else {
      int r = b2 - 256;
      if (r < 2048)       { const int e = r >> 8; W = wg + (size_t)e * 1048576; out = wgT + (size_t)e * 1048576; }
      else if (r < 4096)  { r -= 2048; const int e = r >> 8; W = wu + (size_t)e * 1048576; out = wuT + (size_t)e * 1048576; }
      else                { r -= 4096; const int e = r >> 8; W = wd + (size_t)e * 1048576; out = wdT + (size_t)e * 1048576; }
      split = false;
      r &= 255; n0 = (r & 15) * 64; k0 = (r >> 4) * 64;
    }
    const int rr = tid >> 4, c4 = (tid & 15) * 4;
#pragma unroll
    for (int i = 0; i < 4; ++i) {
      const float4 v = *(const float4*)(W + (size_t)(k0 + rr + i * 16) * 1024 + n0 + c4);
      t_[rr + i * 16][c4 + 0] = v.x; t_[rr + i * 16][c4 + 1] = v.y;
      t_[rr + i * 16][c4 + 2] = v.z; t_[rr + i * 16][c4 + 3] = v.w;
    }
    __syncthreads();
    if (split) {
#pragma unroll
      for (int i = 0; i < 4; ++i) {
        const int n = n0 + rr + i * 16;
        u16* oh = out + (size_t)n * 2048 + k0 + c4;
        const float v0 = t_[c4 + 0][rr + i * 16], v1 = t_[c4 + 1][rr + i * 16];
        const float v2 = t_[c4 + 2][rr + i * 16], v3 = t_[c4 + 3][rr + i * 16];
        *(u64*)(void*)oh = pack4bf(v0, v1, v2, v3);
        *(u64*)(void*)(oh + 1024) = pack4bf(v0 - bf2f(f2bf(v0)), v1 - bf2f(f2bf(v1)),
                                            v2 - bf2f(f2bf(v2)), v3 - bf2f(f2bf(v3)));
      }
    } else {
#pragma unroll
      for (int i = 0; i < 4; ++i) {
        const int n = n0 + rr + i * 16;
        *(u64*)(void*)(out + (size_t)n * 1024 + k0 + c4) =
            pack4bf(t_[c4 + 0][rr + i * 16], t_[c4 + 1][rr + i * 16],
                    t_[c4 + 2][rr + i * 16], t_[c4 + 3][rr + i * 16]);
      }
    }
    return;
  }

  // ------------------- attention path (identical to R11/R15 logic, LDS carved from smem)
  u16* Kh  = (u16*)(smem);               // 8192B
  u16* Kl  = (u16*)(smem + 8192);        // 8192B
  u16* Vth = (u16*)(smem + 16384);       // 9216B
  u16* Vtl = (u16*)(smem + 25600);       // 9216B
  u16* Pp  = (u16*)(smem + 34816);       // 9216B = 4 waves x 16 x 72 u16

  const int b = bid;
  const int head = (b & 7) + 8 * ((b >> 3) & 1);
  const int qb = 31 - ((b >> 4) & 31);
  const int sp = (b >> 9) & 3;
  const int q0 = qb * 64;
  const int ktiles = qb + 1;
  const int kbase = ktiles >> 2, krem = ktiles & 3;
  const int t0 = sp * kbase + (sp < krem ? sp : krem);
  const int t1 = t0 + kbase + (sp < krem ? 1 : 0);
  const int w = tid >> 6, lane = tid & 63;
  const int l15 = lane & 15, lg = lane >> 4;

  short8 qh[2], qlo[2];
  {
    const size_t qbase = (size_t)(q0 + w * 16 + l15) * 3072 + head * 64;
    qh[0]  = *(const short8*)(const void*)(Qh + qbase + lg * 8);
    qh[1]  = *(const short8*)(const void*)(Qh + qbase + 32 + lg * 8);
    qlo[0] = *(const short8*)(const void*)(Ql + qbase + lg * 8);
    qlo[1] = *(const short8*)(const void*)(Ql + qbase + 32 + lg * 8);
  }
  f32x4 oacc[4] = {};
  float m_run = -__builtin_inff(), l_run = 0.f;
  const int qrow0 = q0 + w * 16 + lg * 4;
  const int qcol  = q0 + w * 16 + l15;

  const int vhl = tid >> 7, rem = tid & 127;
  const int vkq = rem & 15, vdg = rem >> 4;
  const u16* vbase = (vhl ? Ql : Qh) + 2048 + head * 64 + vdg * 8;
  u16* vdst = vhl ? Vtl : Vth;
  short8 vr[4];

  auto STAGEK = [&](int kt) {
#pragma unroll
    for (int i = 0; i < 2; ++i) {
      const int inst = w * 2 + i;
      const int key = inst * 8 + (lane >> 3);
      const int db = ((lane & 7) * 16) ^ ((key & 7) << 4);
      gl_lds16((const char*)(Qh + (size_t)(kt * 64 + key) * 3072 + 1024 + head * 64) + db,
               (char*)Kh + inst * 1024);
      gl_lds16((const char*)(Ql + (size_t)(kt * 64 + key) * 3072 + 1024 + head * 64) + db,
               (char*)Kl + inst * 1024);
    }
  };
  auto VLOAD = [&](int kt) {
    const u16* vs = vbase + (size_t)(kt * 64 + vkq * 4) * 3072;
    vr[0] = *(const short8*)(const void*)vs;
    vr[1] = *(const short8*)(const void*)(vs + 3072);
    vr[2] = *(const short8*)(const void*)(vs + 6144);
    vr[3] = *(const short8*)(const void*)(vs + 9216);
  };
  auto VWRITE = [&]() {
#pragma unroll
    for (int jj = 0; jj < 8; ++jj) {
      const u64 pk = (u64)(u16)vr[0][jj] | ((u64)(u16)vr[1][jj] << 16) |
                     ((u64)(u16)vr[2][jj] << 32) | ((u64)(u16)vr[3][jj] << 48);
      *(u64*)(void*)(vdst + (vdg * 8 + jj) * 72 + vkq * 4) = pk;
    }
  };

  if (t0 < t1) {
    STAGEK(t0);
    VLOAD(t0);
    VWRITE();
    __syncthreads();
  }
  for (int t = t0; t < t1; ++t) {
    const int k0 = t * 64;
    const bool more = (t + 1 < t1);
    f32x4 sacc[4];
    __builtin_amdgcn_s_setprio(1);
#pragma unroll
    for (int nt = 0; nt < 4; ++nt) {
      const int key = nt * 16 + l15;
      const char* kbh = (const char*)Kh + key * 128;
      const char* kbl = (const char*)Kl + key * 128;
      const int sw = (key & 7) << 4;
      const short8 kh0 = *(const short8*)(const void*)(kbh + ((lg * 16) ^ sw));
      const short8 kh1 = *(const short8*)(const void*)(kbh + ((64 + lg * 16) ^ sw));
      const short8 kl0 = *(const short8*)(const void*)(kbl + ((lg * 16) ^ sw));
      const short8 kl1 = *(const short8*)(const void*)(kbl + ((64 + lg * 16) ^ sw));
      f32x4 s = {};
      s = mfma16(kh0, qh[0], s);  s = mfma16(kh1, qh[1], s);
      s = mfma16(kh0, qlo[0], s); s = mfma16(kh1, qlo[1], s);
      s = mfma16(kl0, qh[0], s);  s = mfma16(kl1, qh[1], s);
      sacc[nt] = s;
    }
    __builtin_amdgcn_s_setprio(0);
    __syncthreads();                  // B1: K reads done
    if (more) { STAGEK(t + 1); VLOAD(t + 1); }
#pragma unroll
    for (int nt = 0; nt < 4; ++nt)
#pragma unroll
      for (int r = 0; r < 4; ++r) sacc[nt][r] *= SCL2;
    if (t == qb) {
#pragma unroll
      for (int nt = 0; nt < 4; ++nt) {
        const int keyb = k0 + nt * 16 + lg * 4;
#pragma unroll
        for (int r = 0; r < 4; ++r)
          if (keyb + r > qcol) sacc[nt][r] = -__builtin_inff();
      }
    }
    float mx = sacc[0][0];
#pragma unroll
    for (int nt = 0; nt < 4; ++nt)
#pragma unroll
      for (int r = 0; r < 4; ++r) mx = fmaxf(mx, sacc[nt][r]);
    mx = fmaxf(mx, __shfl_xor(mx, 16, 64));
    mx = fmaxf(mx, __shfl_xor(mx, 32, 64));
    const bool grow = mx > m_run + 8.f;
    if (__any(grow)) {
      const float m_new = fmaxf(m_run, mx);
      const float fac = __builtin_amdgcn_exp2f(m_run - m_new);
      m_run = m_new;
      l_run *= fac;
      float facB[4];
#pragma unroll
      for (int r = 0; r < 4; ++r) facB[r] = __shfl(fac, lg * 4 + r, 64);
#pragma unroll
      for (int nd = 0; nd < 4; ++nd)
#pragma unroll
        for (int r = 0; r < 4; ++r) oacc[nd][r] *= facB[r];
    }
    float ls = 0.f;
#pragma unroll
    for (int nt = 0; nt < 4; ++nt)
#pragma unroll
      for (int r = 0; r < 4; ++r) {
        sacc[nt][r] = __builtin_amdgcn_exp2f(sacc[nt][r] - m_run);
        ls += sacc[nt][r];
      }
    ls += __shfl_xor(ls, 16, 64);
    ls += __shfl_xor(ls, 32, 64);
    l_run += ls;
    u16* prow = Pp + w * 1152 + l15 * 72;
#pragma unroll
    for (int nt = 0; nt < 4; ++nt) {
      const u64 pk = (u64)(__float_as_uint(sacc[nt][0]) >> 16) |
                     ((u64)(__float_as_uint(sacc[nt][1]) >> 16) << 16) |
                     ((u64)(__float_as_uint(sacc[nt][2]) >> 16) << 32) |
                     ((u64)(__float_as_uint(sacc[nt][3]) >> 16) << 48);
      *(u64*)(void*)(prow + nt * 16 + lg * 4) = pk;
    }
    __builtin_amdgcn_s_setprio(1);
#pragma unroll
    for (int kk2 = 0; kk2 < 2; ++kk2) {
      const short8 pa = *(const short8*)(const void*)((const char*)prow + kk2 * 64 + lg * 16);
#pragma unroll
      for (int nd = 0; nd < 4; ++nd) {
        const short8 vbh = *(const short8*)(const void*)((const char*)Vth + (nd * 16 + l15) * 144 + kk2 * 64 + lg * 16);
        const short8 vbl = *(const short8*)(const void*)((const char*)Vtl + (nd * 16 + l15) * 144 + kk2 * 64 + lg * 16);
        oacc[nd] = mfma16(pa, vbh, oacc[nd]);
        oacc[nd] = mfma16(pa, vbl, oacc[nd]);
      }
    }
    __builtin_amdgcn_s_setprio(0);
    asm volatile("" ::: "memory");
#pragma unroll
    for (int nt = 0; nt < 4; ++nt) {
      float lo[4];
#pragma unroll
      for (int r = 0; r < 4; ++r)
        lo[r] = sacc[nt][r] - __uint_as_float(__float_as_uint(sacc[nt][r]) & 0xFFFF0000u);
      const u64 pk = (u64)(__float_as_uint(lo[0]) >> 16) |
                     ((u64)(__float_as_uint(lo[1]) >> 16) << 16) |
                     ((u64)(__float_as_uint(lo[2]) >> 16) << 32) |
                     ((u64)(__float_as_uint(lo[3]) >> 16) << 48);
      *(u64*)(void*)(prow + nt * 16 + lg * 4) = pk;
    }
    asm volatile("" ::: "memory");
    __builtin_amdgcn_s_setprio(1);
#pragma unroll
    for (int kk2 = 0; kk2 < 2; ++kk2) {
      const short8 pa = *(const short8*)(const void*)((const char*)prow + kk2 * 64 + lg * 16);
#pragma unroll
      for (int nd = 0; nd < 4; ++nd) {
        const short8 vbh = *(const short8*)(const void*)((const char*)Vth + (nd * 16 + l15) * 144 + kk2 * 64 + lg * 16);
        oacc[nd] = mfma16(pa, vbh, oacc[nd]);
      }
    }
    __builtin_amdgcn_s_setprio(0);
    __syncthreads();                  // B2
    if (more) VWRITE();
  }
  float* Op = Opart + (size_t)sp * S * 1024;
#pragma unroll
  for (int nd = 0; nd < 4; ++nd)
#pragma unroll
    for (int r = 0; r < 4; ++r)
      Op[(size_t)(qrow0 + r) * 1024 + head * 64 + nd * 16 + l15] = oacc[nd][r];
  if (lg == 0) {
    ml[((size_t)sp * S + q0 + w * 16 + l15) * NH + head] = make_float2(m_run, l_run);
  }
}

// ================================================= combine 4 split-K attention partials
__global__ __launch_bounds__(256) void attn_combine(const float* __restrict__ Op,
    const float2* __restrict__ ml, u16* __restrict__ OA2) {
  const int t = blockIdx.x, tid = threadIdx.x;
  const int h = tid >> 4, dq = (tid & 15) * 4;
  float2 a[4];
  float M = -__builtin_inff();
#pragma unroll
  for (int c = 0; c < 4; ++c) {
    a[c] = ml[((size_t)c * S + t) * NH + h];
    if (a[c].y > 0.f) M = fmaxf(M, a[c].x);
  }
  float e[4], denom = 0.f;
#pragma unroll
  for (int c = 0; c < 4; ++c) {
    e[c] = (a[c].y > 0.f) ? exp2f(a[c].x - M) : 0.f;
    denom += e[c] * a[c].y;
  }
  const float inv = 1.f / denom;
  float ov[4] = {0.f, 0.f, 0.f, 0.f};
#pragma unroll
  for (int c = 0; c < 4; ++c) {
    const float4 v = *(const float4*)(Op + ((size_t)c * S + t) * 1024 + h * 64 + dq);
    ov[0] += e[c] * v.x; ov[1] += e[c] * v.y; ov[2] += e[c] * v.z; ov[3] += e[c] * v.w;
  }
#pragma unroll
  for (int c2 = 0; c2 < 4; ++c2) {
    const float o = ov[c2] * inv;
    const size_t idx = (size_t)t * 2048 + h * 64 + dq + c2;
    const u16 hb = f2bf(o);
    OA2[idx] = hb;
    OA2[idx + 1024] = f2bf(o - bf2f(hb));
  }
}

// ================================================= res2 (4 partials) + rmsnorm2 + gate (no atomics)
__global__ __launch_bounds__(256) void rmsnorm_res2_gate(const float* __restrict__ hidden,
    const float* __restrict__ p01, const float* __restrict__ w2, const float* __restrict__ GW,
    float* __restrict__ out, u16* __restrict__ yb,
    int* __restrict__ top2, float2* __restrict__ topw) {
  const int t = blockIdx.x;
  const int d0 = threadIdx.x * 4;
  const size_t base = (size_t)t * D + d0;
  const float4 h4 = *(const float4*)(hidden + base);
  const float4 a4 = *(const float4*)(p01 + base);
  const float4 b4 = *(const float4*)(p01 + (size_t)S * D + base);
  const float4 c4 = *(const float4*)(p01 + 2 * (size_t)S * D + base);
  const float4 e4 = *(const float4*)(p01 + 3 * (size_t)S * D + base);
  float v[4] = {h4.x + a4.x + b4.x + c4.x + e4.x, h4.y + a4.y + b4.y + c4.y + e4.y,
                h4.z + a4.z + b4.z + c4.z + e4.z, h4.w + a4.w + b4.w + c4.w + e4.w};
  float ss = v[0] * v[0] + v[1] * v[1] + v[2] * v[2] + v[3] * v[3];
#pragma unroll
  for (int m = 32; m >= 1; m >>= 1) ss += __shfl_xor(ss, m, 64);
  __shared__ float red[4];
  if ((threadIdx.x & 63) == 0) red[threadIdx.x >> 6] = ss;
  __syncthreads();
  const float rs = rsqrtf((red[0] + red[1] + red[2] + red[3]) * (1.f / (float)D) + EPS);
  const float4 w4 = *(const float4*)(w2 + d0);
  const float y[4] = {v[0] * rs * w4.x, v[1] * rs * w4.y, v[2] * rs * w4.z, v[3] * rs * w4.w};
  *(float4*)(out + base) = make_float4(v[0], v[1], v[2], v[3]);
  *(u64*)(void*)(yb + base) = pack4bf(y[0], y[1], y[2], y[3]);
  float lg[8] = {};
#pragma unroll
  for (int j = 0; j < 4; ++j) {
    const float4 g0 = *(const float4*)(GW + (d0 + j) * 8);
    const float4 g1 = *(const float4*)(GW + (d0 + j) * 8 + 4);
    lg[0] += y[j] * g0.x; lg[1] += y[j] * g0.y; lg[2] += y[j] * g0.z; lg[3] += y[j] * g0.w;
    lg[4] += y[j] * g1.x; lg[5] += y[j] * g1.y; lg[6] += y[j] * g1.z; lg[7] += y[j] * g1.w;
  }
#pragma unroll
  for (int e = 0; e < 8; ++e)
#pragma unroll
    for (int m = 32; m >= 1; m >>= 1) lg[e] += __shfl_xor(lg[e], m, 64);
  __shared__ float wred[4][8];
  if ((threadIdx.x & 63) == 0)
#pragma unroll
    for (int e = 0; e < 8; ++e) wred[threadIdx.x >> 6][e] = lg[e];
  __syncthreads();
  if (threadIdx.x == 0) {
    float L[8];
#pragma unroll
    for (int e = 0; e < 8; ++e) L[e] = wred[0][e] + wred[1][e] + wred[2][e] + wred[3][e];
    int i0 = 0; float v0 = L[0];
    for (int i = 1; i < 8; ++i) if (L[i] > v0) { v0 = L[i]; i0 = i; }
    int i1 = -1; float v1 = -__builtin_inff();
    for (int i = 0; i < 8; ++i) if (i != i0 && L[i] > v1) { v1 = L[i]; i1 = i; }
    const float e1 = expf(v1 - v0);
    const float inv = 1.f / (1.f + e1);
    top2[t] = i0 | (i1 << 4);
    topw[t] = make_float2(inv, e1 * inv);
  }
}

// ================================================= scatter compact: deterministic prefix-scan
__global__ __launch_bounds__(1024) void scatter_compact(const int* __restrict__ top2,
    const float2* __restrict__ topw, int* __restrict__ counts,
    int* __restrict__ tok_map, float* __restrict__ w_map) {
  const int tid = threadIdx.x;
  __shared__ u64 s0[1024], s1[1024];
  int e_[2][2]; float w_[2][2];
  u64 c0 = 0, c1 = 0;
#pragma unroll
  for (int k = 0; k < 2; ++k) {
    const int t = tid * 2 + k;
    const int pk = top2[t];
    const float2 wv = topw[t];
    e_[k][0] = pk & 15; e_[k][1] = (pk >> 4) & 15;
    w_[k][0] = wv.x;    w_[k][1] = wv.y;
#pragma unroll
    for (int s = 0; s < 2; ++s) {
      const int e = e_[k][s];
      if (e < 4) c0 += 1ull << (e * 16); else c1 += 1ull << ((e - 4) * 16);
    }
  }
  s0[tid] = c0; s1[tid] = c1;
  __syncthreads();
  for (int off = 1; off < 1024; off <<= 1) {
    const u64 a0 = (tid >= off) ? s0[tid - off] : 0;
    const u64 a1 = (tid >= off) ? s1[tid - off] : 0;
    __syncthreads();
    s0[tid] += a0; s1[tid] += a1;
    __syncthreads();
  }
  if (tid == 1023) {
#pragma unroll
    for (int e = 0; e < 4; ++e) counts[e] = (int)((s0[1023] >> (e * 16)) & 0xFFFF);
#pragma unroll
    for (int e = 4; e < 8; ++e) counts[e] = (int)((s1[1023] >> ((e - 4) * 16)) & 0xFFFF);
  }
  u64 l0 = s0[tid] - c0, l1 = s1[tid] - c1;
#pragma unroll
  for (int k = 0; k < 2; ++k) {
    const int t = tid * 2 + k;
#pragma unroll
    for (int s = 0; s < 2; ++s) {
      const int e = e_[k][s];
      int p;
      if (e < 4) { p = (int)((l0 >> (e * 16)) & 0xFFFF); l0 += 1ull << (e * 16); }
      else       { p = (int)((l1 >> ((e - 4) * 16)) & 0xFFFF); l1 += 1ull << ((e - 4) * 16); }
      tok_map[e * S + p] = t | (s << 16);
      w_map[e * S + p] = w_[k][s];
    }
  }
}

// ================================================= MoE gate/up GEMM: 128x64 tile, dual-B, dbuf
__global__ __launch_bounds__(256) void moe_gu(const u16* __restrict__ Yb,
    const u16* __restrict__ Wgb, const u16* __restrict__ Wub, u16* __restrict__ Hb,
    const int* __restrict__ counts, const int* __restrict__ tokmap) {
  const int b = blockIdx.x;
  const int e = b & 7, ii = b >> 3;
  const int n0 = (ii & 15) * 64;
  const int m0 = (ii >> 4) * 128;
  const int cnt = counts[e];
  if (m0 >= cnt) return;
  __shared__ u16 SH[2][16 * 512];
  const int tid = threadIdx.x, wv = tid >> 6, lane = tid & 63;
  const int l15 = lane & 15, lg = lane >> 4;
  const int wr = wv >> 1, wc = wv & 1;
  const int sr = lane >> 2, sk = (lane & 3) * 16;
  const u16* B1 = Wgb + (size_t)e * 1048576;
  const u16* B2 = Wub + (size_t)e * 1048576;
  const u16* cp[4];
#pragma unroll
  for (int i = 0; i < 4; ++i) {
    const int c = wv * 4 + i;
    if (c < 8) {
      const int arow = m0 + c * 16 + sr;
      const int tok = tokmap[e * S + arow] & 2047;
      cp[i] = Yb + (size_t)tok * 1024;
    } else if (c < 12) {
      cp[i] = B1 + (size_t)(n0 + (c - 8) * 16 + sr) * 1024;
    } else {
      cp[i] = B2 + (size_t)(n0 + (c - 12) * 16 + sr) * 1024;
    }
  }
  auto STAGE = [&](int buf, int k) {
#pragma unroll
    for (int i = 0; i < 4; ++i) {
      const int c = wv * 4 + i;
      gl_lds16((const char*)(cp[i] + k) + sk, (char*)SH + buf * 16384 + c * 1024);
    }
  };
  f32x4 acc1[4][2] = {};
  f32x4 acc2[4][2] = {};
  STAGE(0, 0);
  __syncthreads();
  int cur = 0;
  for (int kk = 0; kk < 32; ++kk) {
    if (kk < 31) STAGE(cur ^ 1, (kk + 1) * 32);
    const u16* Sb = (const u16*)SH + cur * 8192;
    short8 a[4], b1f[2], b2f[2];
#pragma unroll
    for (int i = 0; i < 4; ++i)
      a[i] = *(const short8*)(const void*)(Sb + (size_t)(wr * 64 + i * 16 + l15) * 32 + lg * 8);
#pragma unroll
    for (int j = 0; j < 2; ++j) {
      b1f[j] = *(const short8*)(const void*)(Sb + 4096 + (size_t)(wc * 32 + j * 16 + l15) * 32 + lg * 8);
      b2f[j] = *(const short8*)(const void*)(Sb + 6144 + (size_t)(wc * 32 + j * 16 + l15) * 32 + lg * 8);
    }
    __builtin_amdgcn_s_setprio(1);
#pragma unroll
    for (int i = 0; i < 4; ++i)
#pragma unroll
      for (int j = 0; j < 2; ++j) {
        acc1[i][j] = mfma16(a[i], b1f[j], acc1[i][j]);
        acc2[i][j] = mfma16(a[i], b2f[j], acc2[i][j]);
      }
    __builtin_amdgcn_s_setprio(0);
    __syncthreads();
    cur ^= 1;
  }
#pragma unroll
  for (int i = 0; i < 4; ++i)
#pragma unroll
    for (int j = 0; j < 2; ++j)
#pragma unroll
      for (int r = 0; r < 4; ++r) {
        const int row = m0 + wr * 64 + i * 16 + lg * 4 + r;
        if (row < cnt) {
          const float g = acc1[i][j][r];
          const float u = acc2[i][j][r];
          const float sig = __builtin_amdgcn_rcpf(1.f + __builtin_amdgcn_exp2f(-g * LOG2E));
          Hb[((size_t)e * 2048 + row) * 1024 + n0 + wc * 32 + j * 16 + l15] = f2bf(u * g * sig);
        }
      }
}

// ================================================= MoE down GEMM: split-K x2 -> 4 bf16 slot planes
__global__ __launch_bounds__(256) void moe_down(const u16* __restrict__ Hb,
    const u16* __restrict__ Wdb, u16* __restrict__ slotp,
    const int* __restrict__ counts, const int* __restrict__ tokmap,
    const float* __restrict__ wmap) {
  const int b = blockIdx.x;
  const int e = b & 7, ii = b >> 3;
  const int m0 = (ii & 15) * 128;
  const int n0 = ((ii >> 4) & 7) * 128;
  const int ks = ii >> 7;
  const int cnt = counts[e];
  if (m0 >= cnt) return;
  __shared__ u16 As[2][128 * 32];
  __shared__ u16 Bs[2][128 * 32];
  const int tid = threadIdx.x, wv = tid >> 6, lane = tid & 63;
  const int l15 = lane & 15, lg = lane >> 4;
  const int wr = wv >> 1, wc = wv & 1;
  const int sr = lane >> 2, sk = (lane & 3) * 16;
  const u16* B = Wdb + (size_t)e * 1048576;
  const u16* aptr[2]; const u16* bptr[2];
#pragma unroll
  for (int i = 0; i < 2; ++i) {
    aptr[i] = Hb + ((size_t)e * 2048 + m0 + (wv * 2 + i) * 16 + sr) * 1024;
    bptr[i] = B + (size_t)(n0 + (wv * 2 + i) * 16 + sr) * 1024;
  }
  auto STAGE = [&](int buf, int k) {
#pragma unroll
    for (int i = 0; i < 2; ++i) {
      gl_lds16((const char*)(aptr[i] + k) + sk, (char*)As + buf * 8192 + (wv * 2 + i) * 1024);
      gl_lds16((const char*)(bptr[i] + k) + sk, (char*)Bs + buf * 8192 + (wv * 2 + i) * 1024);
    }
  };
  f32x4 acc[4][4] = {};
  const int kb0 = ks * 16, kb1 = kb0 + 16;
  STAGE(0, kb0 * 32);
  __syncthreads();
  int cur = 0;
  for (int kk = kb0; kk < kb1; ++kk) {
    if (kk + 1 < kb1) STAGE(cur ^ 1, (kk + 1) * 32);
    const u16* Ab = (const u16*)As + cur * 4096;
    const u16* Bb = (const u16*)Bs + cur * 4096;
    short8 a[4], bb[4];
#pragma unroll
    for (int i = 0; i < 4; ++i)
      a[i] = *(const short8*)(const void*)(Ab + (size_t)(wr * 64 + i * 16 + l15) * 32 + lg * 8);
#pragma unroll
    for (int j = 0; j < 4; ++j)
      bb[j] = *(const short8*)(const void*)(Bb + (size_t)(wc * 64 + j * 16 + l15) * 32 + lg * 8);
    __builtin_amdgcn_s_setprio(1);
#pragma unroll
    for (int i = 0; i < 4; ++i)
#pragma unroll
      for (int j = 0; j < 4; ++j) acc[i][j] = mfma16(a[i], bb[j], acc[i][j]);
    __builtin_amdgcn_s_setprio(0);
    __syncthreads();
    cur ^= 1;
  }
#pragma unroll
  for (int i = 0; i < 4; ++i)
#pragma unroll
    for (int j = 0; j < 4; ++j)
#pragma unroll
      for (int r = 0; r < 4; ++r) {
        const int row = m0 + wr * 64 + i * 16 + lg * 4 + r;
        if (row < cnt) {
          const int raw = tokmap[e * S + row];
          const int t = raw & 2047;
          const int sl = (raw >> 16) & 1;
          const float wgt = wmap[e * S + row];
          slotp[((size_t)(sl * 2 + ks) * S + t) * 1024 + n0 + wc * 64 + j * 16 + l15] =
              f2bf(wgt * acc[i][j][r]);
        }
      }
}

// ================================================= final add: out += sum of 4 slot planes
__global__ __launch_bounds__(256) void final_add(float* __restrict__ out,
    const u16* __restrict__ sp) {
  const size_t i = ((size_t)blockIdx.x * 256 + threadIdx.x) * 4;
  float4 o = *(float4*)(out + i);
#pragma unroll
  for (int c = 0; c < 4; ++c) {
    const u64 a = *(const u64*)(sp + (size_t)c * S * D + i);
    o.x += bf2f((u16)(a));
    o.y += bf2f((u16)(a >> 16));
    o.z += bf2f((u16)(a >> 32));
    o.w += bf2f((u16)(a >> 48));
  }
  *(float4*)(out + i) = o;
}

// ================================================= launch
extern "C" void kernel_launch(void* const* d_in, const int* in_sizes, int n_in,
                              void* d_out, int out_size, void* d_ws, size_t ws_size,
                              hipStream_t stream) {
  const int*   positions = (const int*)d_in[0];
  const float* hidden    = (const float*)d_in[1];
  const float* ln1_w  = (const float*)d_in[3];
  const float* ln2_w  = (const float*)d_in[4];
  const float* wqkv   = (const float*)d_in[5];
  const float* wo     = (const float*)d_in[6];
  const float* gate_w = (const float*)d_in[7];
  const float* wg     = (const float*)d_in[8];
  const float* wu     = (const float*)d_in[9];
  const float* wd     = (const float*)d_in[10];
  float* out = (float*)d_out;

  char* ws = (char*)d_ws;
  const size_t MB = 1ull << 20;
  u16* wqkvT2 = (u16*)(ws);
  u16* QKVh   = (u16*)(ws);
  u16* OA2    = (u16*)(ws);
  u16* woT2   = (u16*)(ws + 12 * MB);       // 4MB  (merged attn -> gemm_wo)
  u16* wgT    = (u16*)(ws + 16 * MB);       // 16MB
  u16* wuT    = (u16*)(ws + 32 * MB);       // 16MB
  u16* wdT    = (u16*)(ws + 48 * MB);       // 16MB
  float2* ropetab = (float2*)(ws + 64 * MB);            // 512KB
  float2* ml      = (float2*)(ws + 64 * MB + 524288);   // 1MB
  char* mapb = ws + 64 * MB + 1572864;
  int*   counts   = (int*)mapb;
  int*   tok_map  = (int*)(mapb + 512);
  float* w_map    = (float*)(mapb + 512 + 65536);
  int*   top2     = (int*)(mapb + 512 + 131072);
  float2* topw    = (float2*)(mapb + 512 + 139264);
  u16* xn2    = (u16*)(ws + 66 * MB);       // 8MB  (ph1-2)
  u16* QKVl   = (u16*)(ws + 66 * MB);       // 12MB (ph3-4, xn2 dead)
  u16* yb     = (u16*)(ws + 66 * MB);       // 4MB  (ph6+, QKVl dead)
  float* Cpart  = (float*)(ws + 78 * MB);   // 48MB (ph2-3)
  float* Opart  = (float*)(ws + 78 * MB);   // 32MB (ph4, Cpart dead)
  float* p01    = (float*)(ws + 78 * MB);   // 32MB (ph5-6)
  u16* Hb     = (u16*)(ws + 78 * MB);       // 32MB (ph7)
  u16* slotp  = (u16*)(ws + 110 * MB);      // 16MB (ph7-8)

  // prep_early: wqkv transpose + rope tab + rmsnorm1 (only what gemm_qkv needs)
  prep_early<<<3072, 256, 0, stream>>>(wqkv, positions, hidden, ln1_w,
                                       wqkvT2, ropetab, xn2);
  gemm_qkv<<<768, 256, 0, stream>>>(xn2, wqkvT2, Cpart);
  qkv_combine<<<S, 256, 0, stream>>>(Cpart, ropetab, QKVh, QKVl);
  // merged: attention (2048 blocks) + late weight transposes (6400 blocks)
  attn_mfma<<<8448, 256, 0, stream>>>(QKVh, QKVl, Opart, ml,
                                      wo, wg, wu, wd, woT2, wgT, wuT, wdT);
  attn_combine<<<S, 256, 0, stream>>>(Opart, ml, OA2);
  gemm_wo<<<512, 256, 0, stream>>>(OA2, woT2, p01);
  rmsnorm_res2_gate<<<S, 256, 0, stream>>>(hidden, p01, ln2_w, gate_w, out, yb, top2, topw);
  scatter_compact<<<1, 1024, 0, stream>>>(top2, topw, counts, tok_map, w_map);
  moe_gu<<<2048, 256, 0, stream>>>(yb, wgT, wuT, Hb, counts, tok_map);
  moe_down<<<2048, 256, 0, stream>>>(Hb, wdT, slotp, counts, tok_map, w_map);
  final_add<<<2048, 256, 0, stream>>>(out, slotp);
}

// Round 17
// 267.482 us; speedup vs baseline: 1.0544x; 1.0031x over previous
//
#include <hip/hip_runtime.h>
#include <math.h>

constexpr int S  = 2048;
constexpr int D  = 1024;
constexpr int NH = 16;
constexpr int NE = 8;
constexpr float EPS   = 1e-6f;
constexpr float THETA = 10000.0f;
constexpr float SCL2  = 0.125f * 1.4426950408889634f;  // attn scale * log2(e)
constexpr float LOG2E = 1.4426950408889634f;

typedef unsigned short u16;
typedef unsigned int   u32;
typedef unsigned long long u64;
typedef __attribute__((ext_vector_type(8))) short short8;
typedef __attribute__((ext_vector_type(4))) float f32x4;

__device__ __forceinline__ u16 f2bf(float x) {
  union { float f; u32 u; } v; v.f = x;
  u32 r = (v.u + 0x7FFFu + ((v.u >> 16) & 1u)) >> 16;
  return (u16)r;
}
__device__ __forceinline__ float bf2f(u16 h) {
  union { u32 u; float f; } v; v.u = ((u32)h) << 16;
  return v.f;
}
__device__ __forceinline__ f32x4 mfma16(short8 a, short8 b, f32x4 c) {
  return __builtin_amdgcn_mfma_f32_16x16x32_bf16(a, b, c, 0, 0, 0);
}
__device__ __forceinline__ void gl_lds16(const void* g, void* l) {
  __builtin_amdgcn_global_load_lds((const __attribute__((address_space(1))) u32*)g,
                                   (__attribute__((address_space(3))) u32*)l, 16, 0, 0);
}
__device__ __forceinline__ u64 pack4bf(float a, float b, float c, float d) {
  return (u64)f2bf(a) | ((u64)f2bf(b) << 16) | ((u64)f2bf(c) << 32) | ((u64)f2bf(d) << 48);
}

// ================================================= prep_early: wqkv transpose + rope + rmsnorm
// [0,768): wqkv split-T; [768,1024): rope tab; [1024,3072): rmsnorm_split rows
__global__ __launch_bounds__(256) void prep_early(const float* __restrict__ wqkv,
    const int* __restrict__ positions, const float* __restrict__ hidden,
    const float* __restrict__ ln1_w, u16* __restrict__ wqkvT2,
    float2* __restrict__ ropetab, u16* __restrict__ xn2) {
  const int b = blockIdx.x;
  const int tid = threadIdx.x;
  if (b >= 1024) {  // rmsnorm_split
    const int t = b - 1024;
    const float* xr = hidden + (size_t)t * D;
    float v[4]; float ss = 0.f;
#pragma unroll
    for (int i = 0; i < 4; ++i) { v[i] = xr[tid + i * 256]; ss += v[i] * v[i]; }
#pragma unroll
    for (int m = 32; m >= 1; m >>= 1) ss += __shfl_xor(ss, m, 64);
    __shared__ float red[4];
    if ((tid & 63) == 0) red[tid >> 6] = ss;
    __syncthreads();
    const float rs = rsqrtf((red[0] + red[1] + red[2] + red[3]) * (1.f / (float)D) + EPS);
#pragma unroll
    for (int i = 0; i < 4; ++i) {
      const int d = tid + i * 256;
      const float y = v[i] * rs * ln1_w[d];
      const u16 h = f2bf(y);
      xn2[(size_t)t * 2048 + d] = h;
      xn2[(size_t)t * 2048 + 1024 + d] = f2bf(y - bf2f(h));
    }
    return;
  }
  if (b >= 768) {  // rope table
    const int idx = (b - 768) * 256 + tid;
    const int t = idx >> 5, p = idx & 31;
    const float inv = powf(THETA, -(float)p * (1.f / 32.f));
    const float fr = (float)positions[t] * inv;
    float sn, cs; sincosf(fr, &sn, &cs);
    ropetab[idx] = make_float2(cs, sn);
    return;
  }
  // wqkv split-transpose: W[1024][3072] -> wqkvT2[3072][2048] (hi|lo)
  __shared__ float t_[64][65];
  const int n0 = (b % 48) * 64, k0 = (b / 48) * 64;
  const int rr = tid >> 4, c4 = (tid & 15) * 4;
#pragma unroll
  for (int i = 0; i < 4; ++i) {
    const float4 v = *(const float4*)(wqkv + (size_t)(k0 + rr + i * 16) * 3072 + n0 + c4);
    t_[rr + i * 16][c4 + 0] = v.x; t_[rr + i * 16][c4 + 1] = v.y;
    t_[rr + i * 16][c4 + 2] = v.z; t_[rr + i * 16][c4 + 3] = v.w;
  }
  __syncthreads();
#pragma unroll
  for (int i = 0; i < 4; ++i) {
    const int n = n0 + rr + i * 16;
    u16* oh = wqkvT2 + (size_t)n * 2048 + k0 + c4;
    const float v0 = t_[c4 + 0][rr + i * 16], v1 = t_[c4 + 1][rr + i * 16];
    const float v2 = t_[c4 + 2][rr + i * 16], v3 = t_[c4 + 3][rr + i * 16];
    *(u64*)(void*)oh = pack4bf(v0, v1, v2, v3);
    *(u64*)(void*)(oh + 1024) = pack4bf(v0 - bf2f(f2bf(v0)), v1 - bf2f(f2bf(v1)),
                                        v2 - bf2f(f2bf(v2)), v3 - bf2f(f2bf(v3)));
  }
}

// ================================================= QKV GEMM: 128x128, split-bf16, dbuf, XCD-swz,
// split-K x2 -> f32 partial planes. grid 768. Within XCD: np innermost (A panel hot,
// 3 B panels L2-resident), then m, then ks.
__global__ __launch_bounds__(256) void gemm_qkv(const u16* __restrict__ A2,
    const u16* __restrict__ Bt2, float* __restrict__ Cpart) {
  __shared__ u16 As[2][128 * 32];
  __shared__ u16 Bs[2][128 * 32];
  const int b = blockIdx.x;
  const int xcd = b & 7, ii = b >> 3;
  const int np = ii % 3;
  const int m0 = ((ii / 3) & 15) * 128;
  const int ks = ii / 48;
  const int n0 = (xcd * 3 + np) * 128;
  const int kk0 = ks * 48, kk1 = kk0 + 48;
  const int tid = threadIdx.x, wv = tid >> 6, lane = tid & 63;
  const int l15 = lane & 15, lg = lane >> 4;
  const int wr = wv >> 1, wc = wv & 1;
  const int sr = lane >> 2, sk = (lane & 3) * 16;
  const u16* aptr[2]; const u16* bptr[2];
#pragma unroll
  for (int i = 0; i < 2; ++i) {
    aptr[i] = A2 + (size_t)(m0 + (wv * 2 + i) * 16 + sr) * 2048;
    bptr[i] = Bt2 + (size_t)(n0 + (wv * 2 + i) * 16 + sr) * 2048;
  }
  auto STAGE = [&](int buf, int kk) {
    const int t = kk * 32;
    int ka, kb;
    if (t < 1024)      { ka = t;        kb = t; }
    else if (t < 2048) { ka = t;        kb = t - 1024; }
    else               { ka = t - 2048; kb = t - 1024; }
#pragma unroll
    for (int i = 0; i < 2; ++i) {
      gl_lds16((const char*)(aptr[i] + ka) + sk, (char*)As + buf * 8192 + (wv * 2 + i) * 1024);
      gl_lds16((const char*)(bptr[i] + kb) + sk, (char*)Bs + buf * 8192 + (wv * 2 + i) * 1024);
    }
  };
  f32x4 acc[4][4] = {};
  STAGE(0, kk0);
  __syncthreads();
  int cur = 0;
  for (int kk = kk0; kk < kk1; ++kk) {
    if (kk + 1 < kk1) STAGE(cur ^ 1, kk + 1);
    const u16* Ab = (const u16*)As + cur * 4096;
    const u16* Bb = (const u16*)Bs + cur * 4096;
    short8 a[4], bb[4];
#pragma unroll
    for (int i = 0; i < 4; ++i)
      a[i] = *(const short8*)(const void*)(Ab + (size_t)(wr * 64 + i * 16 + l15) * 32 + lg * 8);
#pragma unroll
    for (int j = 0; j < 4; ++j)
      bb[j] = *(const short8*)(const void*)(Bb + (size_t)(wc * 64 + j * 16 + l15) * 32 + lg * 8);
    __builtin_amdgcn_s_setprio(1);
#pragma unroll
    for (int i = 0; i < 4; ++i)
#pragma unroll
      for (int j = 0; j < 4; ++j) acc[i][j] = mfma16(a[i], bb[j], acc[i][j]);
    __builtin_amdgcn_s_setprio(0);
    __syncthreads();
    cur ^= 1;
  }
  float* P = Cpart + (size_t)ks * S * 3072;
#pragma unroll
  for (int i = 0; i < 4; ++i)
#pragma unroll
    for (int j = 0; j < 4; ++j)
#pragma unroll
      for (int r = 0; r < 4; ++r) {
        const int row = m0 + wr * 64 + i * 16 + lg * 4 + r;
        const int col = n0 + wc * 64 + j * 16 + l15;
        P[(size_t)row * 3072 + col] = acc[i][j][r];
      }
}

// ================================================= QKV combine: sum 2 planes + rope + hi/lo split
__global__ __launch_bounds__(256) void qkv_combine(const float* __restrict__ Cp,
    const float2* __restrict__ tab, u16* __restrict__ Ch, u16* __restrict__ Cl) {
  const int t = blockIdx.x, tid = threadIdx.x;
  const float* r0 = Cp + (size_t)t * 3072;
  const float* r1 = r0 + (size_t)S * 3072;
  const size_t ob = (size_t)t * 3072;
#pragma unroll
  for (int i = 0; i < 4; ++i) {  // q,k pairs
    const int pi = tid + i * 256;
    const int h = pi >> 5, p = pi & 31;
    const int col = h * 64 + p;
    const float x1 = r0[col] + r1[col];
    const float x2 = r0[col + 32] + r1[col + 32];
    const float2 cs = tab[t * 32 + p];
    const float y1 = x1 * cs.x - x2 * cs.y;
    const float y2 = x1 * cs.y + x2 * cs.x;
    const u16 h1 = f2bf(y1);
    Ch[ob + col] = h1; Cl[ob + col] = f2bf(y1 - bf2f(h1));
    const u16 h2 = f2bf(y2);
    Ch[ob + col + 32] = h2; Cl[ob + col + 32] = f2bf(y2 - bf2f(h2));
  }
#pragma unroll
  for (int i = 0; i < 4; ++i) {  // v
    const int col = 2048 + tid + i * 256;
    const float y = r0[col] + r1[col];
    const u16 h = f2bf(y);
    Ch[ob + col] = h; Cl[ob + col] = f2bf(y - bf2f(h));
  }
}

// ================================================= Wo GEMM: 128x128, split-bf16, dbuf, Kx4.
// xcd owns 2 m-panels (A slice 1MB L2-resident); ii: n=ii&7, mi=(ii>>3)&1, ks=ii>>4. grid 512
__global__ __launch_bounds__(256) void gemm_wo(const u16* __restrict__ A2,
    const u16* __restrict__ Bt2, float* __restrict__ Pout) {
  constexpr int N = 1024;
  __shared__ u16 As[2][128 * 32];
  __shared__ u16 Bs[2][128 * 32];
  const int b = blockIdx.x;
  const int xcd = b & 7, ii = b >> 3;
  const int n0 = (ii & 7) * 128;
  const int m0 = (xcd * 2 + ((ii >> 3) & 1)) * 128;
  const int ks = ii >> 4;
  const int kk0 = ks * 24, kk1 = kk0 + 24;
  const int tid = threadIdx.x, wv = tid >> 6, lane = tid & 63;
  const int l15 = lane & 15, lg = lane >> 4;
  const int wr = wv >> 1, wc = wv & 1;
  const int sr = lane >> 2, sk = (lane & 3) * 16;
  const u16* aptr[2]; const u16* bptr[2];
#pragma unroll
  for (int i = 0; i < 2; ++i) {
    aptr[i] = A2 + (size_t)(m0 + (wv * 2 + i) * 16 + sr) * 2048;
    bptr[i] = Bt2 + (size_t)(n0 + (wv * 2 + i) * 16 + sr) * 2048;
  }
  auto STAGE = [&](int buf, int kk) {
    const int t = kk * 32;
    int ka, kb;
    if (t < 1024)      { ka = t;        kb = t; }
    else if (t < 2048) { ka = t;        kb = t - 1024; }
    else               { ka = t - 2048; kb = t - 1024; }
#pragma unroll
    for (int i = 0; i < 2; ++i) {
      gl_lds16((const char*)(aptr[i] + ka) + sk, (char*)As + buf * 8192 + (wv * 2 + i) * 1024);
      gl_lds16((const char*)(bptr[i] + kb) + sk, (char*)Bs + buf * 8192 + (wv * 2 + i) * 1024);
    }
  };
  f32x4 acc[4][4] = {};
  STAGE(0, kk0);
  __syncthreads();
  int cur = 0;
  for (int kk = kk0; kk < kk1; ++kk) {
    if (kk + 1 < kk1) STAGE(cur ^ 1, kk + 1);
    const u16* Ab = (const u16*)As + cur * 4096;
    const u16* Bb = (const u16*)Bs + cur * 4096;
    short8 a[4], bb[4];
#pragma unroll
    for (int i = 0; i < 4; ++i)
      a[i] = *(const short8*)(const void*)(Ab + (size_t)(wr * 64 + i * 16 + l15) * 32 + lg * 8);
#pragma unroll
    for (int j = 0; j < 4; ++j)
      bb[j] = *(const short8*)(const void*)(Bb + (size_t)(wc * 64 + j * 16 + l15) * 32 + lg * 8);
    __builtin_amdgcn_s_setprio(1);
#pragma unroll
    for (int i = 0; i < 4; ++i)
#pragma unroll
      for (int j = 0; j < 4; ++j) acc[i][j] = mfma16(a[i], bb[j], acc[i][j]);
    __builtin_amdgcn_s_setprio(0);
    __syncthreads();
    cur ^= 1;
  }
  float* P = Pout + (size_t)ks * S * N;
#pragma unroll
  for (int i = 0; i < 4; ++i)
#pragma unroll
    for (int j = 0; j < 4; ++j)
#pragma unroll
      for (int r = 0; r < 4; ++r) {
        const int row = m0 + wr * 64 + i * 16 + lg * 4 + r;
        const int col = n0 + wc * 64 + j * 16 + l15;
        P[(size_t)row * N + col] = acc[i][j][r];
      }
}

// ================================================= MERGED: flash attention (blocks < 2048) +
// late weight transposes (blocks >= 2048). grid 8448
__global__ __launch_bounds__(256, 3) void attn_mfma(const u16* __restrict__ Qh,
    const u16* __restrict__ Ql, float* __restrict__ Opart, float2* __restrict__ ml,
    const float* __restrict__ wo, const float* __restrict__ wg,
    const float* __restrict__ wu, const float* __restrict__ wd,
    u16* __restrict__ woT2, u16* __restrict__ wgT, u16* __restrict__ wuT,
    u16* __restrict__ wdT) {
  __shared__ __align__(16) char smem[44032];
  const int bid = blockIdx.x;
  const int tid = threadIdx.x;

  if (bid >= 2048) {
    // ------------------- weight transpose path (reuses smem as float[64][65])
    float (*t_)[65] = (float (*)[65])smem;
    const int b2 = bid - 2048;
    const float* W; u16* out; bool split;
    int n0, k0;
    if (b2 < 256) {
      W = wo; out = woT2; split = true;
      n0 = (b2 & 15) * 64; k0 = (b2 >> 4) * 64;
    } else {
      int r = b2 - 256;
      if (r < 2048)       { const int e = r >> 8; W = wg + (size_t)e * 1048576; out = wgT + (size_t)e * 1048576; }
      else if (r < 4096)  { r -= 2048; const int e = r >> 8; W = wu + (size_t)e * 1048576; out = wuT + (size_t)e * 1048576; }
      else                { r -= 4096; const int e = r >> 8; W = wd + (size_t)e * 1048576; out = wdT + (size_t)e * 1048576; }
      split = false;
      r &= 255; n0 = (r & 15) * 64; k0 = (r >> 4) * 64;
    }
    const int rr = tid >> 4, c4 = (tid & 15) * 4;
#pragma unroll
    for (int i = 0; i < 4; ++i) {
      const float4 v = *(const float4*)(W + (size_t)(k0 + rr + i * 16) * 1024 + n0 + c4);
      t_[rr + i * 16][c4 + 0] = v.x; t_[rr + i * 16][c4 + 1] = v.y;
      t_[rr + i * 16][c4 + 2] = v.z; t_[rr + i * 16][c4 + 3] = v.w;
    }
    __syncthreads();
    if (split) {
#pragma unroll
      for (int i = 0; i < 4; ++i) {
        const int n = n0 + rr + i * 16;
        u16* oh = out + (size_t)n * 2048 + k0 + c4;
        const float v0 = t_[c4 + 0][rr + i * 16], v1 = t_[c4 + 1][rr + i * 16];
        const float v2 = t_[c4 + 2][rr + i * 16], v3 = t_[c4 + 3][rr + i * 16];
        *(u64*)(void*)oh = pack4bf(v0, v1, v2, v3);
        *(u64*)(void*)(oh + 1024) = pack4bf(v0 - bf2f(f2bf(v0)), v1 - bf2f(f2bf(v1)),
                                            v2 - bf2f(f2bf(v2)), v3 - bf2f(f2bf(v3)));
      }
    } else {
#pragma unroll
      for (int i = 0; i < 4; ++i) {
        const int n = n0 + rr + i * 16;
        *(u64*)(void*)(out + (size_t)n * 1024 + k0 + c4) =
            pack4bf(t_[c4 + 0][rr + i * 16], t_[c4 + 1][rr + i * 16],
                    t_[c4 + 2][rr + i * 16], t_[c4 + 3][rr + i * 16]);
      }
    }
    return;
  }

  // ------------------- attention path (LDS carved from smem)
  u16* Kh  = (u16*)(smem);               // 8192B
  u16* Kl  = (u16*)(smem + 8192);        // 8192B
  u16* Vth = (u16*)(smem + 16384);       // 9216B
  u16* Vtl = (u16*)(smem + 25600);       // 9216B
  u16* Pp  = (u16*)(smem + 34816);       // 9216B = 4 waves x 16 x 72 u16

  const int b = bid;
  const int head = (b & 7) + 8 * ((b >> 3) & 1);
  const int qb = 31 - ((b >> 4) & 31);
  const int sp = (b >> 9) & 3;
  const int q0 = qb * 64;
  const int ktiles = qb + 1;
  const int kbase = ktiles >> 2, krem = ktiles & 3;
  const int t0 = sp * kbase + (sp < krem ? sp : krem);
  const int t1 = t0 + kbase + (sp < krem ? 1 : 0);
  const int w = tid >> 6, lane = tid & 63;
  const int l15 = lane & 15, lg = lane >> 4;

  short8 qh[2], qlo[2];
  {
    const size_t qbase = (size_t)(q0 + w * 16 + l15) * 3072 + head * 64;
    qh[0]  = *(const short8*)(const void*)(Qh + qbase + lg * 8);
    qh[1]  = *(const short8*)(const void*)(Qh + qbase + 32 + lg * 8);
    qlo[0] = *(const short8*)(const void*)(Ql + qbase + lg * 8);
    qlo[1] = *(const short8*)(const void*)(Ql + qbase + 32 + lg * 8);
  }
  f32x4 oacc[4] = {};
  float m_run = -__builtin_inff(), l_run = 0.f;
  const int qrow0 = q0 + w * 16 + lg * 4;
  const int qcol  = q0 + w * 16 + l15;

  const int vhl = tid >> 7, rem = tid & 127;
  const int vkq = rem & 15, vdg = rem >> 4;
  const u16* vbase = (vhl ? Ql : Qh) + 2048 + head * 64 + vdg * 8;
  u16* vdst = vhl ? Vtl : Vth;
  short8 vr[4];

  auto STAGEK = [&](int kt) {
#pragma unroll
    for (int i = 0; i < 2; ++i) {
      const int inst = w * 2 + i;
      const int key = inst * 8 + (lane >> 3);
      const int db = ((lane & 7) * 16) ^ ((key & 7) << 4);
      gl_lds16((const char*)(Qh + (size_t)(kt * 64 + key) * 3072 + 1024 + head * 64) + db,
               (char*)Kh + inst * 1024);
      gl_lds16((const char*)(Ql + (size_t)(kt * 64 + key) * 3072 + 1024 + head * 64) + db,
               (char*)Kl + inst * 1024);
    }
  };
  auto VLOAD = [&](int kt) {
    const u16* vs = vbase + (size_t)(kt * 64 + vkq * 4) * 3072;
    vr[0] = *(const short8*)(const void*)vs;
    vr[1] = *(const short8*)(const void*)(vs + 3072);
    vr[2] = *(const short8*)(const void*)(vs + 6144);
    vr[3] = *(const short8*)(const void*)(vs + 9216);
  };
  auto VWRITE = [&]() {
#pragma unroll
    for (int jj = 0; jj < 8; ++jj) {
      const u64 pk = (u64)(u16)vr[0][jj] | ((u64)(u16)vr[1][jj] << 16) |
                     ((u64)(u16)vr[2][jj] << 32) | ((u64)(u16)vr[3][jj] << 48);
      *(u64*)(void*)(vdst + (vdg * 8 + jj) * 72 + vkq * 4) = pk;
    }
  };

  if (t0 < t1) {
    STAGEK(t0);
    VLOAD(t0);
    VWRITE();
    __syncthreads();
  }
  for (int t = t0; t < t1; ++t) {
    const int k0 = t * 64;
    const bool more = (t + 1 < t1);
    f32x4 sacc[4];
    __builtin_amdgcn_s_setprio(1);
#pragma unroll
    for (int nt = 0; nt < 4; ++nt) {
      const int key = nt * 16 + l15;
      const char* kbh = (const char*)Kh + key * 128;
      const char* kbl = (const char*)Kl + key * 128;
      const int sw = (key & 7) << 4;
      const short8 kh0 = *(const short8*)(const void*)(kbh + ((lg * 16) ^ sw));
      const short8 kh1 = *(const short8*)(const void*)(kbh + ((64 + lg * 16) ^ sw));
      const short8 kl0 = *(const short8*)(const void*)(kbl + ((lg * 16) ^ sw));
      const short8 kl1 = *(const short8*)(const void*)(kbl + ((64 + lg * 16) ^ sw));
      f32x4 s = {};
      s = mfma16(kh0, qh[0], s);  s = mfma16(kh1, qh[1], s);
      s = mfma16(kh0, qlo[0], s); s = mfma16(kh1, qlo[1], s);
      s = mfma16(kl0, qh[0], s);  s = mfma16(kl1, qh[1], s);
      sacc[nt] = s;
    }
    __builtin_amdgcn_s_setprio(0);
    __syncthreads();                  // B1: K reads done
    if (more) { STAGEK(t + 1); VLOAD(t + 1); }
#pragma unroll
    for (int nt = 0; nt < 4; ++nt)
#pragma unroll
      for (int r = 0; r < 4; ++r) sacc[nt][r] *= SCL2;
    if (t == qb) {
#pragma unroll
      for (int nt = 0; nt < 4; ++nt) {
        const int keyb = k0 + nt * 16 + lg * 4;
#pragma unroll
        for (int r = 0; r < 4; ++r)
          if (keyb + r > qcol) sacc[nt][r] = -__builtin_inff();
      }
    }
    float mx = sacc[0][0];
#pragma unroll
    for (int nt = 0; nt < 4; ++nt)
#pragma unroll
      for (int r = 0; r < 4; ++r) mx = fmaxf(mx, sacc[nt][r]);
    mx = fmaxf(mx, __shfl_xor(mx, 16, 64));
    mx = fmaxf(mx, __shfl_xor(mx, 32, 64));
    const bool grow = mx > m_run + 8.f;
    if (__any(grow)) {
      const float m_new = fmaxf(m_run, mx);
      const float fac = __builtin_amdgcn_exp2f(m_run - m_new);
      m_run = m_new;
      l_run *= fac;
      float facB[4];
#pragma unroll
      for (int r = 0; r < 4; ++r) facB[r] = __shfl(fac, lg * 4 + r, 64);
#pragma unroll
      for (int nd = 0; nd < 4; ++nd)
#pragma unroll
        for (int r = 0; r < 4; ++r) oacc[nd][r] *= facB[r];
    }
    float ls = 0.f;
#pragma unroll
    for (int nt = 0; nt < 4; ++nt)
#pragma unroll
      for (int r = 0; r < 4; ++r) {
        sacc[nt][r] = __builtin_amdgcn_exp2f(sacc[nt][r] - m_run);
        ls += sacc[nt][r];
      }
    ls += __shfl_xor(ls, 16, 64);
    ls += __shfl_xor(ls, 32, 64);
    l_run += ls;
    u16* prow = Pp + w * 1152 + l15 * 72;
#pragma unroll
    for (int nt = 0; nt < 4; ++nt) {
      const u64 pk = (u64)(__float_as_uint(sacc[nt][0]) >> 16) |
                     ((u64)(__float_as_uint(sacc[nt][1]) >> 16) << 16) |
                     ((u64)(__float_as_uint(sacc[nt][2]) >> 16) << 32) |
                     ((u64)(__float_as_uint(sacc[nt][3]) >> 16) << 48);
      *(u64*)(void*)(prow + nt * 16 + lg * 4) = pk;
    }
    __builtin_amdgcn_s_setprio(1);
#pragma unroll
    for (int kk2 = 0; kk2 < 2; ++kk2) {
      const short8 pa = *(const short8*)(const void*)((const char*)prow + kk2 * 64 + lg * 16);
#pragma unroll
      for (int nd = 0; nd < 4; ++nd) {
        const short8 vbh = *(const short8*)(const void*)((const char*)Vth + (nd * 16 + l15) * 144 + kk2 * 64 + lg * 16);
        const short8 vbl = *(const short8*)(const void*)((const char*)Vtl + (nd * 16 + l15) * 144 + kk2 * 64 + lg * 16);
        oacc[nd] = mfma16(pa, vbh, oacc[nd]);
        oacc[nd] = mfma16(pa, vbl, oacc[nd]);
      }
    }
    __builtin_amdgcn_s_setprio(0);
    asm volatile("" ::: "memory");
#pragma unroll
    for (int nt = 0; nt < 4; ++nt) {
      float lo[4];
#pragma unroll
      for (int r = 0; r < 4; ++r)
        lo[r] = sacc[nt][r] - __uint_as_float(__float_as_uint(sacc[nt][r]) & 0xFFFF0000u);
      const u64 pk = (u64)(__float_as_uint(lo[0]) >> 16) |
                     ((u64)(__float_as_uint(lo[1]) >> 16) << 16) |
                     ((u64)(__float_as_uint(lo[2]) >> 16) << 32) |
                     ((u64)(__float_as_uint(lo[3]) >> 16) << 48);
      *(u64*)(void*)(prow + nt * 16 + lg * 4) = pk;
    }
    asm volatile("" ::: "memory");
    __builtin_amdgcn_s_setprio(1);
#pragma unroll
    for (int kk2 = 0; kk2 < 2; ++kk2) {
      const short8 pa = *(const short8*)(const void*)((const char*)prow + kk2 * 64 + lg * 16);
#pragma unroll
      for (int nd = 0; nd < 4; ++nd) {
        const short8 vbh = *(const short8*)(const void*)((const char*)Vth + (nd * 16 + l15) * 144 + kk2 * 64 + lg * 16);
        oacc[nd] = mfma16(pa, vbh, oacc[nd]);
      }
    }
    __builtin_amdgcn_s_setprio(0);
    __syncthreads();                  // B2
    if (more) VWRITE();
  }
  float* Op = Opart + (size_t)sp * S * 1024;
#pragma unroll
  for (int nd = 0; nd < 4; ++nd)
#pragma unroll
    for (int r = 0; r < 4; ++r)
      Op[(size_t)(qrow0 + r) * 1024 + head * 64 + nd * 16 + l15] = oacc[nd][r];
  if (lg == 0) {
    ml[((size_t)sp * S + q0 + w * 16 + l15) * NH + head] = make_float2(m_run, l_run);
  }
}

// ================================================= combine 4 split-K attention partials
__global__ __launch_bounds__(256) void attn_combine(const float* __restrict__ Op,
    const float2* __restrict__ ml, u16* __restrict__ OA2) {
  const int t = blockIdx.x, tid = threadIdx.x;
  const int h = tid >> 4, dq = (tid & 15) * 4;
  float2 a[4];
  float M = -__builtin_inff();
#pragma unroll
  for (int c = 0; c < 4; ++c) {
    a[c] = ml[((size_t)c * S + t) * NH + h];
    if (a[c].y > 0.f) M = fmaxf(M, a[c].x);
  }
  float e[4], denom = 0.f;
#pragma unroll
  for (int c = 0; c < 4; ++c) {
    e[c] = (a[c].y > 0.f) ? exp2f(a[c].x - M) : 0.f;
    denom += e[c] * a[c].y;
  }
  const float inv = 1.f / denom;
  float ov[4] = {0.f, 0.f, 0.f, 0.f};
#pragma unroll
  for (int c = 0; c < 4; ++c) {
    const float4 v = *(const float4*)(Op + ((size_t)c * S + t) * 1024 + h * 64 + dq);
    ov[0] += e[c] * v.x; ov[1] += e[c] * v.y; ov[2] += e[c] * v.z; ov[3] += e[c] * v.w;
  }
#pragma unroll
  for (int c2 = 0; c2 < 4; ++c2) {
    const float o = ov[c2] * inv;
    const size_t idx = (size_t)t * 2048 + h * 64 + dq + c2;
    const u16 hb = f2bf(o);
    OA2[idx] = hb;
    OA2[idx + 1024] = f2bf(o - bf2f(hb));
  }
}

// ================================================= res2 (4 partials) + rmsnorm2 + gate (no atomics)
__global__ __launch_bounds__(256) void rmsnorm_res2_gate(const float* __restrict__ hidden,
    const float* __restrict__ p01, const float* __restrict__ w2, const float* __restrict__ GW,
    float* __restrict__ out, u16* __restrict__ yb,
    int* __restrict__ top2, float2* __restrict__ topw) {
  const int t = blockIdx.x;
  const int d0 = threadIdx.x * 4;
  const size_t base = (size_t)t * D + d0;
  const float4 h4 = *(const float4*)(hidden + base);
  const float4 a4 = *(const float4*)(p01 + base);
  const float4 b4 = *(const float4*)(p01 + (size_t)S * D + base);
  const float4 c4 = *(const float4*)(p01 + 2 * (size_t)S * D + base);
  const float4 e4 = *(const float4*)(p01 + 3 * (size_t)S * D + base);
  float v[4] = {h4.x + a4.x + b4.x + c4.x + e4.x, h4.y + a4.y + b4.y + c4.y + e4.y,
                h4.z + a4.z + b4.z + c4.z + e4.z, h4.w + a4.w + b4.w + c4.w + e4.w};
  float ss = v[0] * v[0] + v[1] * v[1] + v[2] * v[2] + v[3] * v[3];
#pragma unroll
  for (int m = 32; m >= 1; m >>= 1) ss += __shfl_xor(ss, m, 64);
  __shared__ float red[4];
  if ((threadIdx.x & 63) == 0) red[threadIdx.x >> 6] = ss;
  __syncthreads();
  const float rs = rsqrtf((red[0] + red[1] + red[2] + red[3]) * (1.f / (float)D) + EPS);
  const float4 w4 = *(const float4*)(w2 + d0);
  const float y[4] = {v[0] * rs * w4.x, v[1] * rs * w4.y, v[2] * rs * w4.z, v[3] * rs * w4.w};
  *(float4*)(out + base) = make_float4(v[0], v[1], v[2], v[3]);
  *(u64*)(void*)(yb + base) = pack4bf(y[0], y[1], y[2], y[3]);
  float lg[8] = {};
#pragma unroll
  for (int j = 0; j < 4; ++j) {
    const float4 g0 = *(const float4*)(GW + (d0 + j) * 8);
    const float4 g1 = *(const float4*)(GW + (d0 + j) * 8 + 4);
    lg[0] += y[j] * g0.x; lg[1] += y[j] * g0.y; lg[2] += y[j] * g0.z; lg[3] += y[j] * g0.w;
    lg[4] += y[j] * g1.x; lg[5] += y[j] * g1.y; lg[6] += y[j] * g1.z; lg[7] += y[j] * g1.w;
  }
#pragma unroll
  for (int e = 0; e < 8; ++e)
#pragma unroll
    for (int m = 32; m >= 1; m >>= 1) lg[e] += __shfl_xor(lg[e], m, 64);
  __shared__ float wred[4][8];
  if ((threadIdx.x & 63) == 0)
#pragma unroll
    for (int e = 0; e < 8; ++e) wred[threadIdx.x >> 6][e] = lg[e];
  __syncthreads();
  if (threadIdx.x == 0) {
    float L[8];
#pragma unroll
    for (int e = 0; e < 8; ++e) L[e] = wred[0][e] + wred[1][e] + wred[2][e] + wred[3][e];
    int i0 = 0; float v0 = L[0];
    for (int i = 1; i < 8; ++i) if (L[i] > v0) { v0 = L[i]; i0 = i; }
    int i1 = -1; float v1 = -__builtin_inff();
    for (int i = 0; i < 8; ++i) if (i != i0 && L[i] > v1) { v1 = L[i]; i1 = i; }
    const float e1 = expf(v1 - v0);
    const float inv = 1.f / (1.f + e1);
    top2[t] = i0 | (i1 << 4);
    topw[t] = make_float2(inv, e1 * inv);
  }
}

// ================================================= scatter compact: deterministic prefix-scan
__global__ __launch_bounds__(1024) void scatter_compact(const int* __restrict__ top2,
    const float2* __restrict__ topw, int* __restrict__ counts,
    int* __restrict__ tok_map, float* __restrict__ w_map) {
  const int tid = threadIdx.x;
  __shared__ u64 s0[1024], s1[1024];
  int e_[2][2]; float w_[2][2];
  u64 c0 = 0, c1 = 0;
#pragma unroll
  for (int k = 0; k < 2; ++k) {
    const int t = tid * 2 + k;
    const int pk = top2[t];
    const float2 wv = topw[t];
    e_[k][0] = pk & 15; e_[k][1] = (pk >> 4) & 15;
    w_[k][0] = wv.x;    w_[k][1] = wv.y;
#pragma unroll
    for (int s = 0; s < 2; ++s) {
      const int e = e_[k][s];
      if (e < 4) c0 += 1ull << (e * 16); else c1 += 1ull << ((e - 4) * 16);
    }
  }
  s0[tid] = c0; s1[tid] = c1;
  __syncthreads();
  for (int off = 1; off < 1024; off <<= 1) {
    const u64 a0 = (tid >= off) ? s0[tid - off] : 0;
    const u64 a1 = (tid >= off) ? s1[tid - off] : 0;
    __syncthreads();
    s0[tid] += a0; s1[tid] += a1;
    __syncthreads();
  }
  if (tid == 1023) {
#pragma unroll
    for (int e = 0; e < 4; ++e) counts[e] = (int)((s0[1023] >> (e * 16)) & 0xFFFF);
#pragma unroll
    for (int e = 4; e < 8; ++e) counts[e] = (int)((s1[1023] >> ((e - 4) * 16)) & 0xFFFF);
  }
  u64 l0 = s0[tid] - c0, l1 = s1[tid] - c1;
#pragma unroll
  for (int k = 0; k < 2; ++k) {
    const int t = tid * 2 + k;
#pragma unroll
    for (int s = 0; s < 2; ++s) {
      const int e = e_[k][s];
      int p;
      if (e < 4) { p = (int)((l0 >> (e * 16)) & 0xFFFF); l0 += 1ull << (e * 16); }
      else       { p = (int)((l1 >> ((e - 4) * 16)) & 0xFFFF); l1 += 1ull << ((e - 4) * 16); }
      tok_map[e * S + p] = t | (s << 16);
      w_map[e * S + p] = w_[k][s];
    }
  }
}

// ================================================= MoE gate/up GEMM: 128x64 tile, dual-B, dbuf
__global__ __launch_bounds__(256) void moe_gu(const u16* __restrict__ Yb,
    const u16* __restrict__ Wgb, const u16* __restrict__ Wub, u16* __restrict__ Hb,
    const int* __restrict__ counts, const int* __restrict__ tokmap) {
  const int b = blockIdx.x;
  const int e = b & 7, ii = b >> 3;
  const int n0 = (ii & 15) * 64;
  const int m0 = (ii >> 4) * 128;
  const int cnt = counts[e];
  if (m0 >= cnt) return;
  __shared__ u16 SH[2][16 * 512];
  const int tid = threadIdx.x, wv = tid >> 6, lane = tid & 63;
  const int l15 = lane & 15, lg = lane >> 4;
  const int wr = wv >> 1, wc = wv & 1;
  const int sr = lane >> 2, sk = (lane & 3) * 16;
  const u16* B1 = Wgb + (size_t)e * 1048576;
  const u16* B2 = Wub + (size_t)e * 1048576;
  const u16* cp[4];
#pragma unroll
  for (int i = 0; i < 4; ++i) {
    const int c = wv * 4 + i;
    if (c < 8) {
      const int arow = m0 + c * 16 + sr;
      const int tok = tokmap[e * S + arow] & 2047;
      cp[i] = Yb + (size_t)tok * 1024;
    } else if (c < 12) {
      cp[i] = B1 + (size_t)(n0 + (c - 8) * 16 + sr) * 1024;
    } else {
      cp[i] = B2 + (size_t)(n0 + (c - 12) * 16 + sr) * 1024;
    }
  }
  auto STAGE = [&](int buf, int k) {
#pragma unroll
    for (int i = 0; i < 4; ++i) {
      const int c = wv * 4 + i;
      gl_lds16((const char*)(cp[i] + k) + sk, (char*)SH + buf * 16384 + c * 1024);
    }
  };
  f32x4 acc1[4][2] = {};
  f32x4 acc2[4][2] = {};
  STAGE(0, 0);
  __syncthreads();
  int cur = 0;
  for (int kk = 0; kk < 32; ++kk) {
    if (kk < 31) STAGE(cur ^ 1, (kk + 1) * 32);
    const u16* Sb = (const u16*)SH + cur * 8192;
    short8 a[4], b1f[2], b2f[2];
#pragma unroll
    for (int i = 0; i < 4; ++i)
      a[i] = *(const short8*)(const void*)(Sb + (size_t)(wr * 64 + i * 16 + l15) * 32 + lg * 8);
#pragma unroll
    for (int j = 0; j < 2; ++j) {
      b1f[j] = *(const short8*)(const void*)(Sb + 4096 + (size_t)(wc * 32 + j * 16 + l15) * 32 + lg * 8);
      b2f[j] = *(const short8*)(const void*)(Sb + 6144 + (size_t)(wc * 32 + j * 16 + l15) * 32 + lg * 8);
    }
    __builtin_amdgcn_s_setprio(1);
#pragma unroll
    for (int i = 0; i < 4; ++i)
#pragma unroll
      for (int j = 0; j < 2; ++j) {
        acc1[i][j] = mfma16(a[i], b1f[j], acc1[i][j]);
        acc2[i][j] = mfma16(a[i], b2f[j], acc2[i][j]);
      }
    __builtin_amdgcn_s_setprio(0);
    __syncthreads();
    cur ^= 1;
  }
#pragma unroll
  for (int i = 0; i < 4; ++i)
#pragma unroll
    for (int j = 0; j < 2; ++j)
#pragma unroll
      for (int r = 0; r < 4; ++r) {
        const int row = m0 + wr * 64 + i * 16 + lg * 4 + r;
        if (row < cnt) {
          const float g = acc1[i][j][r];
          const float u = acc2[i][j][r];
          const float sig = __builtin_amdgcn_rcpf(1.f + __builtin_amdgcn_exp2f(-g * LOG2E));
          Hb[((size_t)e * 2048 + row) * 1024 + n0 + wc * 32 + j * 16 + l15] = f2bf(u * g * sig);
        }
      }
}

// ================================================= MoE down GEMM: split-K x2 -> 4 bf16 slot planes
__global__ __launch_bounds__(256) void moe_down(const u16* __restrict__ Hb,
    const u16* __restrict__ Wdb, u16* __restrict__ slotp,
    const int* __restrict__ counts, const int* __restrict__ tokmap,
    const float* __restrict__ wmap) {
  const int b = blockIdx.x;
  const int e = b & 7, ii = b >> 3;
  const int m0 = (ii & 15) * 128;
  const int n0 = ((ii >> 4) & 7) * 128;
  const int ks = ii >> 7;
  const int cnt = counts[e];
  if (m0 >= cnt) return;
  __shared__ u16 As[2][128 * 32];
  __shared__ u16 Bs[2][128 * 32];
  const int tid = threadIdx.x, wv = tid >> 6, lane = tid & 63;
  const int l15 = lane & 15, lg = lane >> 4;
  const int wr = wv >> 1, wc = wv & 1;
  const int sr = lane >> 2, sk = (lane & 3) * 16;
  const u16* B = Wdb + (size_t)e * 1048576;
  const u16* aptr[2]; const u16* bptr[2];
#pragma unroll
  for (int i = 0; i < 2; ++i) {
    aptr[i] = Hb + ((size_t)e * 2048 + m0 + (wv * 2 + i) * 16 + sr) * 1024;
    bptr[i] = B + (size_t)(n0 + (wv * 2 + i) * 16 + sr) * 1024;
  }
  auto STAGE = [&](int buf, int k) {
#pragma unroll
    for (int i = 0; i < 2; ++i) {
      gl_lds16((const char*)(aptr[i] + k) + sk, (char*)As + buf * 8192 + (wv * 2 + i) * 1024);
      gl_lds16((const char*)(bptr[i] + k) + sk, (char*)Bs + buf * 8192 + (wv * 2 + i) * 1024);
    }
  };
  f32x4 acc[4][4] = {};
  const int kb0 = ks * 16, kb1 = kb0 + 16;
  STAGE(0, kb0 * 32);
  __syncthreads();
  int cur = 0;
  for (int kk = kb0; kk < kb1; ++kk) {
    if (kk + 1 < kb1) STAGE(cur ^ 1, (kk + 1) * 32);
    const u16* Ab = (const u16*)As + cur * 4096;
    const u16* Bb = (const u16*)Bs + cur * 4096;
    short8 a[4], bb[4];
#pragma unroll
    for (int i = 0; i < 4; ++i)
      a[i] = *(const short8*)(const void*)(Ab + (size_t)(wr * 64 + i * 16 + l15) * 32 + lg * 8);
#pragma unroll
    for (int j = 0; j < 4; ++j)
      bb[j] = *(const short8*)(const void*)(Bb + (size_t)(wc * 64 + j * 16 + l15) * 32 + lg * 8);
    __builtin_amdgcn_s_setprio(1);
#pragma unroll
    for (int i = 0; i < 4; ++i)
#pragma unroll
      for (int j = 0; j < 4; ++j) acc[i][j] = mfma16(a[i], bb[j], acc[i][j]);
    __builtin_amdgcn_s_setprio(0);
    __syncthreads();
    cur ^= 1;
  }
#pragma unroll
  for (int i = 0; i < 4; ++i)
#pragma unroll
    for (int j = 0; j < 4; ++j)
#pragma unroll
      for (int r = 0; r < 4; ++r) {
        const int row = m0 + wr * 64 + i * 16 + lg * 4 + r;
        if (row < cnt) {
          const int raw = tokmap[e * S + row];
          const int t = raw & 2047;
          const int sl = (raw >> 16) & 1;
          const float wgt = wmap[e * S + row];
          slotp[((size_t)(sl * 2 + ks) * S + t) * 1024 + n0 + wc * 64 + j * 16 + l15] =
              f2bf(wgt * acc[i][j][r]);
        }
      }
}

// ================================================= final add: out += sum of 4 slot planes
__global__ __launch_bounds__(256) void final_add(float* __restrict__ out,
    const u16* __restrict__ sp) {
  const size_t i = ((size_t)blockIdx.x * 256 + threadIdx.x) * 4;
  float4 o = *(float4*)(out + i);
#pragma unroll
  for (int c = 0; c < 4; ++c) {
    const u64 a = *(const u64*)(sp + (size_t)c * S * D + i);
    o.x += bf2f((u16)(a));
    o.y += bf2f((u16)(a >> 16));
    o.z += bf2f((u16)(a >> 32));
    o.w += bf2f((u16)(a >> 48));
  }
  *(float4*)(out + i) = o;
}

// ================================================= launch
extern "C" void kernel_launch(void* const* d_in, const int* in_sizes, int n_in,
                              void* d_out, int out_size, void* d_ws, size_t ws_size,
                              hipStream_t stream) {
  const int*   positions = (const int*)d_in[0];
  const float* hidden    = (const float*)d_in[1];
  const float* ln1_w  = (const float*)d_in[3];
  const float* ln2_w  = (const float*)d_in[4];
  const float* wqkv   = (const float*)d_in[5];
  const float* wo     = (const float*)d_in[6];
  const float* gate_w = (const float*)d_in[7];
  const float* wg     = (const float*)d_in[8];
  const float* wu     = (const float*)d_in[9];
  const float* wd     = (const float*)d_in[10];
  float* out = (float*)d_out;

  char* ws = (char*)d_ws;
  const size_t MB = 1ull << 20;
  u16* wqkvT2 = (u16*)(ws);
  u16* QKVh   = (u16*)(ws);
  u16* OA2    = (u16*)(ws);
  u16* woT2   = (u16*)(ws + 12 * MB);       // 4MB  (merged attn -> gemm_wo)
  u16* wgT    = (u16*)(ws + 16 * MB);       // 16MB
  u16* wuT    = (u16*)(ws + 32 * MB);       // 16MB
  u16* wdT    = (u16*)(ws + 48 * MB);       // 16MB
  float2* ropetab = (float2*)(ws + 64 * MB);            // 512KB
  float2* ml      = (float2*)(ws + 64 * MB + 524288);   // 1MB
  char* mapb = ws + 64 * MB + 1572864;
  int*   counts   = (int*)mapb;
  int*   tok_map  = (int*)(mapb + 512);
  float* w_map    = (float*)(mapb + 512 + 65536);
  int*   top2     = (int*)(mapb + 512 + 131072);
  float2* topw    = (float2*)(mapb + 512 + 139264);
  u16* xn2    = (u16*)(ws + 66 * MB);       // 8MB  (ph1-2)
  u16* QKVl   = (u16*)(ws + 66 * MB);       // 12MB (ph3-4, xn2 dead)
  u16* yb     = (u16*)(ws + 66 * MB);       // 4MB  (ph6+, QKVl dead)
  float* Cpart  = (float*)(ws + 78 * MB);   // 48MB (ph2-3)
  float* Opart  = (float*)(ws + 78 * MB);   // 32MB (ph4, Cpart dead)
  float* p01    = (float*)(ws + 78 * MB);   // 32MB (ph5-6)
  u16* Hb     = (u16*)(ws + 78 * MB);       // 32MB (ph7)
  u16* slotp  = (u16*)(ws + 110 * MB);      // 16MB (ph7-8)

  prep_early<<<3072, 256, 0, stream>>>(wqkv, positions, hidden, ln1_w,
                                       wqkvT2, ropetab, xn2);
  gemm_qkv<<<768, 256, 0, stream>>>(xn2, wqkvT2, Cpart);
  qkv_combine<<<S, 256, 0, stream>>>(Cpart, ropetab, QKVh, QKVl);
  attn_mfma<<<8448, 256, 0, stream>>>(QKVh, QKVl, Opart, ml,
                                      wo, wg, wu, wd, woT2, wgT, wuT, wdT);
  attn_combine<<<S, 256, 0, stream>>>(Opart, ml, OA2);
  gemm_wo<<<512, 256, 0, stream>>>(OA2, woT2, p01);
  rmsnorm_res2_gate<<<S, 256, 0, stream>>>(hidden, p01, ln2_w, gate_w, out, yb, top2, topw);
  scatter_compact<<<1, 1024, 0, stream>>>(top2, topw, counts, tok_map, w_map);
  moe_gu<<<2048, 256, 0, stream>>>(yb, wgT, wuT, Hb, counts, tok_map);
  moe_down<<<2048, 256, 0, stream>>>(Hb, wdT, slotp, counts, tok_map, w_map);
  final_add<<<2048, 256, 0, stream>>>(out, slotp);
}

// Round 19
// 266.194 us; speedup vs baseline: 1.0595x; 1.0048x over previous
//
#include <hip/hip_runtime.h>
#include <math.h>

constexpr int S  = 2048;
constexpr int D  = 1024;
constexpr int NH = 16;
constexpr int NE = 8;
constexpr float EPS   = 1e-6f;
constexpr float THETA = 10000.0f;
constexpr float SCL2  = 0.125f * 1.4426950408889634f;  // attn scale * log2(e)
constexpr float LOG2E = 1.4426950408889634f;

typedef unsigned short u16;
typedef unsigned int   u32;
typedef unsigned long long u64;
typedef __attribute__((ext_vector_type(8))) short short8;
typedef __attribute__((ext_vector_type(4))) float f32x4;

__device__ __forceinline__ u16 f2bf(float x) {
  union { float f; u32 u; } v; v.f = x;
  u32 r = (v.u + 0x7FFFu + ((v.u >> 16) & 1u)) >> 16;
  return (u16)r;
}
__device__ __forceinline__ float bf2f(u16 h) {
  union { u32 u; float f; } v; v.u = ((u32)h) << 16;
  return v.f;
}
__device__ __forceinline__ f32x4 mfma16(short8 a, short8 b, f32x4 c) {
  return __builtin_amdgcn_mfma_f32_16x16x32_bf16(a, b, c, 0, 0, 0);
}
__device__ __forceinline__ void gl_lds16(const void* g, void* l) {
  __builtin_amdgcn_global_load_lds((const __attribute__((address_space(1))) u32*)g,
                                   (__attribute__((address_space(3))) u32*)l, 16, 0, 0);
}
__device__ __forceinline__ u64 pack4bf(float a, float b, float c, float d) {
  return (u64)f2bf(a) | ((u64)f2bf(b) << 16) | ((u64)f2bf(c) << 32) | ((u64)f2bf(d) << 48);
}

// ================================================= prep_early: wqkv transpose + rope + rmsnorm
// [0,768): wqkv split-T; [768,1024): rope tab; [1024,3072): rmsnorm_split rows
__global__ __launch_bounds__(256) void prep_early(const float* __restrict__ wqkv,
    const int* __restrict__ positions, const float* __restrict__ hidden,
    const float* __restrict__ ln1_w, u16* __restrict__ wqkvT2,
    float2* __restrict__ ropetab, u16* __restrict__ xn2) {
  const int b = blockIdx.x;
  const int tid = threadIdx.x;
  if (b >= 1024) {  // rmsnorm_split
    const int t = b - 1024;
    const float* xr = hidden + (size_t)t * D;
    float v[4]; float ss = 0.f;
#pragma unroll
    for (int i = 0; i < 4; ++i) { v[i] = xr[tid + i * 256]; ss += v[i] * v[i]; }
#pragma unroll
    for (int m = 32; m >= 1; m >>= 1) ss += __shfl_xor(ss, m, 64);
    __shared__ float red[4];
    if ((tid & 63) == 0) red[tid >> 6] = ss;
    __syncthreads();
    const float rs = rsqrtf((red[0] + red[1] + red[2] + red[3]) * (1.f / (float)D) + EPS);
#pragma unroll
    for (int i = 0; i < 4; ++i) {
      const int d = tid + i * 256;
      const float y = v[i] * rs * ln1_w[d];
      const u16 h = f2bf(y);
      xn2[(size_t)t * 2048 + d] = h;
      xn2[(size_t)t * 2048 + 1024 + d] = f2bf(y - bf2f(h));
    }
    return;
  }
  if (b >= 768) {  // rope table
    const int idx = (b - 768) * 256 + tid;
    const int t = idx >> 5, p = idx & 31;
    const float inv = powf(THETA, -(float)p * (1.f / 32.f));
    const float fr = (float)positions[t] * inv;
    float sn, cs; sincosf(fr, &sn, &cs);
    ropetab[idx] = make_float2(cs, sn);
    return;
  }
  // wqkv split-transpose: W[1024][3072] -> wqkvT2[3072][2048] (hi|lo)
  __shared__ float t_[64][65];
  const int n0 = (b % 48) * 64, k0 = (b / 48) * 64;
  const int rr = tid >> 4, c4 = (tid & 15) * 4;
#pragma unroll
  for (int i = 0; i < 4; ++i) {
    const float4 v = *(const float4*)(wqkv + (size_t)(k0 + rr + i * 16) * 3072 + n0 + c4);
    t_[rr + i * 16][c4 + 0] = v.x; t_[rr + i * 16][c4 + 1] = v.y;
    t_[rr + i * 16][c4 + 2] = v.z; t_[rr + i * 16][c4 + 3] = v.w;
  }
  __syncthreads();
#pragma unroll
  for (int i = 0; i < 4; ++i) {
    const int n = n0 + rr + i * 16;
    u16* oh = wqkvT2 + (size_t)n * 2048 + k0 + c4;
    const float v0 = t_[c4 + 0][rr + i * 16], v1 = t_[c4 + 1][rr + i * 16];
    const float v2 = t_[c4 + 2][rr + i * 16], v3 = t_[c4 + 3][rr + i * 16];
    *(u64*)(void*)oh = pack4bf(v0, v1, v2, v3);
    *(u64*)(void*)(oh + 1024) = pack4bf(v0 - bf2f(f2bf(v0)), v1 - bf2f(f2bf(v1)),
                                        v2 - bf2f(f2bf(v2)), v3 - bf2f(f2bf(v3)));
  }
}

// ================================================= QKV GEMM: 128x128, split-bf16, dbuf, XCD-swz,
// split-K x2 -> f32 partial planes. grid 768. Within XCD: np innermost, then m, then ks.
__global__ __launch_bounds__(256) void gemm_qkv(const u16* __restrict__ A2,
    const u16* __restrict__ Bt2, float* __restrict__ Cpart) {
  __shared__ u16 As[2][128 * 32];
  __shared__ u16 Bs[2][128 * 32];
  const int b = blockIdx.x;
  const int xcd = b & 7, ii = b >> 3;
  const int np = ii % 3;
  const int m0 = ((ii / 3) & 15) * 128;
  const int ks = ii / 48;
  const int n0 = (xcd * 3 + np) * 128;
  const int kk0 = ks * 48, kk1 = kk0 + 48;
  const int tid = threadIdx.x, wv = tid >> 6, lane = tid & 63;
  const int l15 = lane & 15, lg = lane >> 4;
  const int wr = wv >> 1, wc = wv & 1;
  const int sr = lane >> 2, sk = (lane & 3) * 16;
  const u16* aptr[2]; const u16* bptr[2];
#pragma unroll
  for (int i = 0; i < 2; ++i) {
    aptr[i] = A2 + (size_t)(m0 + (wv * 2 + i) * 16 + sr) * 2048;
    bptr[i] = Bt2 + (size_t)(n0 + (wv * 2 + i) * 16 + sr) * 2048;
  }
  auto STAGE = [&](int buf, int kk) {
    const int t = kk * 32;
    int ka, kb;
    if (t < 1024)      { ka = t;        kb = t; }
    else if (t < 2048) { ka = t;        kb = t - 1024; }
    else               { ka = t - 2048; kb = t - 1024; }
#pragma unroll
    for (int i = 0; i < 2; ++i) {
      gl_lds16((const char*)(aptr[i] + ka) + sk, (char*)As + buf * 8192 + (wv * 2 + i) * 1024);
      gl_lds16((const char*)(bptr[i] + kb) + sk, (char*)Bs + buf * 8192 + (wv * 2 + i) * 1024);
    }
  };
  f32x4 acc[4][4] = {};
  STAGE(0, kk0);
  __syncthreads();
  int cur = 0;
  for (int kk = kk0; kk < kk1; ++kk) {
    if (kk + 1 < kk1) STAGE(cur ^ 1, kk + 1);
    const u16* Ab = (const u16*)As + cur * 4096;
    const u16* Bb = (const u16*)Bs + cur * 4096;
    short8 a[4], bb[4];
#pragma unroll
    for (int i = 0; i < 4; ++i)
      a[i] = *(const short8*)(const void*)(Ab + (size_t)(wr * 64 + i * 16 + l15) * 32 + lg * 8);
#pragma unroll
    for (int j = 0; j < 4; ++j)
      bb[j] = *(const short8*)(const void*)(Bb + (size_t)(wc * 64 + j * 16 + l15) * 32 + lg * 8);
    __builtin_amdgcn_s_setprio(1);
#pragma unroll
    for (int i = 0; i < 4; ++i)
#pragma unroll
      for (int j = 0; j < 4; ++j) acc[i][j] = mfma16(a[i], bb[j], acc[i][j]);
    __builtin_amdgcn_s_setprio(0);
    __syncthreads();
    cur ^= 1;
  }
  float* P = Cpart + (size_t)ks * S * 3072;
#pragma unroll
  for (int i = 0; i < 4; ++i)
#pragma unroll
    for (int j = 0; j < 4; ++j)
#pragma unroll
      for (int r = 0; r < 4; ++r) {
        const int row = m0 + wr * 64 + i * 16 + lg * 4 + r;
        const int col = n0 + wc * 64 + j * 16 + l15;
        P[(size_t)row * 3072 + col] = acc[i][j][r];
      }
}

// ================================================= QKV combine: sum 2 planes + rope + hi/lo split
__global__ __launch_bounds__(256) void qkv_combine(const float* __restrict__ Cp,
    const float2* __restrict__ tab, u16* __restrict__ Ch, u16* __restrict__ Cl) {
  const int t = blockIdx.x, tid = threadIdx.x;
  const float* r0 = Cp + (size_t)t * 3072;
  const float* r1 = r0 + (size_t)S * 3072;
  const size_t ob = (size_t)t * 3072;
#pragma unroll
  for (int i = 0; i < 4; ++i) {  // q,k pairs
    const int pi = tid + i * 256;
    const int h = pi >> 5, p = pi & 31;
    const int col = h * 64 + p;
    const float x1 = r0[col] + r1[col];
    const float x2 = r0[col + 32] + r1[col + 32];
    const float2 cs = tab[t * 32 + p];
    const float y1 = x1 * cs.x - x2 * cs.y;
    const float y2 = x1 * cs.y + x2 * cs.x;
    const u16 h1 = f2bf(y1);
    Ch[ob + col] = h1; Cl[ob + col] = f2bf(y1 - bf2f(h1));
    const u16 h2 = f2bf(y2);
    Ch[ob + col + 32] = h2; Cl[ob + col + 32] = f2bf(y2 - bf2f(h2));
  }
#pragma unroll
  for (int i = 0; i < 4; ++i) {  // v
    const int col = 2048 + tid + i * 256;
    const float y = r0[col] + r1[col];
    const u16 h = f2bf(y);
    Ch[ob + col] = h; Cl[ob + col] = f2bf(y - bf2f(h));
  }
}

// ================================================= Wo GEMM: 128x128, split-bf16, dbuf, Kx4.
// xcd owns 2 m-panels; ii: n=ii&7, mi=(ii>>3)&1, ks=ii>>4. grid 512
__global__ __launch_bounds__(256) void gemm_wo(const u16* __restrict__ A2,
    const u16* __restrict__ Bt2, float* __restrict__ Pout) {
  constexpr int N = 1024;
  __shared__ u16 As[2][128 * 32];
  __shared__ u16 Bs[2][128 * 32];
  const int b = blockIdx.x;
  const int xcd = b & 7, ii = b >> 3;
  const int n0 = (ii & 7) * 128;
  const int m0 = (xcd * 2 + ((ii >> 3) & 1)) * 128;
  const int ks = ii >> 4;
  const int kk0 = ks * 24, kk1 = kk0 + 24;
  const int tid = threadIdx.x, wv = tid >> 6, lane = tid & 63;
  const int l15 = lane & 15, lg = lane >> 4;
  const int wr = wv >> 1, wc = wv & 1;
  const int sr = lane >> 2, sk = (lane & 3) * 16;
  const u16* aptr[2]; const u16* bptr[2];
#pragma unroll
  for (int i = 0; i < 2; ++i) {
    aptr[i] = A2 + (size_t)(m0 + (wv * 2 + i) * 16 + sr) * 2048;
    bptr[i] = Bt2 + (size_t)(n0 + (wv * 2 + i) * 16 + sr) * 2048;
  }
  auto STAGE = [&](int buf, int kk) {
    const int t = kk * 32;
    int ka, kb;
    if (t < 1024)      { ka = t;        kb = t; }
    else if (t < 2048) { ka = t;        kb = t - 1024; }
    else               { ka = t - 2048; kb = t - 1024; }
#pragma unroll
    for (int i = 0; i < 2; ++i) {
      gl_lds16((const char*)(aptr[i] + ka) + sk, (char*)As + buf * 8192 + (wv * 2 + i) * 1024);
      gl_lds16((const char*)(bptr[i] + kb) + sk, (char*)Bs + buf * 8192 + (wv * 2 + i) * 1024);
    }
  };
  f32x4 acc[4][4] = {};
  STAGE(0, kk0);
  __syncthreads();
  int cur = 0;
  for (int kk = kk0; kk < kk1; ++kk) {
    if (kk + 1 < kk1) STAGE(cur ^ 1, kk + 1);
    const u16* Ab = (const u16*)As + cur * 4096;
    const u16* Bb = (const u16*)Bs + cur * 4096;
    short8 a[4], bb[4];
#pragma unroll
    for (int i = 0; i < 4; ++i)
      a[i] = *(const short8*)(const void*)(Ab + (size_t)(wr * 64 + i * 16 + l15) * 32 + lg * 8);
#pragma unroll
    for (int j = 0; j < 4; ++j)
      bb[j] = *(const short8*)(const void*)(Bb + (size_t)(wc * 64 + j * 16 + l15) * 32 + lg * 8);
    __builtin_amdgcn_s_setprio(1);
#pragma unroll
    for (int i = 0; i < 4; ++i)
#pragma unroll
      for (int j = 0; j < 4; ++j) acc[i][j] = mfma16(a[i], bb[j], acc[i][j]);
    __builtin_amdgcn_s_setprio(0);
    __syncthreads();
    cur ^= 1;
  }
  float* P = Pout + (size_t)ks * S * N;
#pragma unroll
  for (int i = 0; i < 4; ++i)
#pragma unroll
    for (int j = 0; j < 4; ++j)
#pragma unroll
      for (int r = 0; r < 4; ++r) {
        const int row = m0 + wr * 64 + i * 16 + lg * 4 + r;
        const int col = n0 + wc * 64 + j * 16 + l15;
        P[(size_t)row * N + col] = acc[i][j][r];
      }
}

// ================================================= MERGED: flash attention (blocks < 2048) +
// late weight transposes (blocks >= 2048). grid 8448
__global__ __launch_bounds__(256, 3) void attn_mfma(const u16* __restrict__ Qh,
    const u16* __restrict__ Ql, float* __restrict__ Opart, float2* __restrict__ ml,
    const float* __restrict__ wo, const float* __restrict__ wg,
    const float* __restrict__ wu, const float* __restrict__ wd,
    u16* __restrict__ woT2, u16* __restrict__ wgT, u16* __restrict__ wuT,
    u16* __restrict__ wdT) {
  __shared__ __align__(16) char smem[44032];
  const int bid = blockIdx.x;
  const int tid = threadIdx.x;

  if (bid >= 2048) {
    // ------------------- weight transpose path (reuses smem as float[64][65])
    float (*t_)[65] = (float (*)[65])smem;
    const int b2 = bid - 2048;
    const float* W; u16* out; bool split;
    int n0, k0;
    if (b2 < 256) {
      W = wo; out = woT2; split = true;
      n0 = (b2 & 15) * 64; k0 = (b2 >> 4) * 64;
    } else {
      int r = b2 - 256;
      if (r < 2048)       { const int e = r >> 8; W = wg + (size_t)e * 1048576; out = wgT + (size_t)e * 1048576; }
      else if (r < 4096)  { r -= 2048; const int e = r >> 8; W = wu + (size_t)e * 1048576; out = wuT + (size_t)e * 1048576; }
      else                { r -= 4096; const int e = r >> 8; W = wd + (size_t)e * 1048576; out = wdT + (size_t)e * 1048576; }
      split = false;
      r &= 255; n0 = (r & 15) * 64; k0 = (r >> 4) * 64;
    }
    const int rr = tid >> 4, c4 = (tid & 15) * 4;
#pragma unroll
    for (int i = 0; i < 4; ++i) {
      const float4 v = *(const float4*)(W + (size_t)(k0 + rr + i * 16) * 1024 + n0 + c4);
      t_[rr + i * 16][c4 + 0] = v.x; t_[rr + i * 16][c4 + 1] = v.y;
      t_[rr + i * 16][c4 + 2] = v.z; t_[rr + i * 16][c4 + 3] = v.w;
    }
    __syncthreads();
    if (split) {
#pragma unroll
      for (int i = 0; i < 4; ++i) {
        const int n = n0 + rr + i * 16;
        u16* oh = out + (size_t)n * 2048 + k0 + c4;
        const float v0 = t_[c4 + 0][rr + i * 16], v1 = t_[c4 + 1][rr + i * 16];
        const float v2 = t_[c4 + 2][rr + i * 16], v3 = t_[c4 + 3][rr + i * 16];
        *(u64*)(void*)oh = pack4bf(v0, v1, v2, v3);
        *(u64*)(void*)(oh + 1024) = pack4bf(v0 - bf2f(f2bf(v0)), v1 - bf2f(f2bf(v1)),
                                            v2 - bf2f(f2bf(v2)), v3 - bf2f(f2bf(v3)));
      }
    } else {
#pragma unroll
      for (int i = 0; i < 4; ++i) {
        const int n = n0 + rr + i * 16;
        *(u64*)(void*)(out + (size_t)n * 1024 + k0 + c4) =
            pack4bf(t_[c4 + 0][rr + i * 16], t_[c4 + 1][rr + i * 16],
                    t_[c4 + 2][rr + i * 16], t_[c4 + 3][rr + i * 16]);
      }
    }
    return;
  }

  // ------------------- attention path (LDS carved from smem)
  u16* Kh  = (u16*)(smem);               // 8192B
  u16* Kl  = (u16*)(smem + 8192);        // 8192B
  u16* Vth = (u16*)(smem + 16384);       // 9216B
  u16* Vtl = (u16*)(smem + 25600);       // 9216B
  u16* Pp  = (u16*)(smem + 34816);       // 9216B = 4 waves x 16 x 72 u16

  const int b = bid;
  const int head = (b & 7) + 8 * ((b >> 3) & 1);
  const int qb = 31 - ((b >> 4) & 31);
  const int sp = (b >> 9) & 3;
  const int q0 = qb * 64;
  const int ktiles = qb + 1;
  const int kbase = ktiles >> 2, krem = ktiles & 3;
  const int t0 = sp * kbase + (sp < krem ? sp : krem);
  const int t1 = t0 + kbase + (sp < krem ? 1 : 0);
  const int w = tid >> 6, lane = tid & 63;
  const int l15 = lane & 15, lg = lane >> 4;

  short8 qh[2], qlo[2];
  {
    const size_t qbase = (size_t)(q0 + w * 16 + l15) * 3072 + head * 64;
    qh[0]  = *(const short8*)(const void*)(Qh + qbase + lg * 8);
    qh[1]  = *(const short8*)(const void*)(Qh + qbase + 32 + lg * 8);
    qlo[0] = *(const short8*)(const void*)(Ql + qbase + lg * 8);
    qlo[1] = *(const short8*)(const void*)(Ql + qbase + 32 + lg * 8);
  }
  f32x4 oacc[4] = {};
  float m_run = -__builtin_inff(), l_run = 0.f;
  const int qrow0 = q0 + w * 16 + lg * 4;
  const int qcol  = q0 + w * 16 + l15;

  const int vhl = tid >> 7, rem = tid & 127;
  const int vkq = rem & 15, vdg = rem >> 4;
  const u16* vbase = (vhl ? Ql : Qh) + 2048 + head * 64 + vdg * 8;
  u16* vdst = vhl ? Vtl : Vth;
  short8 vr[4];

  auto STAGEK = [&](int kt) {
#pragma unroll
    for (int i = 0; i < 2; ++i) {
      const int inst = w * 2 + i;
      const int key = inst * 8 + (lane >> 3);
      const int db = ((lane & 7) * 16) ^ ((key & 7) << 4);
      gl_lds16((const char*)(Qh + (size_t)(kt * 64 + key) * 3072 + 1024 + head * 64) + db,
               (char*)Kh + inst * 1024);
      gl_lds16((const char*)(Ql + (size_t)(kt * 64 + key) * 3072 + 1024 + head * 64) + db,
               (char*)Kl + inst * 1024);
    }
  };
  auto VLOAD = [&](int kt) {
    const u16* vs = vbase + (size_t)(kt * 64 + vkq * 4) * 3072;
    vr[0] = *(const short8*)(const void*)vs;
    vr[1] = *(const short8*)(const void*)(vs + 3072);
    vr[2] = *(const short8*)(const void*)(vs + 6144);
    vr[3] = *(const short8*)(const void*)(vs + 9216);
  };
  auto VWRITE = [&]() {
#pragma unroll
    for (int jj = 0; jj < 8; ++jj) {
      const u64 pk = (u64)(u16)vr[0][jj] | ((u64)(u16)vr[1][jj] << 16) |
                     ((u64)(u16)vr[2][jj] << 32) | ((u64)(u16)vr[3][jj] << 48);
      *(u64*)(void*)(vdst + (vdg * 8 + jj) * 72 + vkq * 4) = pk;
    }
  };

  if (t0 < t1) {
    STAGEK(t0);
    VLOAD(t0);
    VWRITE();
    __syncthreads();
  }
  for (int t = t0; t < t1; ++t) {
    const int k0 = t * 64;
    const bool more = (t + 1 < t1);
    f32x4 sacc[4];
    __builtin_amdgcn_s_setprio(1);
#pragma unroll
    for (int nt = 0; nt < 4; ++nt) {
      const int key = nt * 16 + l15;
      const char* kbh = (const char*)Kh + key * 128;
      const char* kbl = (const char*)Kl + key * 128;
      const int sw = (key & 7) << 4;
      const short8 kh0 = *(const short8*)(const void*)(kbh + ((lg * 16) ^ sw));
      const short8 kh1 = *(const short8*)(const void*)(kbh + ((64 + lg * 16) ^ sw));
      const short8 kl0 = *(const short8*)(const void*)(kbl + ((lg * 16) ^ sw));
      const short8 kl1 = *(const short8*)(const void*)(kbl + ((64 + lg * 16) ^ sw));
      f32x4 s = {};
      s = mfma16(kh0, qh[0], s);  s = mfma16(kh1, qh[1], s);
      s = mfma16(kh0, qlo[0], s); s = mfma16(kh1, qlo[1], s);
      s = mfma16(kl0, qh[0], s);  s = mfma16(kl1, qh[1], s);
      sacc[nt] = s;
    }
    __builtin_amdgcn_s_setprio(0);
    __syncthreads();                  // B1: K reads done
    if (more) { STAGEK(t + 1); VLOAD(t + 1); }
#pragma unroll
    for (int nt = 0; nt < 4; ++nt)
#pragma unroll
      for (int r = 0; r < 4; ++r) sacc[nt][r] *= SCL2;
    if (t == qb) {
#pragma unroll
      for (int nt = 0; nt < 4; ++nt) {
        const int keyb = k0 + nt * 16 + lg * 4;
#pragma unroll
        for (int r = 0; r < 4; ++r)
          if (keyb + r > qcol) sacc[nt][r] = -__builtin_inff();
      }
    }
    float mx = sacc[0][0];
#pragma unroll
    for (int nt = 0; nt < 4; ++nt)
#pragma unroll
      for (int r = 0; r < 4; ++r) mx = fmaxf(mx, sacc[nt][r]);
    mx = fmaxf(mx, __shfl_xor(mx, 16, 64));
    mx = fmaxf(mx, __shfl_xor(mx, 32, 64));
    const bool grow = mx > m_run + 8.f;
    if (__any(grow)) {
      const float m_new = fmaxf(m_run, mx);
      const float fac = __builtin_amdgcn_exp2f(m_run - m_new);
      m_run = m_new;
      l_run *= fac;
      float facB[4];
#pragma unroll
      for (int r = 0; r < 4; ++r) facB[r] = __shfl(fac, lg * 4 + r, 64);
#pragma unroll
      for (int nd = 0; nd < 4; ++nd)
#pragma unroll
        for (int r = 0; r < 4; ++r) oacc[nd][r] *= facB[r];
    }
    float ls = 0.f;
#pragma unroll
    for (int nt = 0; nt < 4; ++nt)
#pragma unroll
      for (int r = 0; r < 4; ++r) {
        sacc[nt][r] = __builtin_amdgcn_exp2f(sacc[nt][r] - m_run);
        ls += sacc[nt][r];
      }
    ls += __shfl_xor(ls, 16, 64);
    ls += __shfl_xor(ls, 32, 64);
    l_run += ls;
    u16* prow = Pp + w * 1152 + l15 * 72;
#pragma unroll
    for (int nt = 0; nt < 4; ++nt) {
      const u64 pk = (u64)(__float_as_uint(sacc[nt][0]) >> 16) |
                     ((u64)(__float_as_uint(sacc[nt][1]) >> 16) << 16) |
                     ((u64)(__float_as_uint(sacc[nt][2]) >> 16) << 32) |
                     ((u64)(__float_as_uint(sacc[nt][3]) >> 16) << 48);
      *(u64*)(void*)(prow + nt * 16 + lg * 4) = pk;
    }
    __builtin_amdgcn_s_setprio(1);
#pragma unroll
    for (int kk2 = 0; kk2 < 2; ++kk2) {
      const short8 pa = *(const short8*)(const void*)((const char*)prow + kk2 * 64 + lg * 16);
#pragma unroll
      for (int nd = 0; nd < 4; ++nd) {
        const short8 vbh = *(const short8*)(const void*)((const char*)Vth + (nd * 16 + l15) * 144 + kk2 * 64 + lg * 16);
        const short8 vbl = *(const short8*)(const void*)((const char*)Vtl + (nd * 16 + l15) * 144 + kk2 * 64 + lg * 16);
        oacc[nd] = mfma16(pa, vbh, oacc[nd]);
        oacc[nd] = mfma16(pa, vbl, oacc[nd]);
      }
    }
    __builtin_amdgcn_s_setprio(0);
    asm volatile("" ::: "memory");
#pragma unroll
    for (int nt = 0; nt < 4; ++nt) {
      float lo[4];
#pragma unroll
      for (int r = 0; r < 4; ++r)
        lo[r] = sacc[nt][r] - __uint_as_float(__float_as_uint(sacc[nt][r]) & 0xFFFF0000u);
      const u64 pk = (u64)(__float_as_uint(lo[0]) >> 16) |
                     ((u64)(__float_as_uint(lo[1]) >> 16) << 16) |
                     ((u64)(__float_as_uint(lo[2]) >> 16) << 32) |
                     ((u64)(__float_as_uint(lo[3]) >> 16) << 48);
      *(u64*)(void*)(prow + nt * 16 + lg * 4) = pk;
    }
    asm volatile("" ::: "memory");
    __builtin_amdgcn_s_setprio(1);
#pragma unroll
    for (int kk2 = 0; kk2 < 2; ++kk2) {
      const short8 pa = *(const short8*)(const void*)((const char*)prow + kk2 * 64 + lg * 16);
#pragma unroll
      for (int nd = 0; nd < 4; ++nd) {
        const short8 vbh = *(const short8*)(const void*)((const char*)Vth + (nd * 16 + l15) * 144 + kk2 * 64 + lg * 16);
        oacc[nd] = mfma16(pa, vbh, oacc[nd]);
      }
    }
    __builtin_amdgcn_s_setprio(0);
    __syncthreads();                  // B2
    if (more) VWRITE();
  }
  float* Op = Opart + (size_t)sp * S * 1024;
#pragma unroll
  for (int nd = 0; nd < 4; ++nd)
#pragma unroll
    for (int r = 0; r < 4; ++r)
      Op[(size_t)(qrow0 + r) * 1024 + head * 64 + nd * 16 + l15] = oacc[nd][r];
  if (lg == 0) {
    ml[((size_t)sp * S + q0 + w * 16 + l15) * NH + head] = make_float2(m_run, l_run);
  }
}

// ================================================= combine 4 split-K attention partials
__global__ __launch_bounds__(256) void attn_combine(const float* __restrict__ Op,
    const float2* __restrict__ ml, u16* __restrict__ OA2) {
  const int t = blockIdx.x, tid = threadIdx.x;
  const int h = tid >> 4, dq = (tid & 15) * 4;
  float2 a[4];
  float M = -__builtin_inff();
#pragma unroll
  for (int c = 0; c < 4; ++c) {
    a[c] = ml[((size_t)c * S + t) * NH + h];
    if (a[c].y > 0.f) M = fmaxf(M, a[c].x);
  }
  float e[4], denom = 0.f;
#pragma unroll
  for (int c = 0; c < 4; ++c) {
    e[c] = (a[c].y > 0.f) ? exp2f(a[c].x - M) : 0.f;
    denom += e[c] * a[c].y;
  }
  const float inv = 1.f / denom;
  float ov[4] = {0.f, 0.f, 0.f, 0.f};
#pragma unroll
  for (int c = 0; c < 4; ++c) {
    const float4 v = *(const float4*)(Op + ((size_t)c * S + t) * 1024 + h * 64 + dq);
    ov[0] += e[c] * v.x; ov[1] += e[c] * v.y; ov[2] += e[c] * v.z; ov[3] += e[c] * v.w;
  }
#pragma unroll
  for (int c2 = 0; c2 < 4; ++c2) {
    const float o = ov[c2] * inv;
    const size_t idx = (size_t)t * 2048 + h * 64 + dq + c2;
    const u16 hb = f2bf(o);
    OA2[idx] = hb;
    OA2[idx + 1024] = f2bf(o - bf2f(hb));
  }
}

// ================================================= res2 (4 partials) + rmsnorm2 + gate (no atomics)
__global__ __launch_bounds__(256) void rmsnorm_res2_gate(const float* __restrict__ hidden,
    const float* __restrict__ p01, const float* __restrict__ w2, const float* __restrict__ GW,
    float* __restrict__ out, u16* __restrict__ yb,
    int* __restrict__ top2, float2* __restrict__ topw) {
  const int t = blockIdx.x;
  const int d0 = threadIdx.x * 4;
  const size_t base = (size_t)t * D + d0;
  const float4 h4 = *(const float4*)(hidden + base);
  const float4 a4 = *(const float4*)(p01 + base);
  const float4 b4 = *(const float4*)(p01 + (size_t)S * D + base);
  const float4 c4 = *(const float4*)(p01 + 2 * (size_t)S * D + base);
  const float4 e4 = *(const float4*)(p01 + 3 * (size_t)S * D + base);
  float v[4] = {h4.x + a4.x + b4.x + c4.x + e4.x, h4.y + a4.y + b4.y + c4.y + e4.y,
                h4.z + a4.z + b4.z + c4.z + e4.z, h4.w + a4.w + b4.w + c4.w + e4.w};
  float ss = v[0] * v[0] + v[1] * v[1] + v[2] * v[2] + v[3] * v[3];
#pragma unroll
  for (int m = 32; m >= 1; m >>= 1) ss += __shfl_xor(ss, m, 64);
  __shared__ float red[4];
  if ((threadIdx.x & 63) == 0) red[threadIdx.x >> 6] = ss;
  __syncthreads();
  const float rs = rsqrtf((red[0] + red[1] + red[2] + red[3]) * (1.f / (float)D) + EPS);
  const float4 w4 = *(const float4*)(w2 + d0);
  const float y[4] = {v[0] * rs * w4.x, v[1] * rs * w4.y, v[2] * rs * w4.z, v[3] * rs * w4.w};
  *(float4*)(out + base) = make_float4(v[0], v[1], v[2], v[3]);
  *(u64*)(void*)(yb + base) = pack4bf(y[0], y[1], y[2], y[3]);
  float lg[8] = {};
#pragma unroll
  for (int j = 0; j < 4; ++j) {
    const float4 g0 = *(const float4*)(GW + (d0 + j) * 8);
    const float4 g1 = *(const float4*)(GW + (d0 + j) * 8 + 4);
    lg[0] += y[j] * g0.x; lg[1] += y[j] * g0.y; lg[2] += y[j] * g0.z; lg[3] += y[j] * g0.w;
    lg[4] += y[j] * g1.x; lg[5] += y[j] * g1.y; lg[6] += y[j] * g1.z; lg[7] += y[j] * g1.w;
  }
#pragma unroll
  for (int e = 0; e < 8; ++e)
#pragma unroll
    for (int m = 32; m >= 1; m >>= 1) lg[e] += __shfl_xor(lg[e], m, 64);
  __shared__ float wred[4][8];
  if ((threadIdx.x & 63) == 0)
#pragma unroll
    for (int e = 0; e < 8; ++e) wred[threadIdx.x >> 6][e] = lg[e];
  __syncthreads();
  if (threadIdx.x == 0) {
    float L[8];
#pragma unroll
    for (int e = 0; e < 8; ++e) L[e] = wred[0][e] + wred[1][e] + wred[2][e] + wred[3][e];
    int i0 = 0; float v0 = L[0];
    for (int i = 1; i < 8; ++i) if (L[i] > v0) { v0 = L[i]; i0 = i; }
    int i1 = -1; float v1 = -__builtin_inff();
    for (int i = 0; i < 8; ++i) if (i != i0 && L[i] > v1) { v1 = L[i]; i1 = i; }
    const float e1 = expf(v1 - v0);
    const float inv = 1.f / (1.f + e1);
    top2[t] = i0 | (i1 << 4);
    topw[t] = make_float2(inv, e1 * inv);
  }
}

// ================================================= scatter compact: deterministic prefix-scan
__global__ __launch_bounds__(1024) void scatter_compact(const int* __restrict__ top2,
    const float2* __restrict__ topw, int* __restrict__ counts,
    int* __restrict__ tok_map, float* __restrict__ w_map) {
  const int tid = threadIdx.x;
  __shared__ u64 s0[1024], s1[1024];
  int e_[2][2]; float w_[2][2];
  u64 c0 = 0, c1 = 0;
#pragma unroll
  for (int k = 0; k < 2; ++k) {
    const int t = tid * 2 + k;
    const int pk = top2[t];
    const float2 wv = topw[t];
    e_[k][0] = pk & 15; e_[k][1] = (pk >> 4) & 15;
    w_[k][0] = wv.x;    w_[k][1] = wv.y;
#pragma unroll
    for (int s = 0; s < 2; ++s) {
      const int e = e_[k][s];
      if (e < 4) c0 += 1ull << (e * 16); else c1 += 1ull << ((e - 4) * 16);
    }
  }
  s0[tid] = c0; s1[tid] = c1;
  __syncthreads();
  for (int off = 1; off < 1024; off <<= 1) {
    const u64 a0 = (tid >= off) ? s0[tid - off] : 0;
    const u64 a1 = (tid >= off) ? s1[tid - off] : 0;
    __syncthreads();
    s0[tid] += a0; s1[tid] += a1;
    __syncthreads();
  }
  if (tid == 1023) {
#pragma unroll
    for (int e = 0; e < 4; ++e) counts[e] = (int)((s0[1023] >> (e * 16)) & 0xFFFF);
#pragma unroll
    for (int e = 4; e < 8; ++e) counts[e] = (int)((s1[1023] >> ((e - 4) * 16)) & 0xFFFF);
  }
  u64 l0 = s0[tid] - c0, l1 = s1[tid] - c1;
#pragma unroll
  for (int k = 0; k < 2; ++k) {
    const int t = tid * 2 + k;
#pragma unroll
    for (int s = 0; s < 2; ++s) {
      const int e = e_[k][s];
      int p;
      if (e < 4) { p = (int)((l0 >> (e * 16)) & 0xFFFF); l0 += 1ull << (e * 16); }
      else       { p = (int)((l1 >> ((e - 4) * 16)) & 0xFFFF); l1 += 1ull << ((e - 4) * 16); }
      tok_map[e * S + p] = t | (s << 16);
      w_map[e * S + p] = w_[k][s];
    }
  }
}

// ================================================= MoE gate/up GEMM: 128x64 tile, dual-B, dbuf
__global__ __launch_bounds__(256) void moe_gu(const u16* __restrict__ Yb,
    const u16* __restrict__ Wgb, const u16* __restrict__ Wub, u16* __restrict__ Hb,
    const int* __restrict__ counts, const int* __restrict__ tokmap) {
  const int b = blockIdx.x;
  const int e = b & 7, ii = b >> 3;
  const int n0 = (ii & 15) * 64;
  const int m0 = (ii >> 4) * 128;
  const int cnt = counts[e];
  if (m0 >= cnt) return;
  __shared__ u16 SH[2][16 * 512];
  const int tid = threadIdx.x, wv = tid >> 6, lane = tid & 63;
  const int l15 = lane & 15, lg = lane >> 4;
  const int wr = wv >> 1, wc = wv & 1;
  const int sr = lane >> 2, sk = (lane & 3) * 16;
  const u16* B1 = Wgb + (size_t)e * 1048576;
  const u16* B2 = Wub + (size_t)e * 1048576;
  const u16* cp[4];
#pragma unroll
  for (int i = 0; i < 4; ++i) {
    const int c = wv * 4 + i;
    if (c < 8) {
      const int arow = m0 + c * 16 + sr;
      const int tok = tokmap[e * S + arow] & 2047;
      cp[i] = Yb + (size_t)tok * 1024;
    } else if (c < 12) {
      cp[i] = B1 + (size_t)(n0 + (c - 8) * 16 + sr) * 1024;
    } else {
      cp[i] = B2 + (size_t)(n0 + (c - 12) * 16 + sr) * 1024;
    }
  }
  auto STAGE = [&](int buf, int k) {
#pragma unroll
    for (int i = 0; i < 4; ++i) {
      const int c = wv * 4 + i;
      gl_lds16((const char*)(cp[i] + k) + sk, (char*)SH + buf * 16384 + c * 1024);
    }
  };
  f32x4 acc1[4][2] = {};
  f32x4 acc2[4][2] = {};
  STAGE(0, 0);
  __syncthreads();
  int cur = 0;
  for (int kk = 0; kk < 32; ++kk) {
    if (kk < 31) STAGE(cur ^ 1, (kk + 1) * 32);
    const u16* Sb = (const u16*)SH + cur * 8192;
    short8 a[4], b1f[2], b2f[2];
#pragma unroll
    for (int i = 0; i < 4; ++i)
      a[i] = *(const short8*)(const void*)(Sb + (size_t)(wr * 64 + i * 16 + l15) * 32 + lg * 8);
#pragma unroll
    for (int j = 0; j < 2; ++j) {
      b1f[j] = *(const short8*)(const void*)(Sb + 4096 + (size_t)(wc * 32 + j * 16 + l15) * 32 + lg * 8);
      b2f[j] = *(const short8*)(const void*)(Sb + 6144 + (size_t)(wc * 32 + j * 16 + l15) * 32 + lg * 8);
    }
    __builtin_amdgcn_s_setprio(1);
#pragma unroll
    for (int i = 0; i < 4; ++i)
#pragma unroll
      for (int j = 0; j < 2; ++j) {
        acc1[i][j] = mfma16(a[i], b1f[j], acc1[i][j]);
        acc2[i][j] = mfma16(a[i], b2f[j], acc2[i][j]);
      }
    __builtin_amdgcn_s_setprio(0);
    __syncthreads();
    cur ^= 1;
  }
#pragma unroll
  for (int i = 0; i < 4; ++i)
#pragma unroll
    for (int j = 0; j < 2; ++j)
#pragma unroll
      for (int r = 0; r < 4; ++r) {
        const int row = m0 + wr * 64 + i * 16 + lg * 4 + r;
        if (row < cnt) {
          const float g = acc1[i][j][r];
          const float u = acc2[i][j][r];
          const float sig = __builtin_amdgcn_rcpf(1.f + __builtin_amdgcn_exp2f(-g * LOG2E));
          Hb[((size_t)e * 2048 + row) * 1024 + n0 + wc * 32 + j * 16 + l15] = f2bf(u * g * sig);
        }
      }
}

// ================================================= MoE down GEMM: split-K x2 -> 4 bf16 slot planes
__global__ __launch_bounds__(256) void moe_down(const u16* __restrict__ Hb,
    const u16* __restrict__ Wdb, u16* __restrict__ slotp,
    const int* __restrict__ counts, const int* __restrict__ tokmap,
    const float* __restrict__ wmap) {
  const int b = blockIdx.x;
  const int e = b & 7, ii = b >> 3;
  const int m0 = (ii & 15) * 128;
  const int n0 = ((ii >> 4) & 7) * 128;
  const int ks = ii >> 7;
  const int cnt = counts[e];
  if (m0 >= cnt) return;
  __shared__ u16 As[2][128 * 32];
  __shared__ u16 Bs[2][128 * 32];
  const int tid = threadIdx.x, wv = tid >> 6, lane = tid & 63;
  const int l15 = lane & 15, lg = lane >> 4;
  const int wr = wv >> 1, wc = wv & 1;
  const int sr = lane >> 2, sk = (lane & 3) * 16;
  const u16* B = Wdb + (size_t)e * 1048576;
  const u16* aptr[2]; const u16* bptr[2];
#pragma unroll
  for (int i = 0; i < 2; ++i) {
    aptr[i] = Hb + ((size_t)e * 2048 + m0 + (wv * 2 + i) * 16 + sr) * 1024;
    bptr[i] = B + (size_t)(n0 + (wv * 2 + i) * 16 + sr) * 1024;
  }
  auto STAGE = [&](int buf, int k) {
#pragma unroll
    for (int i = 0; i < 2; ++i) {
      gl_lds16((const char*)(aptr[i] + k) + sk, (char*)As + buf * 8192 + (wv * 2 + i) * 1024);
      gl_lds16((const char*)(bptr[i] + k) + sk, (char*)Bs + buf * 8192 + (wv * 2 + i) * 1024);
    }
  };
  f32x4 acc[4][4] = {};
  const int kb0 = ks * 16, kb1 = kb0 + 16;
  STAGE(0, kb0 * 32);
  __syncthreads();
  int cur = 0;
  for (int kk = kb0; kk < kb1; ++kk) {
    if (kk + 1 < kb1) STAGE(cur ^ 1, (kk + 1) * 32);
    const u16* Ab = (const u16*)As + cur * 4096;
    const u16* Bb = (const u16*)Bs + cur * 4096;
    short8 a[4], bb[4];
#pragma unroll
    for (int i = 0; i < 4; ++i)
      a[i] = *(const short8*)(const void*)(Ab + (size_t)(wr * 64 + i * 16 + l15) * 32 + lg * 8);
#pragma unroll
    for (int j = 0; j < 4; ++j)
      bb[j] = *(const short8*)(const void*)(Bb + (size_t)(wc * 64 + j * 16 + l15) * 32 + lg * 8);
    __builtin_amdgcn_s_setprio(1);
#pragma unroll
    for (int i = 0; i < 4; ++i)
#pragma unroll
      for (int j = 0; j < 4; ++j) acc[i][j] = mfma16(a[i], bb[j], acc[i][j]);
    __builtin_amdgcn_s_setprio(0);
    __syncthreads();
    cur ^= 1;
  }
#pragma unroll
  for (int i = 0; i < 4; ++i)
#pragma unroll
    for (int j = 0; j < 4; ++j)
#pragma unroll
      for (int r = 0; r < 4; ++r) {
        const int row = m0 + wr * 64 + i * 16 + lg * 4 + r;
        if (row < cnt) {
          const int raw = tokmap[e * S + row];
          const int t = raw & 2047;
          const int sl = (raw >> 16) & 1;
          const float wgt = wmap[e * S + row];
          slotp[((size_t)(sl * 2 + ks) * S + t) * 1024 + n0 + wc * 64 + j * 16 + l15] =
              f2bf(wgt * acc[i][j][r]);
        }
      }
}

// ================================================= final add: out += sum of 4 slot planes
__global__ __launch_bounds__(256) void final_add(float* __restrict__ out,
    const u16* __restrict__ sp) {
  const size_t i = ((size_t)blockIdx.x * 256 + threadIdx.x) * 4;
  float4 o = *(float4*)(out + i);
#pragma unroll
  for (int c = 0; c < 4; ++c) {
    const u64 a = *(const u64*)(sp + (size_t)c * S * D + i);
    o.x += bf2f((u16)(a));
    o.y += bf2f((u16)(a >> 16));
    o.z += bf2f((u16)(a >> 32));
    o.w += bf2f((u16)(a >> 48));
  }
  *(float4*)(out + i) = o;
}

// ================================================= launch
extern "C" void kernel_launch(void* const* d_in, const int* in_sizes, int n_in,
                              void* d_out, int out_size, void* d_ws, size_t ws_size,
                              hipStream_t stream) {
  const int*   positions = (const int*)d_in[0];
  const float* hidden    = (const float*)d_in[1];
  const float* ln1_w  = (const float*)d_in[3];
  const float* ln2_w  = (const float*)d_in[4];
  const float* wqkv   = (const float*)d_in[5];
  const float* wo     = (const float*)d_in[6];
  const float* gate_w = (const float*)d_in[7];
  const float* wg     = (const float*)d_in[8];
  const float* wu     = (const float*)d_in[9];
  const float* wd     = (const float*)d_in[10];
  float* out = (float*)d_out;

  char* ws = (char*)d_ws;
  const size_t MB = 1ull << 20;
  u16* wqkvT2 = (u16*)(ws);
  u16* QKVh   = (u16*)(ws);
  u16* OA2    = (u16*)(ws);
  u16* woT2   = (u16*)(ws + 12 * MB);       // 4MB  (merged attn -> gemm_wo)
  u16* wgT    = (u16*)(ws + 16 * MB);       // 16MB
  u16* wuT    = (u16*)(ws + 32 * MB);       // 16MB
  u16* wdT    = (u16*)(ws + 48 * MB);       // 16MB
  float2* ropetab = (float2*)(ws + 64 * MB);            // 512KB
  float2* ml      = (float2*)(ws + 64 * MB + 524288);   // 1MB
  char* mapb = ws + 64 * MB + 1572864;
  int*   counts   = (int*)mapb;
  int*   tok_map  = (int*)(mapb + 512);
  float* w_map    = (float*)(mapb + 512 + 65536);
  int*   top2     = (int*)(mapb + 512 + 131072);
  float2* topw    = (float2*)(mapb + 512 + 139264);
  u16* xn2    = (u16*)(ws + 66 * MB);       // 8MB  (ph1-2)
  u16* QKVl   = (u16*)(ws + 66 * MB);       // 12MB (ph3-4, xn2 dead)
  u16* yb     = (u16*)(ws + 66 * MB);       // 4MB  (ph6+, QKVl dead)
  float* Cpart  = (float*)(ws + 78 * MB);   // 48MB (ph2-3)
  float* Opart  = (float*)(ws + 78 * MB);   // 32MB (ph4, Cpart dead)
  float* p01    = (float*)(ws + 78 * MB);   // 32MB (ph5-6)
  u16* Hb     = (u16*)(ws + 78 * MB);       // 32MB (ph7)
  u16* slotp  = (u16*)(ws + 110 * MB);      // 16MB (ph7-8)

  prep_early<<<3072, 256, 0, stream>>>(wqkv, positions, hidden, ln1_w,
                                       wqkvT2, ropetab, xn2);
  gemm_qkv<<<768, 256, 0, stream>>>(xn2, wqkvT2, Cpart);
  qkv_combine<<<S, 256, 0, stream>>>(Cpart, ropetab, QKVh, QKVl);
  attn_mfma<<<8448, 256, 0, stream>>>(QKVh, QKVl, Opart, ml,
                                      wo, wg, wu, wd, woT2, wgT, wuT, wdT);
  attn_combine<<<S, 256, 0, stream>>>(Opart, ml, OA2);
  gemm_wo<<<512, 256, 0, stream>>>(OA2, woT2, p01);
  rmsnorm_res2_gate<<<S, 256, 0, stream>>>(hidden, p01, ln2_w, gate_w, out, yb, top2, topw);
  scatter_compact<<<1, 1024, 0, stream>>>(top2, topw, counts, tok_map, w_map);
  moe_gu<<<2048, 256, 0, stream>>>(yb, wgT, wuT, Hb, counts, tok_map);
  moe_down<<<2048, 256, 0, stream>>>(Hb, wdT, slotp, counts, tok_map, w_map);
  final_add<<<2048, 256, 0, stream>>>(out, slotp);
}